// Round 1
// baseline (29650.272 us; speedup 1.0000x reference)
//
#include <hip/hip_runtime.h>
#include <cmath>

// Problem constants (from reference)
constexpr int NN = 50000;      // nodes
constexpr int NE = 1600000;    // edges
constexpr int H  = 64;         // hidden
constexpr int NL = 5;          // layers
constexpr int NG = 4;          // graphs
constexpr int EIN = 2 * H + 5; // 133
constexpr int NIN = 2 * H;     // 128

__device__ __forceinline__ float silu_f(float x) {
    return x / (1.0f + __expf(-x));
}

// ---------------------------------------------------------------------------
// Encoder: h = LN(silu([x, gv[batch]] @ W1 + b1) @ W2 + b2)
// tile = 64 nodes / block, 4 waves, wave w computes channels [16w, 16w+16)
// ---------------------------------------------------------------------------
__global__ __launch_bounds__(256) void encoder_kernel(
    const float* __restrict__ x, const int* __restrict__ batch,
    const float* __restrict__ case_p, const float* __restrict__ bc_p,
    const float* __restrict__ W1, const float* __restrict__ b1,
    const float* __restrict__ W2, const float* __restrict__ b2,
    const float* __restrict__ g, const float* __restrict__ be,
    float* __restrict__ h)
{
    __shared__ float in_sh[64 * 17];
    __shared__ float m1_sh[64 * 65];
    __shared__ float red_sh[2 * 4 * 64];
    const int lane = threadIdx.x & 63;
    const int w    = threadIdx.x >> 6;
    const int n0   = blockIdx.x * 64;

    // stage: wave w stages node slots [16w, 16w+16)
    for (int i = 0; i < 16; ++i) {
        int slot = w * 16 + i;
        int n = n0 + slot;
        if (n < NN && lane < 16) {
            float v;
            if (lane < 8) v = x[n * 8 + lane];
            else {
                int b = batch[n];
                v = (lane < 12) ? case_p[b * 4 + (lane - 8)]
                                : bc_p[b * 4 + (lane - 12)];
            }
            in_sh[slot * 17 + lane] = v;
        }
    }
    __syncthreads();

    float acc[16];
#pragma unroll
    for (int c = 0; c < 16; ++c) acc[c] = b1[w * 16 + c];
    for (int k = 0; k < 16; ++k) {
        float a = in_sh[lane * 17 + k];
        const float* wr = W1 + k * 64 + w * 16;
#pragma unroll
        for (int c = 0; c < 16; ++c) acc[c] = fmaf(a, wr[c], acc[c]);
    }
#pragma unroll
    for (int c = 0; c < 16; ++c) m1_sh[lane * 65 + w * 16 + c] = silu_f(acc[c]);
    __syncthreads();

    float acc2[16];
#pragma unroll
    for (int c = 0; c < 16; ++c) acc2[c] = b2[w * 16 + c];
    for (int k = 0; k < 64; ++k) {
        float a = m1_sh[lane * 65 + k];
        const float* wr = W2 + k * 64 + w * 16;
#pragma unroll
        for (int c = 0; c < 16; ++c) acc2[c] = fmaf(a, wr[c], acc2[c]);
    }

    float s1 = 0.f, s2 = 0.f;
#pragma unroll
    for (int c = 0; c < 16; ++c) { s1 += acc2[c]; s2 += acc2[c] * acc2[c]; }
    red_sh[w * 64 + lane] = s1;
    red_sh[256 + w * 64 + lane] = s2;
    __syncthreads();
    float t1 = 0.f, t2 = 0.f;
#pragma unroll
    for (int j = 0; j < 4; ++j) {
        t1 += red_sh[j * 64 + lane];
        t2 += red_sh[256 + j * 64 + lane];
    }
    float mean = t1 * (1.0f / 64.0f);
    float var  = t2 * (1.0f / 64.0f) - mean * mean;
    float rstd = rsqrtf(var + 1e-5f);

    int n = n0 + lane;
    if (n < NN) {
#pragma unroll
        for (int c = 0; c < 16; ++c) {
            int ch = w * 16 + c;
            h[n * 64 + ch] = (acc2[c] - mean) * rstd * g[ch] + be[ch];
        }
    }
}

// ---------------------------------------------------------------------------
// Edge MLP + scatter-add: m = LN(silu([h[dst],h[src],ea] @ W1+b1) @ W2+b2)
// agg[dst] += m.  tile = 64 edges / block (NE % 64 == 0, no guards)
// ---------------------------------------------------------------------------
__global__ __launch_bounds__(256) void edge_kernel(
    const float* __restrict__ h, const int* __restrict__ ei,
    const float* __restrict__ ea,
    const float* __restrict__ W1, const float* __restrict__ b1,
    const float* __restrict__ W2, const float* __restrict__ b2,
    const float* __restrict__ g, const float* __restrict__ be,
    float* __restrict__ agg)
{
    __shared__ float in_sh[64 * 133];
    __shared__ float m1_sh[64 * 65];
    __shared__ float red_sh[2 * 4 * 64];
    const int lane = threadIdx.x & 63;
    const int w    = threadIdx.x >> 6;
    const int e0   = blockIdx.x * 64;

    for (int i = 0; i < 16; ++i) {
        int slot = w * 16 + i;
        int eid = e0 + slot;
        int s = ei[eid];         // src = edge_index[0]
        int d = ei[NE + eid];    // dst = edge_index[1]
        in_sh[slot * 133 + lane]      = h[d * 64 + lane];  // xi = h[dst]
        in_sh[slot * 133 + 64 + lane] = h[s * 64 + lane];  // xj = h[src]
        if (lane < 5) in_sh[slot * 133 + 128 + lane] = ea[eid * 5 + lane];
    }
    __syncthreads();

    float acc[16];
#pragma unroll
    for (int c = 0; c < 16; ++c) acc[c] = b1[w * 16 + c];
    for (int k = 0; k < 133; ++k) {
        float a = in_sh[lane * 133 + k];
        const float* wr = W1 + k * 64 + w * 16;
#pragma unroll
        for (int c = 0; c < 16; ++c) acc[c] = fmaf(a, wr[c], acc[c]);
    }
#pragma unroll
    for (int c = 0; c < 16; ++c) m1_sh[lane * 65 + w * 16 + c] = silu_f(acc[c]);
    __syncthreads();

    float acc2[16];
#pragma unroll
    for (int c = 0; c < 16; ++c) acc2[c] = b2[w * 16 + c];
    for (int k = 0; k < 64; ++k) {
        float a = m1_sh[lane * 65 + k];
        const float* wr = W2 + k * 64 + w * 16;
#pragma unroll
        for (int c = 0; c < 16; ++c) acc2[c] = fmaf(a, wr[c], acc2[c]);
    }

    float s1 = 0.f, s2 = 0.f;
#pragma unroll
    for (int c = 0; c < 16; ++c) { s1 += acc2[c]; s2 += acc2[c] * acc2[c]; }
    red_sh[w * 64 + lane] = s1;
    red_sh[256 + w * 64 + lane] = s2;
    __syncthreads();
    float t1 = 0.f, t2 = 0.f;
#pragma unroll
    for (int j = 0; j < 4; ++j) {
        t1 += red_sh[j * 64 + lane];
        t2 += red_sh[256 + j * 64 + lane];
    }
    float mean = t1 * (1.0f / 64.0f);
    float var  = t2 * (1.0f / 64.0f) - mean * mean;
    float rstd = rsqrtf(var + 1e-5f);

    int d = ei[NE + e0 + lane];   // this lane's edge dst
#pragma unroll
    for (int c = 0; c < 16; ++c) {
        int ch = w * 16 + c;
        float v = (acc2[c] - mean) * rstd * g[ch] + be[ch];
        atomicAdd(&agg[d * 64 + ch], v);
    }
}

// ---------------------------------------------------------------------------
// Node MLP + residual: h = h + LN(silu([h,agg] @ W1+b1) @ W2+b2)
// ---------------------------------------------------------------------------
__global__ __launch_bounds__(256) void node_kernel(
    float* __restrict__ h, const float* __restrict__ agg,
    const float* __restrict__ W1, const float* __restrict__ b1,
    const float* __restrict__ W2, const float* __restrict__ b2,
    const float* __restrict__ g, const float* __restrict__ be)
{
    __shared__ float in_sh[64 * 129];
    __shared__ float m1_sh[64 * 65];
    __shared__ float red_sh[2 * 4 * 64];
    const int lane = threadIdx.x & 63;
    const int w    = threadIdx.x >> 6;
    const int n0   = blockIdx.x * 64;

    for (int i = 0; i < 16; ++i) {
        int slot = w * 16 + i;
        int n = n0 + slot;
        if (n < NN) {
            in_sh[slot * 129 + lane]      = h[n * 64 + lane];
            in_sh[slot * 129 + 64 + lane] = agg[n * 64 + lane];
        }
    }
    __syncthreads();

    float acc[16];
#pragma unroll
    for (int c = 0; c < 16; ++c) acc[c] = b1[w * 16 + c];
    for (int k = 0; k < 128; ++k) {
        float a = in_sh[lane * 129 + k];
        const float* wr = W1 + k * 64 + w * 16;
#pragma unroll
        for (int c = 0; c < 16; ++c) acc[c] = fmaf(a, wr[c], acc[c]);
    }
#pragma unroll
    for (int c = 0; c < 16; ++c) m1_sh[lane * 65 + w * 16 + c] = silu_f(acc[c]);
    __syncthreads();

    float acc2[16];
#pragma unroll
    for (int c = 0; c < 16; ++c) acc2[c] = b2[w * 16 + c];
    for (int k = 0; k < 64; ++k) {
        float a = m1_sh[lane * 65 + k];
        const float* wr = W2 + k * 64 + w * 16;
#pragma unroll
        for (int c = 0; c < 16; ++c) acc2[c] = fmaf(a, wr[c], acc2[c]);
    }

    float s1 = 0.f, s2 = 0.f;
#pragma unroll
    for (int c = 0; c < 16; ++c) { s1 += acc2[c]; s2 += acc2[c] * acc2[c]; }
    red_sh[w * 64 + lane] = s1;
    red_sh[256 + w * 64 + lane] = s2;
    __syncthreads();
    float t1 = 0.f, t2 = 0.f;
#pragma unroll
    for (int j = 0; j < 4; ++j) {
        t1 += red_sh[j * 64 + lane];
        t2 += red_sh[256 + j * 64 + lane];
    }
    float mean = t1 * (1.0f / 64.0f);
    float var  = t2 * (1.0f / 64.0f) - mean * mean;
    float rstd = rsqrtf(var + 1e-5f);

    int n = n0 + lane;
    if (n < NN) {
#pragma unroll
        for (int c = 0; c < 16; ++c) {
            int ch = w * 16 + c;
            float hv = in_sh[lane * 129 + ch];   // original h (ch < 64)
            h[n * 64 + ch] = hv + (acc2[c] - mean) * rstd * g[ch] + be[ch];
        }
    }
}

// ---------------------------------------------------------------------------
// Local decoder: out_local = silu(h @ W1 + b1) @ W2 + b2  -> [NN, 6]
// one wave per node; per-wave LDS only (no block barrier; early-exit safe)
// ---------------------------------------------------------------------------
__global__ __launch_bounds__(256) void dec_local_kernel(
    const float* __restrict__ h,
    const float* __restrict__ W1, const float* __restrict__ b1,
    const float* __restrict__ W2, const float* __restrict__ b2,
    float* __restrict__ out)
{
    __shared__ float mid_sh[4][64];
    const int lane = threadIdx.x & 63;
    const int w    = threadIdx.x >> 6;
    const int n = blockIdx.x * 4 + w;
    if (n >= NN) return;

    float a = b1[lane];
    for (int k = 0; k < 64; ++k)
        a = fmaf(h[n * 64 + k], W1[k * 64 + lane], a);
    mid_sh[w][lane] = silu_f(a);
    // wave-internal LDS dependency; compiler inserts lgkmcnt wait
    if (lane < 6) {
        float o = b2[lane];
        for (int k = 0; k < 64; ++k)
            o = fmaf(mid_sh[w][k], W2[k * 6 + lane], o);
        out[n * 6 + lane] = o;
    }
}

// ---------------------------------------------------------------------------
// Pooling: pooled[g][c] = sum_{batch[n]==g} h[n][c];  cnt[g] = count
// ---------------------------------------------------------------------------
__global__ __launch_bounds__(256) void pool_kernel(
    const float* __restrict__ h, const int* __restrict__ batch,
    float* __restrict__ pooled, float* __restrict__ cnt)
{
    const int c   = threadIdx.x & 63;
    const int rep = blockIdx.x * 4 + (threadIdx.x >> 6);   // 1024 reps
    float acc[NG] = {0.f, 0.f, 0.f, 0.f};
    float cl[NG]  = {0.f, 0.f, 0.f, 0.f};
    for (int n = rep; n < NN; n += 1024) {
        int b = batch[n];
        float v = h[n * 64 + c];
#pragma unroll
        for (int gph = 0; gph < NG; ++gph) {
            if (b == gph) { acc[gph] += v; cl[gph] += 1.0f; }
        }
    }
#pragma unroll
    for (int gph = 0; gph < NG; ++gph) {
        atomicAdd(&pooled[gph * 64 + c], acc[gph]);
        if (c == 0) atomicAdd(&cnt[gph], cl[gph]);
    }
}

// ---------------------------------------------------------------------------
// Global decoder: out_global = silu(mean_pool @ W1 + b1) @ W2 + b2 -> [4,4]
// one block, wave per graph
// ---------------------------------------------------------------------------
__global__ __launch_bounds__(256) void dec_global_kernel(
    const float* __restrict__ pooled, const float* __restrict__ cnt,
    const float* __restrict__ W1, const float* __restrict__ b1,
    const float* __restrict__ W2, const float* __restrict__ b2,
    float* __restrict__ out)
{
    __shared__ float mid_sh[4][32];
    const int lane = threadIdx.x & 63;
    const int gph  = threadIdx.x >> 6;
    float inv = 1.0f / fmaxf(cnt[gph], 1.0f);
    if (lane < 32) {
        float a = b1[lane];
        for (int k = 0; k < 64; ++k)
            a = fmaf(pooled[gph * 64 + k] * inv, W1[k * 32 + lane], a);
        mid_sh[gph][lane] = silu_f(a);
    }
    __syncthreads();
    if (lane < 4) {
        float o = b2[lane];
        for (int k = 0; k < 32; ++k)
            o = fmaf(mid_sh[gph][k], W2[k * 4 + lane], o);
        out[gph * 4 + lane] = o;
    }
}

// ---------------------------------------------------------------------------
extern "C" void kernel_launch(void* const* d_in, const int* in_sizes, int n_in,
                              void* d_out, int out_size, void* d_ws, size_t ws_size,
                              hipStream_t stream)
{
    const float* x      = (const float*)d_in[0];
    const int*   ei     = (const int*)  d_in[1];
    const float* ea     = (const float*)d_in[2];
    const int*   batch  = (const int*)  d_in[3];
    const float* case_p = (const float*)d_in[4];
    const float* bc_p   = (const float*)d_in[5];
    const float* enc_W1 = (const float*)d_in[6];
    const float* enc_b1 = (const float*)d_in[7];
    const float* enc_W2 = (const float*)d_in[8];
    const float* enc_b2 = (const float*)d_in[9];
    const float* enc_g  = (const float*)d_in[10];
    const float* enc_be = (const float*)d_in[11];
    const float* eW1    = (const float*)d_in[12];
    const float* eb1    = (const float*)d_in[13];
    const float* eW2    = (const float*)d_in[14];
    const float* eb2    = (const float*)d_in[15];
    const float* eg     = (const float*)d_in[16];
    const float* ebe    = (const float*)d_in[17];
    const float* nW1    = (const float*)d_in[18];
    const float* nb1    = (const float*)d_in[19];
    const float* nW2    = (const float*)d_in[20];
    const float* nb2    = (const float*)d_in[21];
    const float* ng     = (const float*)d_in[22];
    const float* nbe    = (const float*)d_in[23];
    const float* dlW1   = (const float*)d_in[24];
    const float* dlb1   = (const float*)d_in[25];
    const float* dlW2   = (const float*)d_in[26];
    const float* dlb2   = (const float*)d_in[27];
    const float* dgW1   = (const float*)d_in[28];
    const float* dgb1   = (const float*)d_in[29];
    const float* dgW2   = (const float*)d_in[30];
    const float* dgb2   = (const float*)d_in[31];

    float* out = (float*)d_out;

    char* ws = (char*)d_ws;
    const size_t hBytes = (size_t)NN * H * sizeof(float);     // 12.8 MB
    float* h      = (float*)(ws);
    float* agg    = (float*)(ws + hBytes);
    float* pooled = (float*)(ws + 2 * hBytes);
    float* cnt    = (float*)(ws + 2 * hBytes + 256 * sizeof(float));

    hipMemsetAsync(pooled, 0, (256 + 4) * sizeof(float), stream);

    const int nodeBlocks = (NN + 63) / 64;    // 782
    encoder_kernel<<<nodeBlocks, 256, 0, stream>>>(
        x, batch, case_p, bc_p, enc_W1, enc_b1, enc_W2, enc_b2, enc_g, enc_be, h);

    for (int l = 0; l < NL; ++l) {
        hipMemsetAsync(agg, 0, hBytes, stream);
        edge_kernel<<<NE / 64, 256, 0, stream>>>(
            h, ei, ea,
            eW1 + (size_t)l * EIN * H, eb1 + l * H,
            eW2 + (size_t)l * H * H,   eb2 + l * H,
            eg + l * H, ebe + l * H, agg);
        node_kernel<<<nodeBlocks, 256, 0, stream>>>(
            h, agg,
            nW1 + (size_t)l * NIN * H, nb1 + l * H,
            nW2 + (size_t)l * H * H,   nb2 + l * H,
            ng + l * H, nbe + l * H);
    }

    dec_local_kernel<<<(NN + 3) / 4, 256, 0, stream>>>(h, dlW1, dlb1, dlW2, dlb2, out);
    pool_kernel<<<256, 256, 0, stream>>>(h, batch, pooled, cnt);
    dec_global_kernel<<<1, 256, 0, stream>>>(pooled, cnt, dgW1, dgb1, dgW2, dgb2,
                                             out + (size_t)NN * 6);
}

// Round 2
// 13883.788 us; speedup vs baseline: 2.1356x; 2.1356x over previous
//
#include <hip/hip_runtime.h>
#include <cmath>

// Problem constants (from reference)
constexpr int NN = 50000;      // nodes
constexpr int NE = 1600000;    // edges
constexpr int H  = 64;         // hidden
constexpr int NL = 5;          // layers
constexpr int NG = 4;          // graphs
constexpr int EIN = 2 * H + 5; // 133
constexpr int NIN = 2 * H;     // 128

__device__ __forceinline__ float silu_f(float x) {
    return x / (1.0f + __expf(-x));
}

// ---------------------------------------------------------------------------
// Counting sort of edges by dst: degree histogram
// ---------------------------------------------------------------------------
__global__ __launch_bounds__(256) void degree_kernel(
    const int* __restrict__ ei, int* __restrict__ deg)
{
    int e = blockIdx.x * 256 + threadIdx.x;
    if (e < NE) atomicAdd(&deg[ei[NE + e]], 1);
}

// Single-block exclusive scan over deg[0..NN) -> off, cursor (copies)
__global__ __launch_bounds__(1024) void scan_kernel(
    const int* __restrict__ deg, int* __restrict__ off, int* __restrict__ cursor)
{
    __shared__ int sh[1024];
    const int tid = threadIdx.x;
    int running = 0;
    for (int base = 0; base < NN; base += 1024) {
        int v = (base + tid < NN) ? deg[base + tid] : 0;
        sh[tid] = v;
        __syncthreads();
        for (int d = 1; d < 1024; d <<= 1) {
            int t = (tid >= d) ? sh[tid - d] : 0;
            __syncthreads();
            sh[tid] += t;
            __syncthreads();
        }
        int excl = sh[tid] - v;
        if (base + tid < NN) {
            off[base + tid] = running + excl;
            cursor[base + tid] = running + excl;
        }
        int total = sh[1023];
        __syncthreads();
        running += total;
    }
    if (tid == 0) off[NN] = running;
}

// Scatter edge ids into dst-sorted order; also record src/dst per sorted slot
__global__ __launch_bounds__(256) void scatter_kernel(
    const int* __restrict__ ei, int* __restrict__ cursor,
    int* __restrict__ sidx, int* __restrict__ sdst, int* __restrict__ ssrc)
{
    int e = blockIdx.x * 256 + threadIdx.x;
    if (e < NE) {
        int d = ei[NE + e];
        int p = atomicAdd(&cursor[d], 1);
        sidx[p] = e;
        sdst[p] = d;
        ssrc[p] = ei[e];
    }
}

// ---------------------------------------------------------------------------
// Encoder: h = LN(silu([x, gv[batch]] @ W1 + b1) @ W2 + b2)
// tile = 64 nodes / block, 4 waves, wave w computes channels [16w, 16w+16)
// ---------------------------------------------------------------------------
__global__ __launch_bounds__(256) void encoder_kernel(
    const float* __restrict__ x, const int* __restrict__ batch,
    const float* __restrict__ case_p, const float* __restrict__ bc_p,
    const float* __restrict__ W1, const float* __restrict__ b1,
    const float* __restrict__ W2, const float* __restrict__ b2,
    const float* __restrict__ g, const float* __restrict__ be,
    float* __restrict__ h)
{
    __shared__ float in_sh[64 * 17];
    __shared__ float m1_sh[64 * 65];
    __shared__ float red_sh[2 * 4 * 64];
    const int lane = threadIdx.x & 63;
    const int w    = threadIdx.x >> 6;
    const int n0   = blockIdx.x * 64;

    for (int i = 0; i < 16; ++i) {
        int slot = w * 16 + i;
        int n = n0 + slot;
        if (n < NN && lane < 16) {
            float v;
            if (lane < 8) v = x[n * 8 + lane];
            else {
                int b = batch[n];
                v = (lane < 12) ? case_p[b * 4 + (lane - 8)]
                                : bc_p[b * 4 + (lane - 12)];
            }
            in_sh[slot * 17 + lane] = v;
        }
    }
    __syncthreads();

    float acc[16];
#pragma unroll
    for (int c = 0; c < 16; ++c) acc[c] = b1[w * 16 + c];
    for (int k = 0; k < 16; ++k) {
        float a = in_sh[lane * 17 + k];
        const float* wr = W1 + k * 64 + w * 16;
#pragma unroll
        for (int c = 0; c < 16; ++c) acc[c] = fmaf(a, wr[c], acc[c]);
    }
#pragma unroll
    for (int c = 0; c < 16; ++c) m1_sh[lane * 65 + w * 16 + c] = silu_f(acc[c]);
    __syncthreads();

    float acc2[16];
#pragma unroll
    for (int c = 0; c < 16; ++c) acc2[c] = b2[w * 16 + c];
    for (int k = 0; k < 64; ++k) {
        float a = m1_sh[lane * 65 + k];
        const float* wr = W2 + k * 64 + w * 16;
#pragma unroll
        for (int c = 0; c < 16; ++c) acc2[c] = fmaf(a, wr[c], acc2[c]);
    }

    float s1 = 0.f, s2 = 0.f;
#pragma unroll
    for (int c = 0; c < 16; ++c) { s1 += acc2[c]; s2 += acc2[c] * acc2[c]; }
    red_sh[w * 64 + lane] = s1;
    red_sh[256 + w * 64 + lane] = s2;
    __syncthreads();
    float t1 = 0.f, t2 = 0.f;
#pragma unroll
    for (int j = 0; j < 4; ++j) {
        t1 += red_sh[j * 64 + lane];
        t2 += red_sh[256 + j * 64 + lane];
    }
    float mean = t1 * (1.0f / 64.0f);
    float var  = t2 * (1.0f / 64.0f) - mean * mean;
    float rstd = rsqrtf(var + 1e-5f);

    int n = n0 + lane;
    if (n < NN) {
#pragma unroll
        for (int c = 0; c < 16; ++c) {
            int ch = w * 16 + c;
            h[n * 64 + ch] = (acc2[c] - mean) * rstd * g[ch] + be[ch];
        }
    }
}

// ---------------------------------------------------------------------------
// Edge MLP + segmented scatter-add over dst-sorted edges.
// m = LN(silu([h[dst],h[src],ea] @ W1+b1) @ W2+b2); agg[dst] += m.
// Lanes hold 64 consecutive dst-sorted edges -> contiguous equal-dst runs.
// Segmented inclusive scan via shfl_up; last lane of each run does atomics.
// ---------------------------------------------------------------------------
__global__ __launch_bounds__(256) void edge_kernel(
    const float* __restrict__ h,
    const int* __restrict__ sidx, const int* __restrict__ sdst,
    const int* __restrict__ ssrc,
    const float* __restrict__ ea,
    const float* __restrict__ W1, const float* __restrict__ b1,
    const float* __restrict__ W2, const float* __restrict__ b2,
    const float* __restrict__ g, const float* __restrict__ be,
    float* __restrict__ agg)
{
    __shared__ float in_sh[64 * 133];
    __shared__ float m1_sh[64 * 65];
    __shared__ float red_sh[2 * 4 * 64];
    const int lane = threadIdx.x & 63;
    const int w    = threadIdx.x >> 6;
    const int e0   = blockIdx.x * 64;

    for (int i = 0; i < 16; ++i) {
        int slot = w * 16 + i;
        int p = e0 + slot;
        int eid = sidx[p];
        int s = ssrc[p];
        int d = sdst[p];
        in_sh[slot * 133 + lane]      = h[d * 64 + lane];  // xi = h[dst]
        in_sh[slot * 133 + 64 + lane] = h[s * 64 + lane];  // xj = h[src]
        if (lane < 5) in_sh[slot * 133 + 128 + lane] = ea[eid * 5 + lane];
    }
    __syncthreads();

    float acc[16];
#pragma unroll
    for (int c = 0; c < 16; ++c) acc[c] = b1[w * 16 + c];
    for (int k = 0; k < 133; ++k) {
        float a = in_sh[lane * 133 + k];
        const float* wr = W1 + k * 64 + w * 16;
#pragma unroll
        for (int c = 0; c < 16; ++c) acc[c] = fmaf(a, wr[c], acc[c]);
    }
#pragma unroll
    for (int c = 0; c < 16; ++c) m1_sh[lane * 65 + w * 16 + c] = silu_f(acc[c]);
    __syncthreads();

    float acc2[16];
#pragma unroll
    for (int c = 0; c < 16; ++c) acc2[c] = b2[w * 16 + c];
    for (int k = 0; k < 64; ++k) {
        float a = m1_sh[lane * 65 + k];
        const float* wr = W2 + k * 64 + w * 16;
#pragma unroll
        for (int c = 0; c < 16; ++c) acc2[c] = fmaf(a, wr[c], acc2[c]);
    }

    float s1 = 0.f, s2 = 0.f;
#pragma unroll
    for (int c = 0; c < 16; ++c) { s1 += acc2[c]; s2 += acc2[c] * acc2[c]; }
    red_sh[w * 64 + lane] = s1;
    red_sh[256 + w * 64 + lane] = s2;
    __syncthreads();
    float t1 = 0.f, t2 = 0.f;
#pragma unroll
    for (int j = 0; j < 4; ++j) {
        t1 += red_sh[j * 64 + lane];
        t2 += red_sh[256 + j * 64 + lane];
    }
    float mean = t1 * (1.0f / 64.0f);
    float var  = t2 * (1.0f / 64.0f) - mean * mean;
    float rstd = rsqrtf(var + 1e-5f);

    // LN'd per-edge message values for this lane's edge, wave's 16 channels
    float v[16];
#pragma unroll
    for (int c = 0; c < 16; ++c) {
        int ch = w * 16 + c;
        v[c] = (acc2[c] - mean) * rstd * g[ch] + be[ch];
    }

    // segmented inclusive scan across lanes (sorted by dst -> contiguous runs)
    const int d_l = sdst[e0 + lane];
#pragma unroll
    for (int delta = 1; delta < 64; delta <<= 1) {
        int d_up = __shfl_up(d_l, delta);
        bool merge = (lane >= delta) && (d_up == d_l);
#pragma unroll
        for (int c = 0; c < 16; ++c) {
            float vu = __shfl_up(v[c], delta);
            if (merge) v[c] += vu;
        }
    }
    int d_next = __shfl_down(d_l, 1);
    bool last = (lane == 63) || (d_next != d_l);
    if (last) {
#pragma unroll
        for (int c = 0; c < 16; ++c) {
            atomicAdd(&agg[d_l * 64 + w * 16 + c], v[c]);
        }
    }
}

// ---------------------------------------------------------------------------
// Node MLP + residual: h = h + LN(silu([h,agg] @ W1+b1) @ W2+b2)
// ---------------------------------------------------------------------------
__global__ __launch_bounds__(256) void node_kernel(
    float* __restrict__ h, const float* __restrict__ agg,
    const float* __restrict__ W1, const float* __restrict__ b1,
    const float* __restrict__ W2, const float* __restrict__ b2,
    const float* __restrict__ g, const float* __restrict__ be)
{
    __shared__ float in_sh[64 * 129];
    __shared__ float m1_sh[64 * 65];
    __shared__ float red_sh[2 * 4 * 64];
    const int lane = threadIdx.x & 63;
    const int w    = threadIdx.x >> 6;
    const int n0   = blockIdx.x * 64;

    for (int i = 0; i < 16; ++i) {
        int slot = w * 16 + i;
        int n = n0 + slot;
        if (n < NN) {
            in_sh[slot * 129 + lane]      = h[n * 64 + lane];
            in_sh[slot * 129 + 64 + lane] = agg[n * 64 + lane];
        }
    }
    __syncthreads();

    float acc[16];
#pragma unroll
    for (int c = 0; c < 16; ++c) acc[c] = b1[w * 16 + c];
    for (int k = 0; k < 128; ++k) {
        float a = in_sh[lane * 129 + k];
        const float* wr = W1 + k * 64 + w * 16;
#pragma unroll
        for (int c = 0; c < 16; ++c) acc[c] = fmaf(a, wr[c], acc[c]);
    }
#pragma unroll
    for (int c = 0; c < 16; ++c) m1_sh[lane * 65 + w * 16 + c] = silu_f(acc[c]);
    __syncthreads();

    float acc2[16];
#pragma unroll
    for (int c = 0; c < 16; ++c) acc2[c] = b2[w * 16 + c];
    for (int k = 0; k < 64; ++k) {
        float a = m1_sh[lane * 65 + k];
        const float* wr = W2 + k * 64 + w * 16;
#pragma unroll
        for (int c = 0; c < 16; ++c) acc2[c] = fmaf(a, wr[c], acc2[c]);
    }

    float s1 = 0.f, s2 = 0.f;
#pragma unroll
    for (int c = 0; c < 16; ++c) { s1 += acc2[c]; s2 += acc2[c] * acc2[c]; }
    red_sh[w * 64 + lane] = s1;
    red_sh[256 + w * 64 + lane] = s2;
    __syncthreads();
    float t1 = 0.f, t2 = 0.f;
#pragma unroll
    for (int j = 0; j < 4; ++j) {
        t1 += red_sh[j * 64 + lane];
        t2 += red_sh[256 + j * 64 + lane];
    }
    float mean = t1 * (1.0f / 64.0f);
    float var  = t2 * (1.0f / 64.0f) - mean * mean;
    float rstd = rsqrtf(var + 1e-5f);

    int n = n0 + lane;
    if (n < NN) {
#pragma unroll
        for (int c = 0; c < 16; ++c) {
            int ch = w * 16 + c;
            float hv = in_sh[lane * 129 + ch];   // original h (ch < 64)
            h[n * 64 + ch] = hv + (acc2[c] - mean) * rstd * g[ch] + be[ch];
        }
    }
}

// ---------------------------------------------------------------------------
// Local decoder: out_local = silu(h @ W1 + b1) @ W2 + b2  -> [NN, 6]
// ---------------------------------------------------------------------------
__global__ __launch_bounds__(256) void dec_local_kernel(
    const float* __restrict__ h,
    const float* __restrict__ W1, const float* __restrict__ b1,
    const float* __restrict__ W2, const float* __restrict__ b2,
    float* __restrict__ out)
{
    __shared__ float mid_sh[4][64];
    const int lane = threadIdx.x & 63;
    const int w    = threadIdx.x >> 6;
    const int n = blockIdx.x * 4 + w;
    if (n >= NN) return;

    float a = b1[lane];
    for (int k = 0; k < 64; ++k)
        a = fmaf(h[n * 64 + k], W1[k * 64 + lane], a);
    mid_sh[w][lane] = silu_f(a);
    if (lane < 6) {
        float o = b2[lane];
        for (int k = 0; k < 64; ++k)
            o = fmaf(mid_sh[w][k], W2[k * 6 + lane], o);
        out[n * 6 + lane] = o;
    }
}

// ---------------------------------------------------------------------------
// Pooling: pooled[g][c] = sum_{batch[n]==g} h[n][c];  cnt[g] = count
// ---------------------------------------------------------------------------
__global__ __launch_bounds__(256) void pool_kernel(
    const float* __restrict__ h, const int* __restrict__ batch,
    float* __restrict__ pooled, float* __restrict__ cnt)
{
    const int c   = threadIdx.x & 63;
    const int rep = blockIdx.x * 4 + (threadIdx.x >> 6);   // 1024 reps
    float acc[NG] = {0.f, 0.f, 0.f, 0.f};
    float cl[NG]  = {0.f, 0.f, 0.f, 0.f};
    for (int n = rep; n < NN; n += 1024) {
        int b = batch[n];
        float v = h[n * 64 + c];
#pragma unroll
        for (int gph = 0; gph < NG; ++gph) {
            if (b == gph) { acc[gph] += v; cl[gph] += 1.0f; }
        }
    }
#pragma unroll
    for (int gph = 0; gph < NG; ++gph) {
        atomicAdd(&pooled[gph * 64 + c], acc[gph]);
        if (c == 0) atomicAdd(&cnt[gph], cl[gph]);
    }
}

// ---------------------------------------------------------------------------
// Global decoder: out_global = silu(mean_pool @ W1 + b1) @ W2 + b2 -> [4,4]
// ---------------------------------------------------------------------------
__global__ __launch_bounds__(256) void dec_global_kernel(
    const float* __restrict__ pooled, const float* __restrict__ cnt,
    const float* __restrict__ W1, const float* __restrict__ b1,
    const float* __restrict__ W2, const float* __restrict__ b2,
    float* __restrict__ out)
{
    __shared__ float mid_sh[4][32];
    const int lane = threadIdx.x & 63;
    const int gph  = threadIdx.x >> 6;
    float inv = 1.0f / fmaxf(cnt[gph], 1.0f);
    if (lane < 32) {
        float a = b1[lane];
        for (int k = 0; k < 64; ++k)
            a = fmaf(pooled[gph * 64 + k] * inv, W1[k * 32 + lane], a);
        mid_sh[gph][lane] = silu_f(a);
    }
    __syncthreads();
    if (lane < 4) {
        float o = b2[lane];
        for (int k = 0; k < 32; ++k)
            o = fmaf(mid_sh[gph][k], W2[k * 4 + lane], o);
        out[gph * 4 + lane] = o;
    }
}

// ---------------------------------------------------------------------------
extern "C" void kernel_launch(void* const* d_in, const int* in_sizes, int n_in,
                              void* d_out, int out_size, void* d_ws, size_t ws_size,
                              hipStream_t stream)
{
    const float* x      = (const float*)d_in[0];
    const int*   ei     = (const int*)  d_in[1];
    const float* ea     = (const float*)d_in[2];
    const int*   batch  = (const int*)  d_in[3];
    const float* case_p = (const float*)d_in[4];
    const float* bc_p   = (const float*)d_in[5];
    const float* enc_W1 = (const float*)d_in[6];
    const float* enc_b1 = (const float*)d_in[7];
    const float* enc_W2 = (const float*)d_in[8];
    const float* enc_b2 = (const float*)d_in[9];
    const float* enc_g  = (const float*)d_in[10];
    const float* enc_be = (const float*)d_in[11];
    const float* eW1    = (const float*)d_in[12];
    const float* eb1    = (const float*)d_in[13];
    const float* eW2    = (const float*)d_in[14];
    const float* eb2    = (const float*)d_in[15];
    const float* eg     = (const float*)d_in[16];
    const float* ebe    = (const float*)d_in[17];
    const float* nW1    = (const float*)d_in[18];
    const float* nb1    = (const float*)d_in[19];
    const float* nW2    = (const float*)d_in[20];
    const float* nb2    = (const float*)d_in[21];
    const float* ng     = (const float*)d_in[22];
    const float* nbe    = (const float*)d_in[23];
    const float* dlW1   = (const float*)d_in[24];
    const float* dlb1   = (const float*)d_in[25];
    const float* dlW2   = (const float*)d_in[26];
    const float* dlb2   = (const float*)d_in[27];
    const float* dgW1   = (const float*)d_in[28];
    const float* dgb1   = (const float*)d_in[29];
    const float* dgW2   = (const float*)d_in[30];
    const float* dgb2   = (const float*)d_in[31];

    float* out = (float*)d_out;

    char* ws = (char*)d_ws;
    size_t off_b = 0;
    auto alloc = [&](size_t bytes) {
        void* p = ws + off_b;
        off_b = (off_b + bytes + 255) & ~(size_t)255;
        return p;
    };
    const size_t hBytes = (size_t)NN * H * sizeof(float);     // 12.8 MB
    float* h      = (float*)alloc(hBytes);
    float* agg    = (float*)alloc(hBytes);
    float* pooled = (float*)alloc(256 * sizeof(float));
    float* cnt    = (float*)alloc(4 * sizeof(float));
    int*   deg    = (int*)alloc((NN + 1) * sizeof(int));
    int*   offs   = (int*)alloc((NN + 1) * sizeof(int));
    int*   cursor = (int*)alloc((NN + 1) * sizeof(int));
    int*   sidx   = (int*)alloc((size_t)NE * sizeof(int));
    int*   sdst   = (int*)alloc((size_t)NE * sizeof(int));
    int*   ssrc   = (int*)alloc((size_t)NE * sizeof(int));

    hipMemsetAsync(pooled, 0, (256 + 4 + 64) * sizeof(float), stream); // pooled+cnt
    hipMemsetAsync(deg, 0, (NN + 1) * sizeof(int), stream);

    // counting sort of edges by dst (same deterministic work every call)
    degree_kernel<<<(NE + 255) / 256, 256, 0, stream>>>(ei, deg);
    scan_kernel<<<1, 1024, 0, stream>>>(deg, offs, cursor);
    scatter_kernel<<<(NE + 255) / 256, 256, 0, stream>>>(ei, cursor, sidx, sdst, ssrc);

    const int nodeBlocks = (NN + 63) / 64;    // 782
    encoder_kernel<<<nodeBlocks, 256, 0, stream>>>(
        x, batch, case_p, bc_p, enc_W1, enc_b1, enc_W2, enc_b2, enc_g, enc_be, h);

    for (int l = 0; l < NL; ++l) {
        hipMemsetAsync(agg, 0, hBytes, stream);
        edge_kernel<<<NE / 64, 256, 0, stream>>>(
            h, sidx, sdst, ssrc, ea,
            eW1 + (size_t)l * EIN * H, eb1 + l * H,
            eW2 + (size_t)l * H * H,   eb2 + l * H,
            eg + l * H, ebe + l * H, agg);
        node_kernel<<<nodeBlocks, 256, 0, stream>>>(
            h, agg,
            nW1 + (size_t)l * NIN * H, nb1 + l * H,
            nW2 + (size_t)l * H * H,   nb2 + l * H,
            ng + l * H, nbe + l * H);
    }

    dec_local_kernel<<<(NN + 3) / 4, 256, 0, stream>>>(h, dlW1, dlb1, dlW2, dlb2, out);
    pool_kernel<<<256, 256, 0, stream>>>(h, batch, pooled, cnt);
    dec_global_kernel<<<1, 256, 0, stream>>>(pooled, cnt, dgW1, dgb1, dgW2, dgb2,
                                             out + (size_t)NN * 6);
}

// Round 3
// 5798.191 us; speedup vs baseline: 5.1137x; 2.3945x over previous
//
#include <hip/hip_runtime.h>
#include <cmath>

// Problem constants (from reference)
constexpr int NN = 50000;      // nodes
constexpr int NE = 1600000;    // edges
constexpr int H  = 64;         // hidden
constexpr int NL = 5;          // layers
constexpr int NG = 4;          // graphs
constexpr int EIN = 2 * H + 5; // 133
constexpr int NIN = 2 * H;     // 128

__device__ __forceinline__ float silu_f(float x) {
    return x / (1.0f + __expf(-x));
}

// ---------------------------------------------------------------------------
// Counting sort of edges by dst: degree histogram
// ---------------------------------------------------------------------------
__global__ __launch_bounds__(256) void degree_kernel(
    const int* __restrict__ ei, int* __restrict__ deg)
{
    int e = blockIdx.x * 256 + threadIdx.x;
    if (e < NE) atomicAdd(&deg[ei[NE + e]], 1);
}

// Single-block exclusive scan over deg[0..NN) -> off, cursor (copies)
__global__ __launch_bounds__(1024) void scan_kernel(
    const int* __restrict__ deg, int* __restrict__ off, int* __restrict__ cursor)
{
    __shared__ int sh[1024];
    const int tid = threadIdx.x;
    int running = 0;
    for (int base = 0; base < NN; base += 1024) {
        int v = (base + tid < NN) ? deg[base + tid] : 0;
        sh[tid] = v;
        __syncthreads();
        for (int d = 1; d < 1024; d <<= 1) {
            int t = (tid >= d) ? sh[tid - d] : 0;
            __syncthreads();
            sh[tid] += t;
            __syncthreads();
        }
        int excl = sh[tid] - v;
        if (base + tid < NN) {
            off[base + tid] = running + excl;
            cursor[base + tid] = running + excl;
        }
        int total = sh[1023];
        __syncthreads();
        running += total;
    }
    if (tid == 0) off[NN] = running;
}

// Scatter edge ids into dst-sorted order; also record src/dst per sorted slot
__global__ __launch_bounds__(256) void scatter_kernel(
    const int* __restrict__ ei, int* __restrict__ cursor,
    int* __restrict__ sidx, int* __restrict__ sdst, int* __restrict__ ssrc)
{
    int e = blockIdx.x * 256 + threadIdx.x;
    if (e < NE) {
        int d = ei[NE + e];
        int p = atomicAdd(&cursor[d], 1);
        sidx[p] = e;
        sdst[p] = d;
        ssrc[p] = ei[e];
    }
}

// ---------------------------------------------------------------------------
// Encoder: h = LN(silu([x, gv[batch]] @ W1 + b1) @ W2 + b2)
// ---------------------------------------------------------------------------
__global__ __launch_bounds__(256) void encoder_kernel(
    const float* __restrict__ x, const int* __restrict__ batch,
    const float* __restrict__ case_p, const float* __restrict__ bc_p,
    const float* __restrict__ W1, const float* __restrict__ b1,
    const float* __restrict__ W2, const float* __restrict__ b2,
    const float* __restrict__ g, const float* __restrict__ be,
    float* __restrict__ h)
{
    __shared__ float in_sh[64 * 17];
    __shared__ float m1_sh[64 * 65];
    __shared__ float red_sh[2 * 4 * 64];
    const int lane = threadIdx.x & 63;
    const int w    = threadIdx.x >> 6;
    const int wb   = __builtin_amdgcn_readfirstlane(w * 16);  // uniform channel base
    const int n0   = blockIdx.x * 64;

    for (int i = 0; i < 16; ++i) {
        int slot = w * 16 + i;
        int n = n0 + slot;
        if (n < NN && lane < 16) {
            float v;
            if (lane < 8) v = x[n * 8 + lane];
            else {
                int b = batch[n];
                v = (lane < 12) ? case_p[b * 4 + (lane - 8)]
                                : bc_p[b * 4 + (lane - 12)];
            }
            in_sh[slot * 17 + lane] = v;
        }
    }
    __syncthreads();

    float acc[16];
#pragma unroll
    for (int c = 0; c < 16; ++c) acc[c] = b1[wb + c];
    for (int k = 0; k < 16; ++k) {
        float a = in_sh[lane * 17 + k];
        const float4* wr = (const float4*)(W1 + k * 64 + wb);
        float4 w0 = wr[0], w1 = wr[1], w2 = wr[2], w3 = wr[3];
        acc[0]  = fmaf(a, w0.x, acc[0]);  acc[1]  = fmaf(a, w0.y, acc[1]);
        acc[2]  = fmaf(a, w0.z, acc[2]);  acc[3]  = fmaf(a, w0.w, acc[3]);
        acc[4]  = fmaf(a, w1.x, acc[4]);  acc[5]  = fmaf(a, w1.y, acc[5]);
        acc[6]  = fmaf(a, w1.z, acc[6]);  acc[7]  = fmaf(a, w1.w, acc[7]);
        acc[8]  = fmaf(a, w2.x, acc[8]);  acc[9]  = fmaf(a, w2.y, acc[9]);
        acc[10] = fmaf(a, w2.z, acc[10]); acc[11] = fmaf(a, w2.w, acc[11]);
        acc[12] = fmaf(a, w3.x, acc[12]); acc[13] = fmaf(a, w3.y, acc[13]);
        acc[14] = fmaf(a, w3.z, acc[14]); acc[15] = fmaf(a, w3.w, acc[15]);
    }
#pragma unroll
    for (int c = 0; c < 16; ++c) m1_sh[lane * 65 + wb + c] = silu_f(acc[c]);
    __syncthreads();

    float acc2[16];
#pragma unroll
    for (int c = 0; c < 16; ++c) acc2[c] = b2[wb + c];
    for (int k = 0; k < 64; ++k) {
        float a = m1_sh[lane * 65 + k];
        const float4* wr = (const float4*)(W2 + k * 64 + wb);
        float4 w0 = wr[0], w1 = wr[1], w2 = wr[2], w3 = wr[3];
        acc2[0]  = fmaf(a, w0.x, acc2[0]);  acc2[1]  = fmaf(a, w0.y, acc2[1]);
        acc2[2]  = fmaf(a, w0.z, acc2[2]);  acc2[3]  = fmaf(a, w0.w, acc2[3]);
        acc2[4]  = fmaf(a, w1.x, acc2[4]);  acc2[5]  = fmaf(a, w1.y, acc2[5]);
        acc2[6]  = fmaf(a, w1.z, acc2[6]);  acc2[7]  = fmaf(a, w1.w, acc2[7]);
        acc2[8]  = fmaf(a, w2.x, acc2[8]);  acc2[9]  = fmaf(a, w2.y, acc2[9]);
        acc2[10] = fmaf(a, w2.z, acc2[10]); acc2[11] = fmaf(a, w2.w, acc2[11]);
        acc2[12] = fmaf(a, w3.x, acc2[12]); acc2[13] = fmaf(a, w3.y, acc2[13]);
        acc2[14] = fmaf(a, w3.z, acc2[14]); acc2[15] = fmaf(a, w3.w, acc2[15]);
    }

    float s1 = 0.f, s2 = 0.f;
#pragma unroll
    for (int c = 0; c < 16; ++c) { s1 += acc2[c]; s2 += acc2[c] * acc2[c]; }
    red_sh[w * 64 + lane] = s1;
    red_sh[256 + w * 64 + lane] = s2;
    __syncthreads();
    float t1 = 0.f, t2 = 0.f;
#pragma unroll
    for (int j = 0; j < 4; ++j) {
        t1 += red_sh[j * 64 + lane];
        t2 += red_sh[256 + j * 64 + lane];
    }
    float mean = t1 * (1.0f / 64.0f);
    float var  = t2 * (1.0f / 64.0f) - mean * mean;
    float rstd = rsqrtf(var + 1e-5f);

    int n = n0 + lane;
    if (n < NN) {
#pragma unroll
        for (int c = 0; c < 16; ++c) {
            int ch = wb + c;
            h[n * 64 + ch] = (acc2[c] - mean) * rstd * g[ch] + be[ch];
        }
    }
}

// ---------------------------------------------------------------------------
// Edge MLP + segmented scatter-add over dst-sorted edges.
// in_sh reused for mid activations (stride 65) after an extra barrier.
// ---------------------------------------------------------------------------
__global__ __launch_bounds__(256) void edge_kernel(
    const float* __restrict__ h,
    const int* __restrict__ sidx, const int* __restrict__ sdst,
    const int* __restrict__ ssrc,
    const float* __restrict__ ea,
    const float* __restrict__ W1, const float* __restrict__ b1,
    const float* __restrict__ W2, const float* __restrict__ b2,
    const float* __restrict__ g, const float* __restrict__ be,
    float* __restrict__ agg)
{
    __shared__ float in_sh[64 * 133];   // also holds mid acts (stride 65) later
    __shared__ float red_sh[2 * 4 * 64];
    const int lane = threadIdx.x & 63;
    const int w    = threadIdx.x >> 6;
    const int wb   = __builtin_amdgcn_readfirstlane(w * 16);
    const int e0   = blockIdx.x * 64;

    for (int i = 0; i < 16; ++i) {
        int slot = w * 16 + i;
        int p = e0 + slot;
        int eid = sidx[p];
        int s = ssrc[p];
        int d = sdst[p];
        in_sh[slot * 133 + lane]      = h[d * 64 + lane];  // xi = h[dst]
        in_sh[slot * 133 + 64 + lane] = h[s * 64 + lane];  // xj = h[src]
        if (lane < 5) in_sh[slot * 133 + 128 + lane] = ea[eid * 5 + lane];
    }
    __syncthreads();

    float acc[16];
#pragma unroll
    for (int c = 0; c < 16; ++c) acc[c] = b1[wb + c];
    for (int k = 0; k < 133; ++k) {
        float a = in_sh[lane * 133 + k];
        const float4* wr = (const float4*)(W1 + k * 64 + wb);
        float4 w0 = wr[0], w1 = wr[1], w2 = wr[2], w3 = wr[3];
        acc[0]  = fmaf(a, w0.x, acc[0]);  acc[1]  = fmaf(a, w0.y, acc[1]);
        acc[2]  = fmaf(a, w0.z, acc[2]);  acc[3]  = fmaf(a, w0.w, acc[3]);
        acc[4]  = fmaf(a, w1.x, acc[4]);  acc[5]  = fmaf(a, w1.y, acc[5]);
        acc[6]  = fmaf(a, w1.z, acc[6]);  acc[7]  = fmaf(a, w1.w, acc[7]);
        acc[8]  = fmaf(a, w2.x, acc[8]);  acc[9]  = fmaf(a, w2.y, acc[9]);
        acc[10] = fmaf(a, w2.z, acc[10]); acc[11] = fmaf(a, w2.w, acc[11]);
        acc[12] = fmaf(a, w3.x, acc[12]); acc[13] = fmaf(a, w3.y, acc[13]);
        acc[14] = fmaf(a, w3.z, acc[14]); acc[15] = fmaf(a, w3.w, acc[15]);
    }
    __syncthreads();   // everyone done reading in_sh (stride-133 layout)
#pragma unroll
    for (int c = 0; c < 16; ++c) in_sh[lane * 65 + wb + c] = silu_f(acc[c]);
    __syncthreads();

    float acc2[16];
#pragma unroll
    for (int c = 0; c < 16; ++c) acc2[c] = b2[wb + c];
    for (int k = 0; k < 64; ++k) {
        float a = in_sh[lane * 65 + k];
        const float4* wr = (const float4*)(W2 + k * 64 + wb);
        float4 w0 = wr[0], w1 = wr[1], w2 = wr[2], w3 = wr[3];
        acc2[0]  = fmaf(a, w0.x, acc2[0]);  acc2[1]  = fmaf(a, w0.y, acc2[1]);
        acc2[2]  = fmaf(a, w0.z, acc2[2]);  acc2[3]  = fmaf(a, w0.w, acc2[3]);
        acc2[4]  = fmaf(a, w1.x, acc2[4]);  acc2[5]  = fmaf(a, w1.y, acc2[5]);
        acc2[6]  = fmaf(a, w1.z, acc2[6]);  acc2[7]  = fmaf(a, w1.w, acc2[7]);
        acc2[8]  = fmaf(a, w2.x, acc2[8]);  acc2[9]  = fmaf(a, w2.y, acc2[9]);
        acc2[10] = fmaf(a, w2.z, acc2[10]); acc2[11] = fmaf(a, w2.w, acc2[11]);
        acc2[12] = fmaf(a, w3.x, acc2[12]); acc2[13] = fmaf(a, w3.y, acc2[13]);
        acc2[14] = fmaf(a, w3.z, acc2[14]); acc2[15] = fmaf(a, w3.w, acc2[15]);
    }

    float s1 = 0.f, s2 = 0.f;
#pragma unroll
    for (int c = 0; c < 16; ++c) { s1 += acc2[c]; s2 += acc2[c] * acc2[c]; }
    red_sh[w * 64 + lane] = s1;
    red_sh[256 + w * 64 + lane] = s2;
    __syncthreads();
    float t1 = 0.f, t2 = 0.f;
#pragma unroll
    for (int j = 0; j < 4; ++j) {
        t1 += red_sh[j * 64 + lane];
        t2 += red_sh[256 + j * 64 + lane];
    }
    float mean = t1 * (1.0f / 64.0f);
    float var  = t2 * (1.0f / 64.0f) - mean * mean;
    float rstd = rsqrtf(var + 1e-5f);

    float v[16];
#pragma unroll
    for (int c = 0; c < 16; ++c) {
        int ch = wb + c;
        v[c] = (acc2[c] - mean) * rstd * g[ch] + be[ch];
    }

    // segmented inclusive scan across lanes (dst-sorted -> contiguous runs)
    const int d_l = sdst[e0 + lane];
#pragma unroll
    for (int delta = 1; delta < 64; delta <<= 1) {
        int d_up = __shfl_up(d_l, delta);
        bool merge = (lane >= delta) && (d_up == d_l);
#pragma unroll
        for (int c = 0; c < 16; ++c) {
            float vu = __shfl_up(v[c], delta);
            if (merge) v[c] += vu;
        }
    }
    int d_next = __shfl_down(d_l, 1);
    bool last = (lane == 63) || (d_next != d_l);
    if (last) {
#pragma unroll
        for (int c = 0; c < 16; ++c) {
            atomicAdd(&agg[d_l * 64 + wb + c], v[c]);
        }
    }
}

// ---------------------------------------------------------------------------
// Node MLP + residual: h = h + LN(silu([h,agg] @ W1+b1) @ W2+b2)
// in_sh reused for mid activations; residual re-read from global (L2-hot).
// ---------------------------------------------------------------------------
__global__ __launch_bounds__(256) void node_kernel(
    float* __restrict__ h, const float* __restrict__ agg,
    const float* __restrict__ W1, const float* __restrict__ b1,
    const float* __restrict__ W2, const float* __restrict__ b2,
    const float* __restrict__ g, const float* __restrict__ be)
{
    __shared__ float in_sh[64 * 129];
    __shared__ float red_sh[2 * 4 * 64];
    const int lane = threadIdx.x & 63;
    const int w    = threadIdx.x >> 6;
    const int wb   = __builtin_amdgcn_readfirstlane(w * 16);
    const int n0   = blockIdx.x * 64;

    for (int i = 0; i < 16; ++i) {
        int slot = w * 16 + i;
        int n = n0 + slot;
        if (n < NN) {
            in_sh[slot * 129 + lane]      = h[n * 64 + lane];
            in_sh[slot * 129 + 64 + lane] = agg[n * 64 + lane];
        }
    }
    __syncthreads();

    float acc[16];
#pragma unroll
    for (int c = 0; c < 16; ++c) acc[c] = b1[wb + c];
    for (int k = 0; k < 128; ++k) {
        float a = in_sh[lane * 129 + k];
        const float4* wr = (const float4*)(W1 + k * 64 + wb);
        float4 w0 = wr[0], w1 = wr[1], w2 = wr[2], w3 = wr[3];
        acc[0]  = fmaf(a, w0.x, acc[0]);  acc[1]  = fmaf(a, w0.y, acc[1]);
        acc[2]  = fmaf(a, w0.z, acc[2]);  acc[3]  = fmaf(a, w0.w, acc[3]);
        acc[4]  = fmaf(a, w1.x, acc[4]);  acc[5]  = fmaf(a, w1.y, acc[5]);
        acc[6]  = fmaf(a, w1.z, acc[6]);  acc[7]  = fmaf(a, w1.w, acc[7]);
        acc[8]  = fmaf(a, w2.x, acc[8]);  acc[9]  = fmaf(a, w2.y, acc[9]);
        acc[10] = fmaf(a, w2.z, acc[10]); acc[11] = fmaf(a, w2.w, acc[11]);
        acc[12] = fmaf(a, w3.x, acc[12]); acc[13] = fmaf(a, w3.y, acc[13]);
        acc[14] = fmaf(a, w3.z, acc[14]); acc[15] = fmaf(a, w3.w, acc[15]);
    }
    __syncthreads();
#pragma unroll
    for (int c = 0; c < 16; ++c) in_sh[lane * 65 + wb + c] = silu_f(acc[c]);
    __syncthreads();

    float acc2[16];
#pragma unroll
    for (int c = 0; c < 16; ++c) acc2[c] = b2[wb + c];
    for (int k = 0; k < 64; ++k) {
        float a = in_sh[lane * 65 + k];
        const float4* wr = (const float4*)(W2 + k * 64 + wb);
        float4 w0 = wr[0], w1 = wr[1], w2 = wr[2], w3 = wr[3];
        acc2[0]  = fmaf(a, w0.x, acc2[0]);  acc2[1]  = fmaf(a, w0.y, acc2[1]);
        acc2[2]  = fmaf(a, w0.z, acc2[2]);  acc2[3]  = fmaf(a, w0.w, acc2[3]);
        acc2[4]  = fmaf(a, w1.x, acc2[4]);  acc2[5]  = fmaf(a, w1.y, acc2[5]);
        acc2[6]  = fmaf(a, w1.z, acc2[6]);  acc2[7]  = fmaf(a, w1.w, acc2[7]);
        acc2[8]  = fmaf(a, w2.x, acc2[8]);  acc2[9]  = fmaf(a, w2.y, acc2[9]);
        acc2[10] = fmaf(a, w2.z, acc2[10]); acc2[11] = fmaf(a, w2.w, acc2[11]);
        acc2[12] = fmaf(a, w3.x, acc2[12]); acc2[13] = fmaf(a, w3.y, acc2[13]);
        acc2[14] = fmaf(a, w3.z, acc2[14]); acc2[15] = fmaf(a, w3.w, acc2[15]);
    }

    float s1 = 0.f, s2 = 0.f;
#pragma unroll
    for (int c = 0; c < 16; ++c) { s1 += acc2[c]; s2 += acc2[c] * acc2[c]; }
    red_sh[w * 64 + lane] = s1;
    red_sh[256 + w * 64 + lane] = s2;
    __syncthreads();
    float t1 = 0.f, t2 = 0.f;
#pragma unroll
    for (int j = 0; j < 4; ++j) {
        t1 += red_sh[j * 64 + lane];
        t2 += red_sh[256 + j * 64 + lane];
    }
    float mean = t1 * (1.0f / 64.0f);
    float var  = t2 * (1.0f / 64.0f) - mean * mean;
    float rstd = rsqrtf(var + 1e-5f);

    int n = n0 + lane;
    if (n < NN) {
#pragma unroll
        for (int c = 0; c < 16; ++c) {
            int ch = wb + c;
            float hv = h[n * 64 + ch];   // residual (L2-hot re-read)
            h[n * 64 + ch] = hv + (acc2[c] - mean) * rstd * g[ch] + be[ch];
        }
    }
}

// ---------------------------------------------------------------------------
// Local decoder: out_local = silu(h @ W1 + b1) @ W2 + b2  -> [NN, 6]
// ---------------------------------------------------------------------------
__global__ __launch_bounds__(256) void dec_local_kernel(
    const float* __restrict__ h,
    const float* __restrict__ W1, const float* __restrict__ b1,
    const float* __restrict__ W2, const float* __restrict__ b2,
    float* __restrict__ out)
{
    __shared__ float mid_sh[4][64];
    const int lane = threadIdx.x & 63;
    const int w    = threadIdx.x >> 6;
    const int n = blockIdx.x * 4 + w;
    if (n >= NN) return;

    float a = b1[lane];
    for (int k = 0; k < 64; ++k)
        a = fmaf(h[n * 64 + k], W1[k * 64 + lane], a);
    mid_sh[w][lane] = silu_f(a);
    if (lane < 6) {
        float o = b2[lane];
        for (int k = 0; k < 64; ++k)
            o = fmaf(mid_sh[w][k], W2[k * 6 + lane], o);
        out[n * 6 + lane] = o;
    }
}

// ---------------------------------------------------------------------------
// Pooling: pooled[g][c] = sum_{batch[n]==g} h[n][c];  cnt[g] = count
// ---------------------------------------------------------------------------
__global__ __launch_bounds__(256) void pool_kernel(
    const float* __restrict__ h, const int* __restrict__ batch,
    float* __restrict__ pooled, float* __restrict__ cnt)
{
    const int c   = threadIdx.x & 63;
    const int rep = blockIdx.x * 4 + (threadIdx.x >> 6);   // 1024 reps
    float acc[NG] = {0.f, 0.f, 0.f, 0.f};
    float cl[NG]  = {0.f, 0.f, 0.f, 0.f};
    for (int n = rep; n < NN; n += 1024) {
        int b = batch[n];
        float v = h[n * 64 + c];
#pragma unroll
        for (int gph = 0; gph < NG; ++gph) {
            if (b == gph) { acc[gph] += v; cl[gph] += 1.0f; }
        }
    }
#pragma unroll
    for (int gph = 0; gph < NG; ++gph) {
        atomicAdd(&pooled[gph * 64 + c], acc[gph]);
        if (c == 0) atomicAdd(&cnt[gph], cl[gph]);
    }
}

// ---------------------------------------------------------------------------
// Global decoder: out_global = silu(mean_pool @ W1 + b1) @ W2 + b2 -> [4,4]
// ---------------------------------------------------------------------------
__global__ __launch_bounds__(256) void dec_global_kernel(
    const float* __restrict__ pooled, const float* __restrict__ cnt,
    const float* __restrict__ W1, const float* __restrict__ b1,
    const float* __restrict__ W2, const float* __restrict__ b2,
    float* __restrict__ out)
{
    __shared__ float mid_sh[4][32];
    const int lane = threadIdx.x & 63;
    const int gph  = threadIdx.x >> 6;
    float inv = 1.0f / fmaxf(cnt[gph], 1.0f);
    if (lane < 32) {
        float a = b1[lane];
        for (int k = 0; k < 64; ++k)
            a = fmaf(pooled[gph * 64 + k] * inv, W1[k * 32 + lane], a);
        mid_sh[gph][lane] = silu_f(a);
    }
    __syncthreads();
    if (lane < 4) {
        float o = b2[lane];
        for (int k = 0; k < 32; ++k)
            o = fmaf(mid_sh[gph][k], W2[k * 4 + lane], o);
        out[gph * 4 + lane] = o;
    }
}

// ---------------------------------------------------------------------------
extern "C" void kernel_launch(void* const* d_in, const int* in_sizes, int n_in,
                              void* d_out, int out_size, void* d_ws, size_t ws_size,
                              hipStream_t stream)
{
    const float* x      = (const float*)d_in[0];
    const int*   ei     = (const int*)  d_in[1];
    const float* ea     = (const float*)d_in[2];
    const int*   batch  = (const int*)  d_in[3];
    const float* case_p = (const float*)d_in[4];
    const float* bc_p   = (const float*)d_in[5];
    const float* enc_W1 = (const float*)d_in[6];
    const float* enc_b1 = (const float*)d_in[7];
    const float* enc_W2 = (const float*)d_in[8];
    const float* enc_b2 = (const float*)d_in[9];
    const float* enc_g  = (const float*)d_in[10];
    const float* enc_be = (const float*)d_in[11];
    const float* eW1    = (const float*)d_in[12];
    const float* eb1    = (const float*)d_in[13];
    const float* eW2    = (const float*)d_in[14];
    const float* eb2    = (const float*)d_in[15];
    const float* eg     = (const float*)d_in[16];
    const float* ebe    = (const float*)d_in[17];
    const float* nW1    = (const float*)d_in[18];
    const float* nb1    = (const float*)d_in[19];
    const float* nW2    = (const float*)d_in[20];
    const float* nb2    = (const float*)d_in[21];
    const float* ng     = (const float*)d_in[22];
    const float* nbe    = (const float*)d_in[23];
    const float* dlW1   = (const float*)d_in[24];
    const float* dlb1   = (const float*)d_in[25];
    const float* dlW2   = (const float*)d_in[26];
    const float* dlb2   = (const float*)d_in[27];
    const float* dgW1   = (const float*)d_in[28];
    const float* dgb1   = (const float*)d_in[29];
    const float* dgW2   = (const float*)d_in[30];
    const float* dgb2   = (const float*)d_in[31];

    float* out = (float*)d_out;

    char* ws = (char*)d_ws;
    size_t off_b = 0;
    auto alloc = [&](size_t bytes) {
        void* p = ws + off_b;
        off_b = (off_b + bytes + 255) & ~(size_t)255;
        return p;
    };
    const size_t hBytes = (size_t)NN * H * sizeof(float);     // 12.8 MB
    float* h      = (float*)alloc(hBytes);
    float* agg    = (float*)alloc(hBytes);
    float* pooled = (float*)alloc(256 * sizeof(float));
    float* cnt    = (float*)alloc(4 * sizeof(float));
    int*   deg    = (int*)alloc((NN + 1) * sizeof(int));
    int*   offs   = (int*)alloc((NN + 1) * sizeof(int));
    int*   cursor = (int*)alloc((NN + 1) * sizeof(int));
    int*   sidx   = (int*)alloc((size_t)NE * sizeof(int));
    int*   sdst   = (int*)alloc((size_t)NE * sizeof(int));
    int*   ssrc   = (int*)alloc((size_t)NE * sizeof(int));

    hipMemsetAsync(pooled, 0, (256 + 4 + 64) * sizeof(float), stream); // pooled+cnt
    hipMemsetAsync(deg, 0, (NN + 1) * sizeof(int), stream);

    // counting sort of edges by dst (same deterministic work every call)
    degree_kernel<<<(NE + 255) / 256, 256, 0, stream>>>(ei, deg);
    scan_kernel<<<1, 1024, 0, stream>>>(deg, offs, cursor);
    scatter_kernel<<<(NE + 255) / 256, 256, 0, stream>>>(ei, cursor, sidx, sdst, ssrc);

    const int nodeBlocks = (NN + 63) / 64;    // 782
    encoder_kernel<<<nodeBlocks, 256, 0, stream>>>(
        x, batch, case_p, bc_p, enc_W1, enc_b1, enc_W2, enc_b2, enc_g, enc_be, h);

    for (int l = 0; l < NL; ++l) {
        hipMemsetAsync(agg, 0, hBytes, stream);
        edge_kernel<<<NE / 64, 256, 0, stream>>>(
            h, sidx, sdst, ssrc, ea,
            eW1 + (size_t)l * EIN * H, eb1 + l * H,
            eW2 + (size_t)l * H * H,   eb2 + l * H,
            eg + l * H, ebe + l * H, agg);
        node_kernel<<<nodeBlocks, 256, 0, stream>>>(
            h, agg,
            nW1 + (size_t)l * NIN * H, nb1 + l * H,
            nW2 + (size_t)l * H * H,   nb2 + l * H,
            ng + l * H, nbe + l * H);
    }

    dec_local_kernel<<<(NN + 3) / 4, 256, 0, stream>>>(h, dlW1, dlb1, dlW2, dlb2, out);
    pool_kernel<<<256, 256, 0, stream>>>(h, batch, pooled, cnt);
    dec_global_kernel<<<1, 256, 0, stream>>>(pooled, cnt, dgW1, dgb1, dgW2, dgb2,
                                             out + (size_t)NN * 6);
}

// Round 4
// 3740.685 us; speedup vs baseline: 7.9264x; 1.5500x over previous
//
#include <hip/hip_runtime.h>
#include <cmath>

// Problem constants (from reference)
constexpr int NN = 50000;      // nodes
constexpr int NE = 1600000;    // edges
constexpr int H  = 64;         // hidden
constexpr int NL = 5;          // layers
constexpr int NG = 4;          // graphs
constexpr int EIN = 2 * H + 5; // 133
constexpr int NIN = 2 * H;     // 128

__device__ __forceinline__ float silu_f(float x) {
    return x / (1.0f + __expf(-x));
}

// round-to-nearest-even fp32 -> bf16 bits
__device__ __forceinline__ unsigned int f2bf(float f) {
    unsigned int u = __float_as_uint(f);
    u += 0x7fffu + ((u >> 16) & 1u);
    return u >> 16;
}
__device__ __forceinline__ unsigned int pack_bf16x2(float x, float y) {
    return f2bf(x) | (f2bf(y) << 16);
}
__device__ __forceinline__ float2 unpack_bf16x2(unsigned int u) {
    float2 r;
    r.x = __uint_as_float(u << 16);          // first element (low 16)
    r.y = __uint_as_float(u & 0xffff0000u);  // second element (high 16)
    return r;
}

// ---------------------------------------------------------------------------
// Counting sort of edges by dst: degree histogram
// ---------------------------------------------------------------------------
__global__ __launch_bounds__(256) void degree_kernel(
    const int* __restrict__ ei, int* __restrict__ deg)
{
    int e = blockIdx.x * 256 + threadIdx.x;
    if (e < NE) atomicAdd(&deg[ei[NE + e]], 1);
}

// Single-block exclusive scan over deg[0..NN) -> off, cursor (copies)
__global__ __launch_bounds__(1024) void scan_kernel(
    const int* __restrict__ deg, int* __restrict__ off, int* __restrict__ cursor)
{
    __shared__ int sh[1024];
    const int tid = threadIdx.x;
    int running = 0;
    for (int base = 0; base < NN; base += 1024) {
        int v = (base + tid < NN) ? deg[base + tid] : 0;
        sh[tid] = v;
        __syncthreads();
        for (int d = 1; d < 1024; d <<= 1) {
            int t = (tid >= d) ? sh[tid - d] : 0;
            __syncthreads();
            sh[tid] += t;
            __syncthreads();
        }
        int excl = sh[tid] - v;
        if (base + tid < NN) {
            off[base + tid] = running + excl;
            cursor[base + tid] = running + excl;
        }
        int total = sh[1023];
        __syncthreads();
        running += total;
    }
    if (tid == 0) off[NN] = running;
}

// Scatter edge ids into dst-sorted order; also record src/dst per sorted slot
__global__ __launch_bounds__(256) void scatter_kernel(
    const int* __restrict__ ei, int* __restrict__ cursor,
    int* __restrict__ sidx, int* __restrict__ sdst, int* __restrict__ ssrc)
{
    int e = blockIdx.x * 256 + threadIdx.x;
    if (e < NE) {
        int d = ei[NE + e];
        int p = atomicAdd(&cursor[d], 1);
        sidx[p] = e;
        sdst[p] = d;
        ssrc[p] = ei[e];
    }
}

// ---------------------------------------------------------------------------
// Encoder: h = LN(silu([x, gv[batch]] @ W1 + b1) @ W2 + b2)
// ---------------------------------------------------------------------------
__global__ __launch_bounds__(256) void encoder_kernel(
    const float* __restrict__ x, const int* __restrict__ batch,
    const float* __restrict__ case_p, const float* __restrict__ bc_p,
    const float* __restrict__ W1, const float* __restrict__ b1,
    const float* __restrict__ W2, const float* __restrict__ b2,
    const float* __restrict__ g, const float* __restrict__ be,
    float* __restrict__ h)
{
    __shared__ float in_sh[64 * 17];
    __shared__ float m1_sh[64 * 65];
    __shared__ float red_sh[2 * 4 * 64];
    const int lane = threadIdx.x & 63;
    const int w    = threadIdx.x >> 6;
    const int wb   = __builtin_amdgcn_readfirstlane(w * 16);  // uniform channel base
    const int n0   = blockIdx.x * 64;

    for (int i = 0; i < 16; ++i) {
        int slot = w * 16 + i;
        int n = n0 + slot;
        if (n < NN && lane < 16) {
            float v;
            if (lane < 8) v = x[n * 8 + lane];
            else {
                int b = batch[n];
                v = (lane < 12) ? case_p[b * 4 + (lane - 8)]
                                : bc_p[b * 4 + (lane - 12)];
            }
            in_sh[slot * 17 + lane] = v;
        }
    }
    __syncthreads();

    float acc[16];
#pragma unroll
    for (int c = 0; c < 16; ++c) acc[c] = b1[wb + c];
    for (int k = 0; k < 16; ++k) {
        float a = in_sh[lane * 17 + k];
        const float4* wr = (const float4*)(W1 + k * 64 + wb);
        float4 w0 = wr[0], w1 = wr[1], w2 = wr[2], w3 = wr[3];
        acc[0]  = fmaf(a, w0.x, acc[0]);  acc[1]  = fmaf(a, w0.y, acc[1]);
        acc[2]  = fmaf(a, w0.z, acc[2]);  acc[3]  = fmaf(a, w0.w, acc[3]);
        acc[4]  = fmaf(a, w1.x, acc[4]);  acc[5]  = fmaf(a, w1.y, acc[5]);
        acc[6]  = fmaf(a, w1.z, acc[6]);  acc[7]  = fmaf(a, w1.w, acc[7]);
        acc[8]  = fmaf(a, w2.x, acc[8]);  acc[9]  = fmaf(a, w2.y, acc[9]);
        acc[10] = fmaf(a, w2.z, acc[10]); acc[11] = fmaf(a, w2.w, acc[11]);
        acc[12] = fmaf(a, w3.x, acc[12]); acc[13] = fmaf(a, w3.y, acc[13]);
        acc[14] = fmaf(a, w3.z, acc[14]); acc[15] = fmaf(a, w3.w, acc[15]);
    }
#pragma unroll
    for (int c = 0; c < 16; ++c) m1_sh[lane * 65 + wb + c] = silu_f(acc[c]);
    __syncthreads();

    float acc2[16];
#pragma unroll
    for (int c = 0; c < 16; ++c) acc2[c] = b2[wb + c];
    for (int k = 0; k < 64; ++k) {
        float a = m1_sh[lane * 65 + k];
        const float4* wr = (const float4*)(W2 + k * 64 + wb);
        float4 w0 = wr[0], w1 = wr[1], w2 = wr[2], w3 = wr[3];
        acc2[0]  = fmaf(a, w0.x, acc2[0]);  acc2[1]  = fmaf(a, w0.y, acc2[1]);
        acc2[2]  = fmaf(a, w0.z, acc2[2]);  acc2[3]  = fmaf(a, w0.w, acc2[3]);
        acc2[4]  = fmaf(a, w1.x, acc2[4]);  acc2[5]  = fmaf(a, w1.y, acc2[5]);
        acc2[6]  = fmaf(a, w1.z, acc2[6]);  acc2[7]  = fmaf(a, w1.w, acc2[7]);
        acc2[8]  = fmaf(a, w2.x, acc2[8]);  acc2[9]  = fmaf(a, w2.y, acc2[9]);
        acc2[10] = fmaf(a, w2.z, acc2[10]); acc2[11] = fmaf(a, w2.w, acc2[11]);
        acc2[12] = fmaf(a, w3.x, acc2[12]); acc2[13] = fmaf(a, w3.y, acc2[13]);
        acc2[14] = fmaf(a, w3.z, acc2[14]); acc2[15] = fmaf(a, w3.w, acc2[15]);
    }

    float s1 = 0.f, s2 = 0.f;
#pragma unroll
    for (int c = 0; c < 16; ++c) { s1 += acc2[c]; s2 += acc2[c] * acc2[c]; }
    red_sh[w * 64 + lane] = s1;
    red_sh[256 + w * 64 + lane] = s2;
    __syncthreads();
    float t1 = 0.f, t2 = 0.f;
#pragma unroll
    for (int j = 0; j < 4; ++j) {
        t1 += red_sh[j * 64 + lane];
        t2 += red_sh[256 + j * 64 + lane];
    }
    float mean = t1 * (1.0f / 64.0f);
    float var  = t2 * (1.0f / 64.0f) - mean * mean;
    float rstd = rsqrtf(var + 1e-5f);

    int n = n0 + lane;
    if (n < NN) {
#pragma unroll
        for (int c = 0; c < 16; ++c) {
            int ch = wb + c;
            h[n * 64 + ch] = (acc2[c] - mean) * rstd * g[ch] + be[ch];
        }
    }
}

// ---------------------------------------------------------------------------
// Edge MLP + segmented scatter-add over dst-sorted edges.
// Activations staged in LDS as packed bf16x2 (weights/acc/LN/scan stay fp32).
// in_sh rows: 69 u32 words/edge = 138 bf16: k 0..63 = h[dst], 64..127 = h[src],
// 128..132 = ea, 133 = 0 pad. Odd word stride -> conflict-free.
// Mid activations reuse in_sh at 33-word stride (odd -> conflict-free).
// LDS total ~19.7 KB -> 8 blocks/CU.
// ---------------------------------------------------------------------------
__global__ __launch_bounds__(256) void edge_kernel(
    const float* __restrict__ h,
    const int* __restrict__ sidx, const int* __restrict__ sdst,
    const int* __restrict__ ssrc,
    const float* __restrict__ ea,
    const float* __restrict__ W1, const float* __restrict__ b1,
    const float* __restrict__ W2, const float* __restrict__ b2,
    const float* __restrict__ g, const float* __restrict__ be,
    float* __restrict__ agg)
{
    __shared__ unsigned int in_sh[64 * 69];   // 17664 B; also mid acts later
    __shared__ float red_sh[2 * 4 * 64];
    const int lane = threadIdx.x & 63;
    const int w    = threadIdx.x >> 6;
    const int wb   = __builtin_amdgcn_readfirstlane(w * 16);
    const int e0   = blockIdx.x * 64;

    // stage h[dst] (pairs 0..31) with lanes 0..31, h[src] (pairs 32..63) with
    // lanes 32..63; each lane loads float2, packs bf16x2, one ds_write_b32
    for (int i = 0; i < 16; ++i) {
        int slot = w * 16 + i;
        int p = e0 + slot;
        if (lane < 32) {
            int d = sdst[p];
            float2 v = *(const float2*)(h + (size_t)d * 64 + lane * 2);
            in_sh[slot * 69 + lane] = pack_bf16x2(v.x, v.y);
        } else {
            int s = ssrc[p];
            float2 v = *(const float2*)(h + (size_t)s * 64 + (lane - 32) * 2);
            in_sh[slot * 69 + lane] = pack_bf16x2(v.x, v.y);   // words 32..63
        }
    }
    // ea staging: 16 slots x 3 pairs = 48 lanes; pair 2 = (ea4, 0)
    if (lane < 48) {
        int slot = w * 16 + lane / 3;
        int pr   = lane % 3;
        int p    = e0 + slot;
        int eid  = sidx[p];
        float a0 = ea[(size_t)eid * 5 + pr * 2];
        float a1 = (pr < 2) ? ea[(size_t)eid * 5 + pr * 2 + 1] : 0.0f;
        in_sh[slot * 69 + 64 + pr] = pack_bf16x2(a0, a1);
    }
    __syncthreads();

    float acc[16];
#pragma unroll
    for (int c = 0; c < 16; ++c) acc[c] = b1[wb + c];
    for (int j = 0; j < 66; ++j) {           // k = 2j, 2j+1 (0..131)
        float2 a2 = unpack_bf16x2(in_sh[lane * 69 + j]);
        const float4* wr0 = (const float4*)(W1 + (2 * j) * 64 + wb);
        const float4* wr1 = (const float4*)(W1 + (2 * j + 1) * 64 + wb);
        float4 u0 = wr0[0], u1 = wr0[1], u2 = wr0[2], u3 = wr0[3];
        float4 v0 = wr1[0], v1 = wr1[1], v2 = wr1[2], v3 = wr1[3];
        float a = a2.x, b = a2.y;
        acc[0]  = fmaf(a, u0.x, acc[0]);  acc[0]  = fmaf(b, v0.x, acc[0]);
        acc[1]  = fmaf(a, u0.y, acc[1]);  acc[1]  = fmaf(b, v0.y, acc[1]);
        acc[2]  = fmaf(a, u0.z, acc[2]);  acc[2]  = fmaf(b, v0.z, acc[2]);
        acc[3]  = fmaf(a, u0.w, acc[3]);  acc[3]  = fmaf(b, v0.w, acc[3]);
        acc[4]  = fmaf(a, u1.x, acc[4]);  acc[4]  = fmaf(b, v1.x, acc[4]);
        acc[5]  = fmaf(a, u1.y, acc[5]);  acc[5]  = fmaf(b, v1.y, acc[5]);
        acc[6]  = fmaf(a, u1.z, acc[6]);  acc[6]  = fmaf(b, v1.z, acc[6]);
        acc[7]  = fmaf(a, u1.w, acc[7]);  acc[7]  = fmaf(b, v1.w, acc[7]);
        acc[8]  = fmaf(a, u2.x, acc[8]);  acc[8]  = fmaf(b, v2.x, acc[8]);
        acc[9]  = fmaf(a, u2.y, acc[9]);  acc[9]  = fmaf(b, v2.y, acc[9]);
        acc[10] = fmaf(a, u2.z, acc[10]); acc[10] = fmaf(b, v2.z, acc[10]);
        acc[11] = fmaf(a, u2.w, acc[11]); acc[11] = fmaf(b, v2.w, acc[11]);
        acc[12] = fmaf(a, u3.x, acc[12]); acc[12] = fmaf(b, v3.x, acc[12]);
        acc[13] = fmaf(a, u3.y, acc[13]); acc[13] = fmaf(b, v3.y, acc[13]);
        acc[14] = fmaf(a, u3.z, acc[14]); acc[14] = fmaf(b, v3.z, acc[14]);
        acc[15] = fmaf(a, u3.w, acc[15]); acc[15] = fmaf(b, v3.w, acc[15]);
    }
    {   // tail k = 132 (pair word 66; high half is the zero pad)
        float2 a2 = unpack_bf16x2(in_sh[lane * 69 + 66]);
        const float4* wr = (const float4*)(W1 + 132 * 64 + wb);
        float4 w0 = wr[0], w1 = wr[1], w2 = wr[2], w3 = wr[3];
        float a = a2.x;
        acc[0]  = fmaf(a, w0.x, acc[0]);  acc[1]  = fmaf(a, w0.y, acc[1]);
        acc[2]  = fmaf(a, w0.z, acc[2]);  acc[3]  = fmaf(a, w0.w, acc[3]);
        acc[4]  = fmaf(a, w1.x, acc[4]);  acc[5]  = fmaf(a, w1.y, acc[5]);
        acc[6]  = fmaf(a, w1.z, acc[6]);  acc[7]  = fmaf(a, w1.w, acc[7]);
        acc[8]  = fmaf(a, w2.x, acc[8]);  acc[9]  = fmaf(a, w2.y, acc[9]);
        acc[10] = fmaf(a, w2.z, acc[10]); acc[11] = fmaf(a, w2.w, acc[11]);
        acc[12] = fmaf(a, w3.x, acc[12]); acc[13] = fmaf(a, w3.y, acc[13]);
        acc[14] = fmaf(a, w3.z, acc[14]); acc[15] = fmaf(a, w3.w, acc[15]);
    }
    __syncthreads();   // done reading stride-69 layout
    // mid acts: bf16x2, stride 33 words/edge (odd -> conflict-free)
#pragma unroll
    for (int c = 0; c < 16; c += 2) {
        in_sh[lane * 33 + (wb + c) / 2] =
            pack_bf16x2(silu_f(acc[c]), silu_f(acc[c + 1]));
    }
    __syncthreads();

    float acc2[16];
#pragma unroll
    for (int c = 0; c < 16; ++c) acc2[c] = b2[wb + c];
    for (int j = 0; j < 32; ++j) {           // k = 2j, 2j+1 (0..63)
        float2 a2 = unpack_bf16x2(in_sh[lane * 33 + j]);
        const float4* wr0 = (const float4*)(W2 + (2 * j) * 64 + wb);
        const float4* wr1 = (const float4*)(W2 + (2 * j + 1) * 64 + wb);
        float4 u0 = wr0[0], u1 = wr0[1], u2 = wr0[2], u3 = wr0[3];
        float4 v0 = wr1[0], v1 = wr1[1], v2 = wr1[2], v3 = wr1[3];
        float a = a2.x, b = a2.y;
        acc2[0]  = fmaf(a, u0.x, acc2[0]);  acc2[0]  = fmaf(b, v0.x, acc2[0]);
        acc2[1]  = fmaf(a, u0.y, acc2[1]);  acc2[1]  = fmaf(b, v0.y, acc2[1]);
        acc2[2]  = fmaf(a, u0.z, acc2[2]);  acc2[2]  = fmaf(b, v0.z, acc2[2]);
        acc2[3]  = fmaf(a, u0.w, acc2[3]);  acc2[3]  = fmaf(b, v0.w, acc2[3]);
        acc2[4]  = fmaf(a, u1.x, acc2[4]);  acc2[4]  = fmaf(b, v1.x, acc2[4]);
        acc2[5]  = fmaf(a, u1.y, acc2[5]);  acc2[5]  = fmaf(b, v1.y, acc2[5]);
        acc2[6]  = fmaf(a, u1.z, acc2[6]);  acc2[6]  = fmaf(b, v1.z, acc2[6]);
        acc2[7]  = fmaf(a, u1.w, acc2[7]);  acc2[7]  = fmaf(b, v1.w, acc2[7]);
        acc2[8]  = fmaf(a, u2.x, acc2[8]);  acc2[8]  = fmaf(b, v2.x, acc2[8]);
        acc2[9]  = fmaf(a, u2.y, acc2[9]);  acc2[9]  = fmaf(b, v2.y, acc2[9]);
        acc2[10] = fmaf(a, u2.z, acc2[10]); acc2[10] = fmaf(b, v2.z, acc2[10]);
        acc2[11] = fmaf(a, u2.w, acc2[11]); acc2[11] = fmaf(b, v2.w, acc2[11]);
        acc2[12] = fmaf(a, u3.x, acc2[12]); acc2[12] = fmaf(b, v3.x, acc2[12]);
        acc2[13] = fmaf(a, u3.y, acc2[13]); acc2[13] = fmaf(b, v3.y, acc2[13]);
        acc2[14] = fmaf(a, u3.z, acc2[14]); acc2[14] = fmaf(b, v3.z, acc2[14]);
        acc2[15] = fmaf(a, u3.w, acc2[15]); acc2[15] = fmaf(b, v3.w, acc2[15]);
    }

    float s1 = 0.f, s2 = 0.f;
#pragma unroll
    for (int c = 0; c < 16; ++c) { s1 += acc2[c]; s2 += acc2[c] * acc2[c]; }
    red_sh[w * 64 + lane] = s1;
    red_sh[256 + w * 64 + lane] = s2;
    __syncthreads();
    float t1 = 0.f, t2 = 0.f;
#pragma unroll
    for (int j = 0; j < 4; ++j) {
        t1 += red_sh[j * 64 + lane];
        t2 += red_sh[256 + j * 64 + lane];
    }
    float mean = t1 * (1.0f / 64.0f);
    float var  = t2 * (1.0f / 64.0f) - mean * mean;
    float rstd = rsqrtf(var + 1e-5f);

    float v[16];
#pragma unroll
    for (int c = 0; c < 16; ++c) {
        int ch = wb + c;
        v[c] = (acc2[c] - mean) * rstd * g[ch] + be[ch];
    }

    // segmented inclusive scan across lanes (dst-sorted -> contiguous runs)
    const int d_l = sdst[e0 + lane];
#pragma unroll
    for (int delta = 1; delta < 64; delta <<= 1) {
        int d_up = __shfl_up(d_l, delta);
        bool merge = (lane >= delta) && (d_up == d_l);
#pragma unroll
        for (int c = 0; c < 16; ++c) {
            float vu = __shfl_up(v[c], delta);
            if (merge) v[c] += vu;
        }
    }
    int d_next = __shfl_down(d_l, 1);
    bool last = (lane == 63) || (d_next != d_l);
    if (last) {
#pragma unroll
        for (int c = 0; c < 16; ++c) {
            atomicAdd(&agg[d_l * 64 + wb + c], v[c]);
        }
    }
}

// ---------------------------------------------------------------------------
// Node MLP + residual: h = h + LN(silu([h,agg] @ W1+b1) @ W2+b2)
// ---------------------------------------------------------------------------
__global__ __launch_bounds__(256) void node_kernel(
    float* __restrict__ h, const float* __restrict__ agg,
    const float* __restrict__ W1, const float* __restrict__ b1,
    const float* __restrict__ W2, const float* __restrict__ b2,
    const float* __restrict__ g, const float* __restrict__ be)
{
    __shared__ float in_sh[64 * 129];
    __shared__ float red_sh[2 * 4 * 64];
    const int lane = threadIdx.x & 63;
    const int w    = threadIdx.x >> 6;
    const int wb   = __builtin_amdgcn_readfirstlane(w * 16);
    const int n0   = blockIdx.x * 64;

    for (int i = 0; i < 16; ++i) {
        int slot = w * 16 + i;
        int n = n0 + slot;
        if (n < NN) {
            in_sh[slot * 129 + lane]      = h[n * 64 + lane];
            in_sh[slot * 129 + 64 + lane] = agg[n * 64 + lane];
        }
    }
    __syncthreads();

    float acc[16];
#pragma unroll
    for (int c = 0; c < 16; ++c) acc[c] = b1[wb + c];
    for (int k = 0; k < 128; ++k) {
        float a = in_sh[lane * 129 + k];
        const float4* wr = (const float4*)(W1 + k * 64 + wb);
        float4 w0 = wr[0], w1 = wr[1], w2 = wr[2], w3 = wr[3];
        acc[0]  = fmaf(a, w0.x, acc[0]);  acc[1]  = fmaf(a, w0.y, acc[1]);
        acc[2]  = fmaf(a, w0.z, acc[2]);  acc[3]  = fmaf(a, w0.w, acc[3]);
        acc[4]  = fmaf(a, w1.x, acc[4]);  acc[5]  = fmaf(a, w1.y, acc[5]);
        acc[6]  = fmaf(a, w1.z, acc[6]);  acc[7]  = fmaf(a, w1.w, acc[7]);
        acc[8]  = fmaf(a, w2.x, acc[8]);  acc[9]  = fmaf(a, w2.y, acc[9]);
        acc[10] = fmaf(a, w2.z, acc[10]); acc[11] = fmaf(a, w2.w, acc[11]);
        acc[12] = fmaf(a, w3.x, acc[12]); acc[13] = fmaf(a, w3.y, acc[13]);
        acc[14] = fmaf(a, w3.z, acc[14]); acc[15] = fmaf(a, w3.w, acc[15]);
    }
    __syncthreads();
#pragma unroll
    for (int c = 0; c < 16; ++c) in_sh[lane * 65 + wb + c] = silu_f(acc[c]);
    __syncthreads();

    float acc2[16];
#pragma unroll
    for (int c = 0; c < 16; ++c) acc2[c] = b2[wb + c];
    for (int k = 0; k < 64; ++k) {
        float a = in_sh[lane * 65 + k];
        const float4* wr = (const float4*)(W2 + k * 64 + wb);
        float4 w0 = wr[0], w1 = wr[1], w2 = wr[2], w3 = wr[3];
        acc2[0]  = fmaf(a, w0.x, acc2[0]);  acc2[1]  = fmaf(a, w0.y, acc2[1]);
        acc2[2]  = fmaf(a, w0.z, acc2[2]);  acc2[3]  = fmaf(a, w0.w, acc2[3]);
        acc2[4]  = fmaf(a, w1.x, acc2[4]);  acc2[5]  = fmaf(a, w1.y, acc2[5]);
        acc2[6]  = fmaf(a, w1.z, acc2[6]);  acc2[7]  = fmaf(a, w1.w, acc2[7]);
        acc2[8]  = fmaf(a, w2.x, acc2[8]);  acc2[9]  = fmaf(a, w2.y, acc2[9]);
        acc2[10] = fmaf(a, w2.z, acc2[10]); acc2[11] = fmaf(a, w2.w, acc2[11]);
        acc2[12] = fmaf(a, w3.x, acc2[12]); acc2[13] = fmaf(a, w3.y, acc2[13]);
        acc2[14] = fmaf(a, w3.z, acc2[14]); acc2[15] = fmaf(a, w3.w, acc2[15]);
    }

    float s1 = 0.f, s2 = 0.f;
#pragma unroll
    for (int c = 0; c < 16; ++c) { s1 += acc2[c]; s2 += acc2[c] * acc2[c]; }
    red_sh[w * 64 + lane] = s1;
    red_sh[256 + w * 64 + lane] = s2;
    __syncthreads();
    float t1 = 0.f, t2 = 0.f;
#pragma unroll
    for (int j = 0; j < 4; ++j) {
        t1 += red_sh[j * 64 + lane];
        t2 += red_sh[256 + j * 64 + lane];
    }
    float mean = t1 * (1.0f / 64.0f);
    float var  = t2 * (1.0f / 64.0f) - mean * mean;
    float rstd = rsqrtf(var + 1e-5f);

    int n = n0 + lane;
    if (n < NN) {
#pragma unroll
        for (int c = 0; c < 16; ++c) {
            int ch = wb + c;
            float hv = h[n * 64 + ch];   // residual (L2-hot re-read)
            h[n * 64 + ch] = hv + (acc2[c] - mean) * rstd * g[ch] + be[ch];
        }
    }
}

// ---------------------------------------------------------------------------
// Local decoder: out_local = silu(h @ W1 + b1) @ W2 + b2  -> [NN, 6]
// ---------------------------------------------------------------------------
__global__ __launch_bounds__(256) void dec_local_kernel(
    const float* __restrict__ h,
    const float* __restrict__ W1, const float* __restrict__ b1,
    const float* __restrict__ W2, const float* __restrict__ b2,
    float* __restrict__ out)
{
    __shared__ float mid_sh[4][64];
    const int lane = threadIdx.x & 63;
    const int w    = threadIdx.x >> 6;
    const int n = blockIdx.x * 4 + w;
    if (n >= NN) return;

    float a = b1[lane];
    for (int k = 0; k < 64; ++k)
        a = fmaf(h[n * 64 + k], W1[k * 64 + lane], a);
    mid_sh[w][lane] = silu_f(a);
    if (lane < 6) {
        float o = b2[lane];
        for (int k = 0; k < 64; ++k)
            o = fmaf(mid_sh[w][k], W2[k * 6 + lane], o);
        out[n * 6 + lane] = o;
    }
}

// ---------------------------------------------------------------------------
// Pooling: pooled[g][c] = sum_{batch[n]==g} h[n][c];  cnt[g] = count
// ---------------------------------------------------------------------------
__global__ __launch_bounds__(256) void pool_kernel(
    const float* __restrict__ h, const int* __restrict__ batch,
    float* __restrict__ pooled, float* __restrict__ cnt)
{
    const int c   = threadIdx.x & 63;
    const int rep = blockIdx.x * 4 + (threadIdx.x >> 6);   // 1024 reps
    float acc[NG] = {0.f, 0.f, 0.f, 0.f};
    float cl[NG]  = {0.f, 0.f, 0.f, 0.f};
    for (int n = rep; n < NN; n += 1024) {
        int b = batch[n];
        float v = h[n * 64 + c];
#pragma unroll
        for (int gph = 0; gph < NG; ++gph) {
            if (b == gph) { acc[gph] += v; cl[gph] += 1.0f; }
        }
    }
#pragma unroll
    for (int gph = 0; gph < NG; ++gph) {
        atomicAdd(&pooled[gph * 64 + c], acc[gph]);
        if (c == 0) atomicAdd(&cnt[gph], cl[gph]);
    }
}

// ---------------------------------------------------------------------------
// Global decoder: out_global = silu(mean_pool @ W1 + b1) @ W2 + b2 -> [4,4]
// ---------------------------------------------------------------------------
__global__ __launch_bounds__(256) void dec_global_kernel(
    const float* __restrict__ pooled, const float* __restrict__ cnt,
    const float* __restrict__ W1, const float* __restrict__ b1,
    const float* __restrict__ W2, const float* __restrict__ b2,
    float* __restrict__ out)
{
    __shared__ float mid_sh[4][32];
    const int lane = threadIdx.x & 63;
    const int gph  = threadIdx.x >> 6;
    float inv = 1.0f / fmaxf(cnt[gph], 1.0f);
    if (lane < 32) {
        float a = b1[lane];
        for (int k = 0; k < 64; ++k)
            a = fmaf(pooled[gph * 64 + k] * inv, W1[k * 32 + lane], a);
        mid_sh[gph][lane] = silu_f(a);
    }
    __syncthreads();
    if (lane < 4) {
        float o = b2[lane];
        for (int k = 0; k < 32; ++k)
            o = fmaf(mid_sh[gph][k], W2[k * 4 + lane], o);
        out[gph * 4 + lane] = o;
    }
}

// ---------------------------------------------------------------------------
extern "C" void kernel_launch(void* const* d_in, const int* in_sizes, int n_in,
                              void* d_out, int out_size, void* d_ws, size_t ws_size,
                              hipStream_t stream)
{
    const float* x      = (const float*)d_in[0];
    const int*   ei     = (const int*)  d_in[1];
    const float* ea     = (const float*)d_in[2];
    const int*   batch  = (const int*)  d_in[3];
    const float* case_p = (const float*)d_in[4];
    const float* bc_p   = (const float*)d_in[5];
    const float* enc_W1 = (const float*)d_in[6];
    const float* enc_b1 = (const float*)d_in[7];
    const float* enc_W2 = (const float*)d_in[8];
    const float* enc_b2 = (const float*)d_in[9];
    const float* enc_g  = (const float*)d_in[10];
    const float* enc_be = (const float*)d_in[11];
    const float* eW1    = (const float*)d_in[12];
    const float* eb1    = (const float*)d_in[13];
    const float* eW2    = (const float*)d_in[14];
    const float* eb2    = (const float*)d_in[15];
    const float* eg     = (const float*)d_in[16];
    const float* ebe    = (const float*)d_in[17];
    const float* nW1    = (const float*)d_in[18];
    const float* nb1    = (const float*)d_in[19];
    const float* nW2    = (const float*)d_in[20];
    const float* nb2    = (const float*)d_in[21];
    const float* ng     = (const float*)d_in[22];
    const float* nbe    = (const float*)d_in[23];
    const float* dlW1   = (const float*)d_in[24];
    const float* dlb1   = (const float*)d_in[25];
    const float* dlW2   = (const float*)d_in[26];
    const float* dlb2   = (const float*)d_in[27];
    const float* dgW1   = (const float*)d_in[28];
    const float* dgb1   = (const float*)d_in[29];
    const float* dgW2   = (const float*)d_in[30];
    const float* dgb2   = (const float*)d_in[31];

    float* out = (float*)d_out;

    char* ws = (char*)d_ws;
    size_t off_b = 0;
    auto alloc = [&](size_t bytes) {
        void* p = ws + off_b;
        off_b = (off_b + bytes + 255) & ~(size_t)255;
        return p;
    };
    const size_t hBytes = (size_t)NN * H * sizeof(float);     // 12.8 MB
    float* h      = (float*)alloc(hBytes);
    float* agg    = (float*)alloc(hBytes);
    float* pooled = (float*)alloc(256 * sizeof(float));
    float* cnt    = (float*)alloc(4 * sizeof(float));
    int*   deg    = (int*)alloc((NN + 1) * sizeof(int));
    int*   offs   = (int*)alloc((NN + 1) * sizeof(int));
    int*   cursor = (int*)alloc((NN + 1) * sizeof(int));
    int*   sidx   = (int*)alloc((size_t)NE * sizeof(int));
    int*   sdst   = (int*)alloc((size_t)NE * sizeof(int));
    int*   ssrc   = (int*)alloc((size_t)NE * sizeof(int));

    hipMemsetAsync(pooled, 0, (256 + 4 + 64) * sizeof(float), stream); // pooled+cnt
    hipMemsetAsync(deg, 0, (NN + 1) * sizeof(int), stream);

    // counting sort of edges by dst (same deterministic work every call)
    degree_kernel<<<(NE + 255) / 256, 256, 0, stream>>>(ei, deg);
    scan_kernel<<<1, 1024, 0, stream>>>(deg, offs, cursor);
    scatter_kernel<<<(NE + 255) / 256, 256, 0, stream>>>(ei, cursor, sidx, sdst, ssrc);

    const int nodeBlocks = (NN + 63) / 64;    // 782
    encoder_kernel<<<nodeBlocks, 256, 0, stream>>>(
        x, batch, case_p, bc_p, enc_W1, enc_b1, enc_W2, enc_b2, enc_g, enc_be, h);

    for (int l = 0; l < NL; ++l) {
        hipMemsetAsync(agg, 0, hBytes, stream);
        edge_kernel<<<NE / 64, 256, 0, stream>>>(
            h, sidx, sdst, ssrc, ea,
            eW1 + (size_t)l * EIN * H, eb1 + l * H,
            eW2 + (size_t)l * H * H,   eb2 + l * H,
            eg + l * H, ebe + l * H, agg);
        node_kernel<<<nodeBlocks, 256, 0, stream>>>(
            h, agg,
            nW1 + (size_t)l * NIN * H, nb1 + l * H,
            nW2 + (size_t)l * H * H,   nb2 + l * H,
            ng + l * H, nbe + l * H);
    }

    dec_local_kernel<<<(NN + 3) / 4, 256, 0, stream>>>(h, dlW1, dlb1, dlW2, dlb2, out);
    pool_kernel<<<256, 256, 0, stream>>>(h, batch, pooled, cnt);
    dec_global_kernel<<<1, 256, 0, stream>>>(pooled, cnt, dgW1, dgb1, dgW2, dgb2,
                                             out + (size_t)NN * 6);
}

// Round 5
// 3268.645 us; speedup vs baseline: 9.0711x; 1.1444x over previous
//
#include <hip/hip_runtime.h>
#include <cmath>

// Problem constants (from reference)
constexpr int NN = 50000;      // nodes
constexpr int NE = 1600000;    // edges
constexpr int H  = 64;         // hidden
constexpr int NL = 5;          // layers
constexpr int NG = 4;          // graphs
constexpr int EIN = 2 * H + 5; // 133
constexpr int NIN = 2 * H;     // 128

typedef short bf16x8 __attribute__((ext_vector_type(8)));
typedef float f32x4  __attribute__((ext_vector_type(4)));

__device__ __forceinline__ float silu_f(float x) {
    return x / (1.0f + __expf(-x));
}

// round-to-nearest-even fp32 -> bf16 bits
__device__ __forceinline__ unsigned int f2bf(float f) {
    unsigned int u = __float_as_uint(f);
    u += 0x7fffu + ((u >> 16) & 1u);
    return u >> 16;
}
__device__ __forceinline__ unsigned int pack_bf16x2(float x, float y) {
    return f2bf(x) | (f2bf(y) << 16);
}

// ---------------------------------------------------------------------------
// Counting sort of edges by dst: degree histogram
// ---------------------------------------------------------------------------
__global__ __launch_bounds__(256) void degree_kernel(
    const int* __restrict__ ei, int* __restrict__ deg)
{
    int e = blockIdx.x * 256 + threadIdx.x;
    if (e < NE) atomicAdd(&deg[ei[NE + e]], 1);
}

// Single-block exclusive scan over deg[0..NN) -> off, cursor (copies)
__global__ __launch_bounds__(1024) void scan_kernel(
    const int* __restrict__ deg, int* __restrict__ off, int* __restrict__ cursor)
{
    __shared__ int sh[1024];
    const int tid = threadIdx.x;
    int running = 0;
    for (int base = 0; base < NN; base += 1024) {
        int v = (base + tid < NN) ? deg[base + tid] : 0;
        sh[tid] = v;
        __syncthreads();
        for (int d = 1; d < 1024; d <<= 1) {
            int t = (tid >= d) ? sh[tid - d] : 0;
            __syncthreads();
            sh[tid] += t;
            __syncthreads();
        }
        int excl = sh[tid] - v;
        if (base + tid < NN) {
            off[base + tid] = running + excl;
            cursor[base + tid] = running + excl;
        }
        int total = sh[1023];
        __syncthreads();
        running += total;
    }
    if (tid == 0) off[NN] = running;
}

// Scatter edge ids into dst-sorted order; also record src/dst per sorted slot
__global__ __launch_bounds__(256) void scatter_kernel(
    const int* __restrict__ ei, int* __restrict__ cursor,
    int* __restrict__ sidx, int* __restrict__ sdst, int* __restrict__ ssrc)
{
    int e = blockIdx.x * 256 + threadIdx.x;
    if (e < NE) {
        int d = ei[NE + e];
        int p = atomicAdd(&cursor[d], 1);
        sidx[p] = e;
        sdst[p] = d;
        ssrc[p] = ei[e];
    }
}

// ---------------------------------------------------------------------------
// Pre-pack edge-MLP weights into MFMA A-fragment order, bf16.
// A = W^T: A[m=ch_out][k]. Fragment: elem (ks, mt, lane, j) =
//   W[k = ks*32 + (lane>>4)*8 + j][ch = mt*16 + (lane&15)]  (0 if k >= K_real)
// W1: K padded 133->160 (5 ks), W2: K=64 (2 ks). Per layer: 10240 / 4096 shorts.
// ---------------------------------------------------------------------------
__global__ __launch_bounds__(256) void pack_weights_kernel(
    const float* __restrict__ eW1, const float* __restrict__ eW2,
    short* __restrict__ W1pk, short* __restrict__ W2pk)
{
    int l = blockIdx.y;
    int t = blockIdx.x * 256 + threadIdx.x;   // 0..14335
    if (t < 10240) {
        int j = t & 7, lane = (t >> 3) & 63, mt = (t >> 9) & 3, ks = t >> 11;
        int k  = ks * 32 + (lane >> 4) * 8 + j;
        int ch = mt * 16 + (lane & 15);
        float v = (k < EIN) ? eW1[(size_t)l * EIN * H + k * H + ch] : 0.0f;
        W1pk[(size_t)l * 10240 + t] = (short)f2bf(v);
    } else if (t < 10240 + 4096) {
        int t2 = t - 10240;
        int j = t2 & 7, lane = (t2 >> 3) & 63, mt = (t2 >> 9) & 3, ks = t2 >> 11;
        int k = ks * 32 + (lane >> 4) * 8 + j;
        int m = mt * 16 + (lane & 15);
        float v = eW2[(size_t)l * H * H + k * H + m];
        W2pk[(size_t)l * 4096 + t2] = (short)f2bf(v);
    }
}

// ---------------------------------------------------------------------------
// Encoder: h = LN(silu([x, gv[batch]] @ W1 + b1) @ W2 + b2)
// ---------------------------------------------------------------------------
__global__ __launch_bounds__(256) void encoder_kernel(
    const float* __restrict__ x, const int* __restrict__ batch,
    const float* __restrict__ case_p, const float* __restrict__ bc_p,
    const float* __restrict__ W1, const float* __restrict__ b1,
    const float* __restrict__ W2, const float* __restrict__ b2,
    const float* __restrict__ g, const float* __restrict__ be,
    float* __restrict__ h)
{
    __shared__ float in_sh[64 * 17];
    __shared__ float m1_sh[64 * 65];
    __shared__ float red_sh[2 * 4 * 64];
    const int lane = threadIdx.x & 63;
    const int w    = threadIdx.x >> 6;
    const int wb   = __builtin_amdgcn_readfirstlane(w * 16);
    const int n0   = blockIdx.x * 64;

    for (int i = 0; i < 16; ++i) {
        int slot = w * 16 + i;
        int n = n0 + slot;
        if (n < NN && lane < 16) {
            float v;
            if (lane < 8) v = x[n * 8 + lane];
            else {
                int b = batch[n];
                v = (lane < 12) ? case_p[b * 4 + (lane - 8)]
                                : bc_p[b * 4 + (lane - 12)];
            }
            in_sh[slot * 17 + lane] = v;
        }
    }
    __syncthreads();

    float acc[16];
#pragma unroll
    for (int c = 0; c < 16; ++c) acc[c] = b1[wb + c];
    for (int k = 0; k < 16; ++k) {
        float a = in_sh[lane * 17 + k];
        const float4* wr = (const float4*)(W1 + k * 64 + wb);
        float4 w0 = wr[0], w1 = wr[1], w2 = wr[2], w3 = wr[3];
        acc[0]  = fmaf(a, w0.x, acc[0]);  acc[1]  = fmaf(a, w0.y, acc[1]);
        acc[2]  = fmaf(a, w0.z, acc[2]);  acc[3]  = fmaf(a, w0.w, acc[3]);
        acc[4]  = fmaf(a, w1.x, acc[4]);  acc[5]  = fmaf(a, w1.y, acc[5]);
        acc[6]  = fmaf(a, w1.z, acc[6]);  acc[7]  = fmaf(a, w1.w, acc[7]);
        acc[8]  = fmaf(a, w2.x, acc[8]);  acc[9]  = fmaf(a, w2.y, acc[9]);
        acc[10] = fmaf(a, w2.z, acc[10]); acc[11] = fmaf(a, w2.w, acc[11]);
        acc[12] = fmaf(a, w3.x, acc[12]); acc[13] = fmaf(a, w3.y, acc[13]);
        acc[14] = fmaf(a, w3.z, acc[14]); acc[15] = fmaf(a, w3.w, acc[15]);
    }
#pragma unroll
    for (int c = 0; c < 16; ++c) m1_sh[lane * 65 + wb + c] = silu_f(acc[c]);
    __syncthreads();

    float acc2[16];
#pragma unroll
    for (int c = 0; c < 16; ++c) acc2[c] = b2[wb + c];
    for (int k = 0; k < 64; ++k) {
        float a = m1_sh[lane * 65 + k];
        const float4* wr = (const float4*)(W2 + k * 64 + wb);
        float4 w0 = wr[0], w1 = wr[1], w2 = wr[2], w3 = wr[3];
        acc2[0]  = fmaf(a, w0.x, acc2[0]);  acc2[1]  = fmaf(a, w0.y, acc2[1]);
        acc2[2]  = fmaf(a, w0.z, acc2[2]);  acc2[3]  = fmaf(a, w0.w, acc2[3]);
        acc2[4]  = fmaf(a, w1.x, acc2[4]);  acc2[5]  = fmaf(a, w1.y, acc2[5]);
        acc2[6]  = fmaf(a, w1.z, acc2[6]);  acc2[7]  = fmaf(a, w1.w, acc2[7]);
        acc2[8]  = fmaf(a, w2.x, acc2[8]);  acc2[9]  = fmaf(a, w2.y, acc2[9]);
        acc2[10] = fmaf(a, w2.z, acc2[10]); acc2[11] = fmaf(a, w2.w, acc2[11]);
        acc2[12] = fmaf(a, w3.x, acc2[12]); acc2[13] = fmaf(a, w3.y, acc2[13]);
        acc2[14] = fmaf(a, w3.z, acc2[14]); acc2[15] = fmaf(a, w3.w, acc2[15]);
    }

    float s1 = 0.f, s2 = 0.f;
#pragma unroll
    for (int c = 0; c < 16; ++c) { s1 += acc2[c]; s2 += acc2[c] * acc2[c]; }
    red_sh[w * 64 + lane] = s1;
    red_sh[256 + w * 64 + lane] = s2;
    __syncthreads();
    float t1 = 0.f, t2 = 0.f;
#pragma unroll
    for (int j = 0; j < 4; ++j) {
        t1 += red_sh[j * 64 + lane];
        t2 += red_sh[256 + j * 64 + lane];
    }
    float mean = t1 * (1.0f / 64.0f);
    float var  = t2 * (1.0f / 64.0f) - mean * mean;
    float rstd = rsqrtf(var + 1e-5f);

    int n = n0 + lane;
    if (n < NN) {
#pragma unroll
        for (int c = 0; c < 16; ++c) {
            int ch = wb + c;
            h[n * 64 + ch] = (acc2[c] - mean) * rstd * g[ch] + be[ch];
        }
    }
}

// ---------------------------------------------------------------------------
// Edge MLP via MFMA + segmented scatter-add over dst-sorted edges.
// Computes C^T = W^T @ X^T so activations are MFMA B-operands read from
// row-major bf16 LDS rows (ds_read_b128 per K-step); weights are pre-packed
// A-fragments (per-lane dwordx4, L2-hot). Each wave owns 16 edges end-to-end:
// NO __syncthreads anywhere (all LDS traffic wave-local, DS pipe in-order).
// C^T lane mapping (16x16x32): n=edge=lane&15, m=ch=mt*16+quad*4+reg ->
// each lane holds 16 channels of ONE edge: LN = in-lane sum + 2 shfl_xor;
// segmented scan runs over the lane&15 dimension (masked, quad-preserving).
// LDS: 4 waves x (16 rows x 84 words B1 + 16 x 36 words mid) = 30720 B.
// ---------------------------------------------------------------------------
__global__ __launch_bounds__(256, 5) void edge_kernel(
    const float* __restrict__ h,
    const int* __restrict__ sidx, const int* __restrict__ sdst,
    const int* __restrict__ ssrc,
    const float* __restrict__ ea,
    const short* __restrict__ W1pk, const float* __restrict__ b1,
    const short* __restrict__ W2pk, const float* __restrict__ b2,
    const float* __restrict__ g, const float* __restrict__ be,
    float* __restrict__ agg)
{
    __shared__ unsigned int lds[4 * 1344 + 4 * 576];
    const int lane = threadIdx.x & 63;
    const int w    = threadIdx.x >> 6;
    const int quad = lane >> 4;
    const int l15  = lane & 15;
    const int e0   = blockIdx.x * 64 + w * 16;     // this wave's 16 edges
    unsigned int* B1  = lds + w * 1344;            // 16 rows x 84 words
    unsigned int* MID = lds + 4 * 1344 + w * 576;  // 16 rows x 36 words

    // stage X rows: bf16 k 0..127 = [h[dst] | h[src]] (words 0..63)
    for (int i = 0; i < 16; ++i) {
        int p = e0 + i;
        const float* src = (lane < 32)
            ? (h + (size_t)sdst[p] * 64 + lane * 2)
            : (h + (size_t)ssrc[p] * 64 + (lane - 32) * 2);
        float2 v = *(const float2*)src;
        B1[i * 84 + lane] = pack_bf16x2(v.x, v.y);
    }
    // k 128..132 = ea, 133..159 = 0 (words 64..79)
    for (int t = 0; t < 4; ++t) {
        int gidx = t * 64 + lane;      // 0..255
        int si = gidx >> 4;            // slot 0..15
        int wd = gidx & 15;            // word 64+wd
        unsigned int val = 0;
        if (wd < 3) {
            size_t eb = (size_t)sidx[e0 + si] * 5;
            if (wd == 0)      val = pack_bf16x2(ea[eb + 0], ea[eb + 1]);
            else if (wd == 1) val = pack_bf16x2(ea[eb + 2], ea[eb + 3]);
            else              val = pack_bf16x2(ea[eb + 4], 0.0f);
        }
        B1[si * 84 + 64 + wd] = val;
    }

    // GEMM1: C1^T[ch][edge], K=160 (5 ks), M=64 ch (4 mt)
    f32x4 acc1[4] = {{0,0,0,0},{0,0,0,0},{0,0,0,0},{0,0,0,0}};
    const unsigned int* brow = B1 + l15 * 84;
    for (int ks = 0; ks < 5; ++ks) {
        bf16x8 bfrag = *(const bf16x8*)(brow + ks * 16 + quad * 4);
        const short* apk = W1pk + (size_t)(ks * 4) * 512 + lane * 8;
#pragma unroll
        for (int mt = 0; mt < 4; ++mt) {
            bf16x8 afrag = *(const bf16x8*)(apk + mt * 512);
            acc1[mt] = __builtin_amdgcn_mfma_f32_16x16x32_bf16(
                afrag, bfrag, acc1[mt], 0, 0, 0);
        }
    }
    // epilogue 1: bias + silu -> MID[edge=l15][ch] bf16 row-major (b64 writes)
#pragma unroll
    for (int mt = 0; mt < 4; ++mt) {
        int ch0 = mt * 16 + quad * 4;
        float v0 = silu_f(acc1[mt][0] + b1[ch0 + 0]);
        float v1 = silu_f(acc1[mt][1] + b1[ch0 + 1]);
        float v2 = silu_f(acc1[mt][2] + b1[ch0 + 2]);
        float v3 = silu_f(acc1[mt][3] + b1[ch0 + 3]);
        uint2 pk;
        pk.x = pack_bf16x2(v0, v1);
        pk.y = pack_bf16x2(v2, v3);
        *(uint2*)(MID + l15 * 36 + mt * 8 + quad * 2) = pk;
    }

    // GEMM2: C2^T[ch][edge], K=64 (2 ks)
    f32x4 acc2[4] = {{0,0,0,0},{0,0,0,0},{0,0,0,0},{0,0,0,0}};
    const unsigned int* mrow = MID + l15 * 36;
    for (int ks = 0; ks < 2; ++ks) {
        bf16x8 bfrag = *(const bf16x8*)(mrow + ks * 16 + quad * 4);
        const short* apk = W2pk + (size_t)(ks * 4) * 512 + lane * 8;
#pragma unroll
        for (int mt = 0; mt < 4; ++mt) {
            bf16x8 afrag = *(const bf16x8*)(apk + mt * 512);
            acc2[mt] = __builtin_amdgcn_mfma_f32_16x16x32_bf16(
                afrag, bfrag, acc2[mt], 0, 0, 0);
        }
    }

    // bias + LN over the 64 channels of this lane's edge
    float vals[16];
    float s1 = 0.f, s2 = 0.f;
#pragma unroll
    for (int mt = 0; mt < 4; ++mt) {
#pragma unroll
        for (int r = 0; r < 4; ++r) {
            int ch = mt * 16 + quad * 4 + r;
            float vv = acc2[mt][r] + b2[ch];
            vals[mt * 4 + r] = vv;
            s1 += vv; s2 += vv * vv;
        }
    }
    s1 += __shfl_xor(s1, 16); s1 += __shfl_xor(s1, 32);
    s2 += __shfl_xor(s2, 16); s2 += __shfl_xor(s2, 32);
    float mean = s1 * (1.0f / 64.0f);
    float var  = s2 * (1.0f / 64.0f) - mean * mean;
    float rstd = rsqrtf(var + 1e-5f);
#pragma unroll
    for (int mt = 0; mt < 4; ++mt) {
#pragma unroll
        for (int r = 0; r < 4; ++r) {
            int ch = mt * 16 + quad * 4 + r;
            vals[mt * 4 + r] = (vals[mt * 4 + r] - mean) * rstd * g[ch] + be[ch];
        }
    }

    // segmented inclusive scan over the wave's 16 edges (lane&15 dimension);
    // masking on (l15 >= delta) keeps shfl_up within the same quad.
    int d_l = sdst[e0 + l15];
#pragma unroll
    for (int delta = 1; delta < 16; delta <<= 1) {
        int d_up = __shfl_up(d_l, delta);
        bool merge = (l15 >= delta) && (d_up == d_l);
#pragma unroll
        for (int c = 0; c < 16; ++c) {
            float vu = __shfl_up(vals[c], delta);
            if (merge) vals[c] += vu;
        }
    }
    int d_next = __shfl_down(d_l, 1);
    bool last = (l15 == 15) || (d_next != d_l);
    if (last) {
#pragma unroll
        for (int mt = 0; mt < 4; ++mt) {
#pragma unroll
            for (int r = 0; r < 4; ++r) {
                int ch = mt * 16 + quad * 4 + r;
                atomicAdd(&agg[(size_t)d_l * 64 + ch], vals[mt * 4 + r]);
            }
        }
    }
}

// ---------------------------------------------------------------------------
// Node MLP + residual: h = h + LN(silu([h,agg] @ W1+b1) @ W2+b2)
// ---------------------------------------------------------------------------
__global__ __launch_bounds__(256) void node_kernel(
    float* __restrict__ h, const float* __restrict__ agg,
    const float* __restrict__ W1, const float* __restrict__ b1,
    const float* __restrict__ W2, const float* __restrict__ b2,
    const float* __restrict__ g, const float* __restrict__ be)
{
    __shared__ float in_sh[64 * 129];
    __shared__ float red_sh[2 * 4 * 64];
    const int lane = threadIdx.x & 63;
    const int w    = threadIdx.x >> 6;
    const int wb   = __builtin_amdgcn_readfirstlane(w * 16);
    const int n0   = blockIdx.x * 64;

    for (int i = 0; i < 16; ++i) {
        int slot = w * 16 + i;
        int n = n0 + slot;
        if (n < NN) {
            in_sh[slot * 129 + lane]      = h[n * 64 + lane];
            in_sh[slot * 129 + 64 + lane] = agg[n * 64 + lane];
        }
    }
    __syncthreads();

    float acc[16];
#pragma unroll
    for (int c = 0; c < 16; ++c) acc[c] = b1[wb + c];
    for (int k = 0; k < 128; ++k) {
        float a = in_sh[lane * 129 + k];
        const float4* wr = (const float4*)(W1 + k * 64 + wb);
        float4 w0 = wr[0], w1 = wr[1], w2 = wr[2], w3 = wr[3];
        acc[0]  = fmaf(a, w0.x, acc[0]);  acc[1]  = fmaf(a, w0.y, acc[1]);
        acc[2]  = fmaf(a, w0.z, acc[2]);  acc[3]  = fmaf(a, w0.w, acc[3]);
        acc[4]  = fmaf(a, w1.x, acc[4]);  acc[5]  = fmaf(a, w1.y, acc[5]);
        acc[6]  = fmaf(a, w1.z, acc[6]);  acc[7]  = fmaf(a, w1.w, acc[7]);
        acc[8]  = fmaf(a, w2.x, acc[8]);  acc[9]  = fmaf(a, w2.y, acc[9]);
        acc[10] = fmaf(a, w2.z, acc[10]); acc[11] = fmaf(a, w2.w, acc[11]);
        acc[12] = fmaf(a, w3.x, acc[12]); acc[13] = fmaf(a, w3.y, acc[13]);
        acc[14] = fmaf(a, w3.z, acc[14]); acc[15] = fmaf(a, w3.w, acc[15]);
    }
    __syncthreads();
#pragma unroll
    for (int c = 0; c < 16; ++c) in_sh[lane * 65 + wb + c] = silu_f(acc[c]);
    __syncthreads();

    float acc2[16];
#pragma unroll
    for (int c = 0; c < 16; ++c) acc2[c] = b2[wb + c];
    for (int k = 0; k < 64; ++k) {
        float a = in_sh[lane * 65 + k];
        const float4* wr = (const float4*)(W2 + k * 64 + wb);
        float4 w0 = wr[0], w1 = wr[1], w2 = wr[2], w3 = wr[3];
        acc2[0]  = fmaf(a, w0.x, acc2[0]);  acc2[1]  = fmaf(a, w0.y, acc2[1]);
        acc2[2]  = fmaf(a, w0.z, acc2[2]);  acc2[3]  = fmaf(a, w0.w, acc2[3]);
        acc2[4]  = fmaf(a, w1.x, acc2[4]);  acc2[5]  = fmaf(a, w1.y, acc2[5]);
        acc2[6]  = fmaf(a, w1.z, acc2[6]);  acc2[7]  = fmaf(a, w1.w, acc2[7]);
        acc2[8]  = fmaf(a, w2.x, acc2[8]);  acc2[9]  = fmaf(a, w2.y, acc2[9]);
        acc2[10] = fmaf(a, w2.z, acc2[10]); acc2[11] = fmaf(a, w2.w, acc2[11]);
        acc2[12] = fmaf(a, w3.x, acc2[12]); acc2[13] = fmaf(a, w3.y, acc2[13]);
        acc2[14] = fmaf(a, w3.z, acc2[14]); acc2[15] = fmaf(a, w3.w, acc2[15]);
    }

    float s1 = 0.f, s2 = 0.f;
#pragma unroll
    for (int c = 0; c < 16; ++c) { s1 += acc2[c]; s2 += acc2[c] * acc2[c]; }
    red_sh[w * 64 + lane] = s1;
    red_sh[256 + w * 64 + lane] = s2;
    __syncthreads();
    float t1 = 0.f, t2 = 0.f;
#pragma unroll
    for (int j = 0; j < 4; ++j) {
        t1 += red_sh[j * 64 + lane];
        t2 += red_sh[256 + j * 64 + lane];
    }
    float mean = t1 * (1.0f / 64.0f);
    float var  = t2 * (1.0f / 64.0f) - mean * mean;
    float rstd = rsqrtf(var + 1e-5f);

    int n = n0 + lane;
    if (n < NN) {
#pragma unroll
        for (int c = 0; c < 16; ++c) {
            int ch = wb + c;
            float hv = h[n * 64 + ch];   // residual (L2-hot re-read)
            h[n * 64 + ch] = hv + (acc2[c] - mean) * rstd * g[ch] + be[ch];
        }
    }
}

// ---------------------------------------------------------------------------
// Local decoder: out_local = silu(h @ W1 + b1) @ W2 + b2  -> [NN, 6]
// ---------------------------------------------------------------------------
__global__ __launch_bounds__(256) void dec_local_kernel(
    const float* __restrict__ h,
    const float* __restrict__ W1, const float* __restrict__ b1,
    const float* __restrict__ W2, const float* __restrict__ b2,
    float* __restrict__ out)
{
    __shared__ float mid_sh[4][64];
    const int lane = threadIdx.x & 63;
    const int w    = threadIdx.x >> 6;
    const int n = blockIdx.x * 4 + w;
    if (n >= NN) return;

    float a = b1[lane];
    for (int k = 0; k < 64; ++k)
        a = fmaf(h[n * 64 + k], W1[k * 64 + lane], a);
    mid_sh[w][lane] = silu_f(a);
    if (lane < 6) {
        float o = b2[lane];
        for (int k = 0; k < 64; ++k)
            o = fmaf(mid_sh[w][k], W2[k * 6 + lane], o);
        out[n * 6 + lane] = o;
    }
}

// ---------------------------------------------------------------------------
// Pooling: pooled[g][c] = sum_{batch[n]==g} h[n][c];  cnt[g] = count
// ---------------------------------------------------------------------------
__global__ __launch_bounds__(256) void pool_kernel(
    const float* __restrict__ h, const int* __restrict__ batch,
    float* __restrict__ pooled, float* __restrict__ cnt)
{
    const int c   = threadIdx.x & 63;
    const int rep = blockIdx.x * 4 + (threadIdx.x >> 6);   // 1024 reps
    float acc[NG] = {0.f, 0.f, 0.f, 0.f};
    float cl[NG]  = {0.f, 0.f, 0.f, 0.f};
    for (int n = rep; n < NN; n += 1024) {
        int b = batch[n];
        float v = h[n * 64 + c];
#pragma unroll
        for (int gph = 0; gph < NG; ++gph) {
            if (b == gph) { acc[gph] += v; cl[gph] += 1.0f; }
        }
    }
#pragma unroll
    for (int gph = 0; gph < NG; ++gph) {
        atomicAdd(&pooled[gph * 64 + c], acc[gph]);
        if (c == 0) atomicAdd(&cnt[gph], cl[gph]);
    }
}

// ---------------------------------------------------------------------------
// Global decoder: out_global = silu(mean_pool @ W1 + b1) @ W2 + b2 -> [4,4]
// ---------------------------------------------------------------------------
__global__ __launch_bounds__(256) void dec_global_kernel(
    const float* __restrict__ pooled, const float* __restrict__ cnt,
    const float* __restrict__ W1, const float* __restrict__ b1,
    const float* __restrict__ W2, const float* __restrict__ b2,
    float* __restrict__ out)
{
    __shared__ float mid_sh[4][32];
    const int lane = threadIdx.x & 63;
    const int gph  = threadIdx.x >> 6;
    float inv = 1.0f / fmaxf(cnt[gph], 1.0f);
    if (lane < 32) {
        float a = b1[lane];
        for (int k = 0; k < 64; ++k)
            a = fmaf(pooled[gph * 64 + k] * inv, W1[k * 32 + lane], a);
        mid_sh[gph][lane] = silu_f(a);
    }
    __syncthreads();
    if (lane < 4) {
        float o = b2[lane];
        for (int k = 0; k < 32; ++k)
            o = fmaf(mid_sh[gph][k], W2[k * 4 + lane], o);
        out[gph * 4 + lane] = o;
    }
}

// ---------------------------------------------------------------------------
extern "C" void kernel_launch(void* const* d_in, const int* in_sizes, int n_in,
                              void* d_out, int out_size, void* d_ws, size_t ws_size,
                              hipStream_t stream)
{
    const float* x      = (const float*)d_in[0];
    const int*   ei     = (const int*)  d_in[1];
    const float* ea     = (const float*)d_in[2];
    const int*   batch  = (const int*)  d_in[3];
    const float* case_p = (const float*)d_in[4];
    const float* bc_p   = (const float*)d_in[5];
    const float* enc_W1 = (const float*)d_in[6];
    const float* enc_b1 = (const float*)d_in[7];
    const float* enc_W2 = (const float*)d_in[8];
    const float* enc_b2 = (const float*)d_in[9];
    const float* enc_g  = (const float*)d_in[10];
    const float* enc_be = (const float*)d_in[11];
    const float* eW1    = (const float*)d_in[12];
    const float* eb1    = (const float*)d_in[13];
    const float* eW2    = (const float*)d_in[14];
    const float* eb2    = (const float*)d_in[15];
    const float* eg     = (const float*)d_in[16];
    const float* ebe    = (const float*)d_in[17];
    const float* nW1    = (const float*)d_in[18];
    const float* nb1    = (const float*)d_in[19];
    const float* nW2    = (const float*)d_in[20];
    const float* nb2    = (const float*)d_in[21];
    const float* ng     = (const float*)d_in[22];
    const float* nbe    = (const float*)d_in[23];
    const float* dlW1   = (const float*)d_in[24];
    const float* dlb1   = (const float*)d_in[25];
    const float* dlW2   = (const float*)d_in[26];
    const float* dlb2   = (const float*)d_in[27];
    const float* dgW1   = (const float*)d_in[28];
    const float* dgb1   = (const float*)d_in[29];
    const float* dgW2   = (const float*)d_in[30];
    const float* dgb2   = (const float*)d_in[31];

    float* out = (float*)d_out;

    char* ws = (char*)d_ws;
    size_t off_b = 0;
    auto alloc = [&](size_t bytes) {
        void* p = ws + off_b;
        off_b = (off_b + bytes + 255) & ~(size_t)255;
        return p;
    };
    const size_t hBytes = (size_t)NN * H * sizeof(float);     // 12.8 MB
    float* h      = (float*)alloc(hBytes);
    float* agg    = (float*)alloc(hBytes);
    float* pooled = (float*)alloc(256 * sizeof(float));
    float* cnt    = (float*)alloc(4 * sizeof(float));
    int*   deg    = (int*)alloc((NN + 1) * sizeof(int));
    int*   offs   = (int*)alloc((NN + 1) * sizeof(int));
    int*   cursor = (int*)alloc((NN + 1) * sizeof(int));
    int*   sidx   = (int*)alloc((size_t)NE * sizeof(int));
    int*   sdst   = (int*)alloc((size_t)NE * sizeof(int));
    int*   ssrc   = (int*)alloc((size_t)NE * sizeof(int));
    short* W1pk   = (short*)alloc((size_t)NL * 10240 * sizeof(short));
    short* W2pk   = (short*)alloc((size_t)NL * 4096 * sizeof(short));

    hipMemsetAsync(pooled, 0, (256 + 4 + 64) * sizeof(float), stream); // pooled+cnt
    hipMemsetAsync(deg, 0, (NN + 1) * sizeof(int), stream);

    // counting sort of edges by dst + weight pre-pack (deterministic each call)
    degree_kernel<<<(NE + 255) / 256, 256, 0, stream>>>(ei, deg);
    scan_kernel<<<1, 1024, 0, stream>>>(deg, offs, cursor);
    scatter_kernel<<<(NE + 255) / 256, 256, 0, stream>>>(ei, cursor, sidx, sdst, ssrc);
    pack_weights_kernel<<<dim3(56, NL), 256, 0, stream>>>(eW1, eW2, W1pk, W2pk);

    const int nodeBlocks = (NN + 63) / 64;    // 782
    encoder_kernel<<<nodeBlocks, 256, 0, stream>>>(
        x, batch, case_p, bc_p, enc_W1, enc_b1, enc_W2, enc_b2, enc_g, enc_be, h);

    for (int l = 0; l < NL; ++l) {
        hipMemsetAsync(agg, 0, hBytes, stream);
        edge_kernel<<<NE / 64, 256, 0, stream>>>(
            h, sidx, sdst, ssrc, ea,
            W1pk + (size_t)l * 10240, eb1 + l * H,
            W2pk + (size_t)l * 4096,  eb2 + l * H,
            eg + l * H, ebe + l * H, agg);
        node_kernel<<<nodeBlocks, 256, 0, stream>>>(
            h, agg,
            nW1 + (size_t)l * NIN * H, nb1 + l * H,
            nW2 + (size_t)l * H * H,   nb2 + l * H,
            ng + l * H, nbe + l * H);
    }

    dec_local_kernel<<<(NN + 3) / 4, 256, 0, stream>>>(h, dlW1, dlb1, dlW2, dlb2, out);
    pool_kernel<<<256, 256, 0, stream>>>(h, batch, pooled, cnt);
    dec_global_kernel<<<1, 256, 0, stream>>>(pooled, cnt, dgW1, dgb1, dgW2, dgb2,
                                             out + (size_t)NN * 6);
}

// Round 6
// 1847.306 us; speedup vs baseline: 16.0505x; 1.7694x over previous
//
#include <hip/hip_runtime.h>
#include <cmath>

// Problem constants (from reference)
constexpr int NN = 50000;      // nodes
constexpr int NE = 1600000;    // edges
constexpr int H  = 64;         // hidden
constexpr int NL = 5;          // layers
constexpr int NG = 4;          // graphs
constexpr int EIN = 2 * H + 5; // 133
constexpr int NIN = 2 * H;     // 128

typedef short bf16x8 __attribute__((ext_vector_type(8)));
typedef float f32x4  __attribute__((ext_vector_type(4)));

__device__ __forceinline__ float silu_f(float x) {
    return x / (1.0f + __expf(-x));
}

// round-to-nearest-even fp32 -> bf16 bits
__device__ __forceinline__ unsigned int f2bf(float f) {
    unsigned int u = __float_as_uint(f);
    u += 0x7fffu + ((u >> 16) & 1u);
    return u >> 16;
}
__device__ __forceinline__ unsigned int pack_bf16x2(float x, float y) {
    return f2bf(x) | (f2bf(y) << 16);
}

// ---------------------------------------------------------------------------
// Counting sort of edges by dst
// ---------------------------------------------------------------------------
__global__ __launch_bounds__(256) void degree_kernel(
    const int* __restrict__ ei, int* __restrict__ deg)
{
    int e = blockIdx.x * 256 + threadIdx.x;
    if (e < NE) atomicAdd(&deg[ei[NE + e]], 1);
}

__global__ __launch_bounds__(1024) void scan_kernel(
    const int* __restrict__ deg, int* __restrict__ off, int* __restrict__ cursor)
{
    __shared__ int sh[1024];
    const int tid = threadIdx.x;
    int running = 0;
    for (int base = 0; base < NN; base += 1024) {
        int v = (base + tid < NN) ? deg[base + tid] : 0;
        sh[tid] = v;
        __syncthreads();
        for (int d = 1; d < 1024; d <<= 1) {
            int t = (tid >= d) ? sh[tid - d] : 0;
            __syncthreads();
            sh[tid] += t;
            __syncthreads();
        }
        int excl = sh[tid] - v;
        if (base + tid < NN) {
            off[base + tid] = running + excl;
            cursor[base + tid] = running + excl;
        }
        int total = sh[1023];
        __syncthreads();
        running += total;
    }
    if (tid == 0) off[NN] = running;
}

__global__ __launch_bounds__(256) void scatter_kernel(
    const int* __restrict__ ei, int* __restrict__ cursor,
    int* __restrict__ sidx, int* __restrict__ sdst, int* __restrict__ ssrc)
{
    int e = blockIdx.x * 256 + threadIdx.x;
    if (e < NE) {
        int d = ei[NE + e];
        int p = atomicAdd(&cursor[d], 1);
        sidx[p] = e;
        sdst[p] = d;
        ssrc[p] = ei[e];
    }
}

// ---------------------------------------------------------------------------
// Pre-pack edge_attr into sorted-edge order, bf16, 16B/edge (5 vals + 3 zero)
// ---------------------------------------------------------------------------
__global__ __launch_bounds__(256) void ea_pack_kernel(
    const float* __restrict__ ea, const int* __restrict__ sidx,
    uint4* __restrict__ ea_pk)
{
    int p = blockIdx.x * 256 + threadIdx.x;
    if (p < NE) {
        const float* s = ea + (size_t)sidx[p] * 5;
        uint4 v;
        v.x = pack_bf16x2(s[0], s[1]);
        v.y = pack_bf16x2(s[2], s[3]);
        v.z = pack_bf16x2(s[4], 0.0f);
        v.w = 0u;
        ea_pk[p] = v;
    }
}

// ---------------------------------------------------------------------------
// Pre-pack MLP weights into MFMA A-fragment order (bf16).
// A = W^T: elem(ks, mt, lane, j) = W[k = ks*32 + (lane>>4)*8 + j][ch = mt*16 + (lane&15)]
// edge W1: K 133->160 (5 ks, 10240/layer); edge W2: K=64 (4096);
// node W1: K=128 (4 ks, 8192); node W2: K=64 (4096). total 26624/layer.
// ---------------------------------------------------------------------------
__global__ __launch_bounds__(256) void pack_weights_kernel(
    const float* __restrict__ eW1, const float* __restrict__ eW2,
    const float* __restrict__ nW1, const float* __restrict__ nW2,
    short* __restrict__ eW1pk, short* __restrict__ eW2pk,
    short* __restrict__ nW1pk, short* __restrict__ nW2pk)
{
    int l = blockIdx.y;
    int t = blockIdx.x * 256 + threadIdx.x;
    if (t < 10240) {
        int j = t & 7, lane = (t >> 3) & 63, mt = (t >> 9) & 3, ks = t >> 11;
        int k  = ks * 32 + (lane >> 4) * 8 + j;
        int ch = mt * 16 + (lane & 15);
        float v = (k < EIN) ? eW1[(size_t)l * EIN * H + k * H + ch] : 0.0f;
        eW1pk[(size_t)l * 10240 + t] = (short)f2bf(v);
    } else if (t < 14336) {
        int t2 = t - 10240;
        int j = t2 & 7, lane = (t2 >> 3) & 63, mt = (t2 >> 9) & 3, ks = t2 >> 11;
        int k = ks * 32 + (lane >> 4) * 8 + j;
        int ch = mt * 16 + (lane & 15);
        eW2pk[(size_t)l * 4096 + t2] = (short)f2bf(eW2[(size_t)l * H * H + k * H + ch]);
    } else if (t < 22528) {
        int t3 = t - 14336;
        int j = t3 & 7, lane = (t3 >> 3) & 63, mt = (t3 >> 9) & 3, ks = t3 >> 11;
        int k = ks * 32 + (lane >> 4) * 8 + j;
        int ch = mt * 16 + (lane & 15);
        nW1pk[(size_t)l * 8192 + t3] = (short)f2bf(nW1[(size_t)l * NIN * H + k * H + ch]);
    } else if (t < 26624) {
        int t4 = t - 22528;
        int j = t4 & 7, lane = (t4 >> 3) & 63, mt = (t4 >> 9) & 3, ks = t4 >> 11;
        int k = ks * 32 + (lane >> 4) * 8 + j;
        int ch = mt * 16 + (lane & 15);
        nW2pk[(size_t)l * 4096 + t4] = (short)f2bf(nW2[(size_t)l * H * H + k * H + ch]);
    }
}

// ---------------------------------------------------------------------------
// Encoder: h = LN(silu([x, gv[batch]] @ W1 + b1) @ W2 + b2); writes h (fp32)
// and h2 (bf16 mirror used by edge/node MFMA staging).
// ---------------------------------------------------------------------------
__global__ __launch_bounds__(256) void encoder_kernel(
    const float* __restrict__ x, const int* __restrict__ batch,
    const float* __restrict__ case_p, const float* __restrict__ bc_p,
    const float* __restrict__ W1, const float* __restrict__ b1,
    const float* __restrict__ W2, const float* __restrict__ b2,
    const float* __restrict__ g, const float* __restrict__ be,
    float* __restrict__ h, unsigned int* __restrict__ h2)
{
    __shared__ float in_sh[64 * 17];
    __shared__ float m1_sh[64 * 65];
    __shared__ float red_sh[2 * 4 * 64];
    const int lane = threadIdx.x & 63;
    const int w    = threadIdx.x >> 6;
    const int wb   = __builtin_amdgcn_readfirstlane(w * 16);
    const int n0   = blockIdx.x * 64;

    for (int i = 0; i < 16; ++i) {
        int slot = w * 16 + i;
        int n = n0 + slot;
        if (n < NN && lane < 16) {
            float v;
            if (lane < 8) v = x[n * 8 + lane];
            else {
                int b = batch[n];
                v = (lane < 12) ? case_p[b * 4 + (lane - 8)]
                                : bc_p[b * 4 + (lane - 12)];
            }
            in_sh[slot * 17 + lane] = v;
        }
    }
    __syncthreads();

    float acc[16];
#pragma unroll
    for (int c = 0; c < 16; ++c) acc[c] = b1[wb + c];
    for (int k = 0; k < 16; ++k) {
        float a = in_sh[lane * 17 + k];
        const float4* wr = (const float4*)(W1 + k * 64 + wb);
        float4 w0 = wr[0], w1 = wr[1], w2 = wr[2], w3 = wr[3];
        acc[0]  = fmaf(a, w0.x, acc[0]);  acc[1]  = fmaf(a, w0.y, acc[1]);
        acc[2]  = fmaf(a, w0.z, acc[2]);  acc[3]  = fmaf(a, w0.w, acc[3]);
        acc[4]  = fmaf(a, w1.x, acc[4]);  acc[5]  = fmaf(a, w1.y, acc[5]);
        acc[6]  = fmaf(a, w1.z, acc[6]);  acc[7]  = fmaf(a, w1.w, acc[7]);
        acc[8]  = fmaf(a, w2.x, acc[8]);  acc[9]  = fmaf(a, w2.y, acc[9]);
        acc[10] = fmaf(a, w2.z, acc[10]); acc[11] = fmaf(a, w2.w, acc[11]);
        acc[12] = fmaf(a, w3.x, acc[12]); acc[13] = fmaf(a, w3.y, acc[13]);
        acc[14] = fmaf(a, w3.z, acc[14]); acc[15] = fmaf(a, w3.w, acc[15]);
    }
#pragma unroll
    for (int c = 0; c < 16; ++c) m1_sh[lane * 65 + wb + c] = silu_f(acc[c]);
    __syncthreads();

    float acc2[16];
#pragma unroll
    for (int c = 0; c < 16; ++c) acc2[c] = b2[wb + c];
    for (int k = 0; k < 64; ++k) {
        float a = m1_sh[lane * 65 + k];
        const float4* wr = (const float4*)(W2 + k * 64 + wb);
        float4 w0 = wr[0], w1 = wr[1], w2 = wr[2], w3 = wr[3];
        acc2[0]  = fmaf(a, w0.x, acc2[0]);  acc2[1]  = fmaf(a, w0.y, acc2[1]);
        acc2[2]  = fmaf(a, w0.z, acc2[2]);  acc2[3]  = fmaf(a, w0.w, acc2[3]);
        acc2[4]  = fmaf(a, w1.x, acc2[4]);  acc2[5]  = fmaf(a, w1.y, acc2[5]);
        acc2[6]  = fmaf(a, w1.z, acc2[6]);  acc2[7]  = fmaf(a, w1.w, acc2[7]);
        acc2[8]  = fmaf(a, w2.x, acc2[8]);  acc2[9]  = fmaf(a, w2.y, acc2[9]);
        acc2[10] = fmaf(a, w2.z, acc2[10]); acc2[11] = fmaf(a, w2.w, acc2[11]);
        acc2[12] = fmaf(a, w3.x, acc2[12]); acc2[13] = fmaf(a, w3.y, acc2[13]);
        acc2[14] = fmaf(a, w3.z, acc2[14]); acc2[15] = fmaf(a, w3.w, acc2[15]);
    }

    float s1 = 0.f, s2 = 0.f;
#pragma unroll
    for (int c = 0; c < 16; ++c) { s1 += acc2[c]; s2 += acc2[c] * acc2[c]; }
    red_sh[w * 64 + lane] = s1;
    red_sh[256 + w * 64 + lane] = s2;
    __syncthreads();
    float t1 = 0.f, t2 = 0.f;
#pragma unroll
    for (int j = 0; j < 4; ++j) {
        t1 += red_sh[j * 64 + lane];
        t2 += red_sh[256 + j * 64 + lane];
    }
    float mean = t1 * (1.0f / 64.0f);
    float var  = t2 * (1.0f / 64.0f) - mean * mean;
    float rstd = rsqrtf(var + 1e-5f);

    int n = n0 + lane;
    if (n < NN) {
        float vals[16];
#pragma unroll
        for (int c = 0; c < 16; ++c) {
            int ch = wb + c;
            vals[c] = (acc2[c] - mean) * rstd * g[ch] + be[ch];
            h[n * 64 + ch] = vals[c];
        }
        uint4 p0, p1;
        p0.x = pack_bf16x2(vals[0], vals[1]);   p0.y = pack_bf16x2(vals[2], vals[3]);
        p0.z = pack_bf16x2(vals[4], vals[5]);   p0.w = pack_bf16x2(vals[6], vals[7]);
        p1.x = pack_bf16x2(vals[8], vals[9]);   p1.y = pack_bf16x2(vals[10], vals[11]);
        p1.z = pack_bf16x2(vals[12], vals[13]); p1.w = pack_bf16x2(vals[14], vals[15]);
        *(uint4*)(h2 + (size_t)n * 32 + w * 8)     = p0;
        *(uint4*)(h2 + (size_t)n * 32 + w * 8 + 4) = p1;
    }
}

// ---------------------------------------------------------------------------
// Edge MLP via MFMA + segmented scatter-add over dst-sorted edges.
// Staging is pure copy from bf16 mirrors (h2, ea_pk): no pack VALU.
// MID aliases B1 (wave-local, DS pipe in-order per wave): LDS 21504 B
// -> 7 blocks/CU. No __syncthreads anywhere.
// ---------------------------------------------------------------------------
__global__ __launch_bounds__(256, 7) void edge_kernel(
    const unsigned int* __restrict__ h2,
    const int* __restrict__ sdst, const int* __restrict__ ssrc,
    const uint4* __restrict__ ea_pk,
    const short* __restrict__ W1pk, const float* __restrict__ b1,
    const short* __restrict__ W2pk, const float* __restrict__ b2,
    const float* __restrict__ g, const float* __restrict__ be,
    float* __restrict__ agg)
{
    __shared__ unsigned int lds[4 * 1344];
    const int lane = threadIdx.x & 63;
    const int w    = threadIdx.x >> 6;
    const int quad = lane >> 4;
    const int l15  = lane & 15;
    const int e0   = blockIdx.x * 64 + w * 16;     // this wave's 16 edges
    unsigned int* B1  = lds + w * 1344;            // 16 rows x 84 words
    unsigned int* MID = B1;                        // aliased; stride 36

    // stage h2 rows: 8 iters x 2 edges (lanes: dstA|srcA|dstB|srcB x 16)
    const int grp = quad;                 // 0..3
    const int j2  = l15 * 2;
#pragma unroll
    for (int i = 0; i < 8; ++i) {
        int p = e0 + 2 * i + (grp >> 1);
        int node = (grp & 1) ? ssrc[p] : sdst[p];
        uint2 v = *(const uint2*)(h2 + (size_t)node * 32 + j2);
        *(uint2*)(B1 + (2 * i + (grp >> 1)) * 84 + (grp & 1) * 32 + j2) = v;
    }
    // ea (words 64..67): lanes 0..15, one 16B load (coalesced) + b128 write
    if (lane < 16) {
        uint4 v = ea_pk[e0 + lane];
        *(uint4*)(B1 + lane * 84 + 64) = v;
    }
    // zeros (words 68..79): lanes 0..47
    if (lane < 48) {
        uint4 z = {0u, 0u, 0u, 0u};
        *(uint4*)(B1 + (lane / 3) * 84 + 68 + (lane % 3) * 4) = z;
    }

    // GEMM1: C1^T[ch][edge], K=160 (5 ks)
    f32x4 acc1[4] = {{0,0,0,0},{0,0,0,0},{0,0,0,0},{0,0,0,0}};
    const unsigned int* brow = B1 + l15 * 84;
    for (int ks = 0; ks < 5; ++ks) {
        bf16x8 bfrag = *(const bf16x8*)(brow + ks * 16 + quad * 4);
        const short* apk = W1pk + (size_t)(ks * 4) * 512 + lane * 8;
#pragma unroll
        for (int mt = 0; mt < 4; ++mt) {
            bf16x8 afrag = *(const bf16x8*)(apk + mt * 512);
            acc1[mt] = __builtin_amdgcn_mfma_f32_16x16x32_bf16(
                afrag, bfrag, acc1[mt], 0, 0, 0);
        }
    }
    // epilogue 1: bias + silu -> MID (aliased over B1; all B1 reads complete)
#pragma unroll
    for (int mt = 0; mt < 4; ++mt) {
        int ch0 = mt * 16 + quad * 4;
        float v0 = silu_f(acc1[mt][0] + b1[ch0 + 0]);
        float v1 = silu_f(acc1[mt][1] + b1[ch0 + 1]);
        float v2 = silu_f(acc1[mt][2] + b1[ch0 + 2]);
        float v3 = silu_f(acc1[mt][3] + b1[ch0 + 3]);
        uint2 pk;
        pk.x = pack_bf16x2(v0, v1);
        pk.y = pack_bf16x2(v2, v3);
        *(uint2*)(MID + l15 * 36 + mt * 8 + quad * 2) = pk;
    }

    // GEMM2: C2^T[ch][edge], K=64 (2 ks)
    f32x4 acc2[4] = {{0,0,0,0},{0,0,0,0},{0,0,0,0},{0,0,0,0}};
    const unsigned int* mrow = MID + l15 * 36;
    for (int ks = 0; ks < 2; ++ks) {
        bf16x8 bfrag = *(const bf16x8*)(mrow + ks * 16 + quad * 4);
        const short* apk = W2pk + (size_t)(ks * 4) * 512 + lane * 8;
#pragma unroll
        for (int mt = 0; mt < 4; ++mt) {
            bf16x8 afrag = *(const bf16x8*)(apk + mt * 512);
            acc2[mt] = __builtin_amdgcn_mfma_f32_16x16x32_bf16(
                afrag, bfrag, acc2[mt], 0, 0, 0);
        }
    }

    // bias + LN over the 64 channels of this lane's edge
    float vals[16];
    float s1 = 0.f, s2 = 0.f;
#pragma unroll
    for (int mt = 0; mt < 4; ++mt) {
#pragma unroll
        for (int r = 0; r < 4; ++r) {
            int ch = mt * 16 + quad * 4 + r;
            float vv = acc2[mt][r] + b2[ch];
            vals[mt * 4 + r] = vv;
            s1 += vv; s2 += vv * vv;
        }
    }
    s1 += __shfl_xor(s1, 16); s1 += __shfl_xor(s1, 32);
    s2 += __shfl_xor(s2, 16); s2 += __shfl_xor(s2, 32);
    float mean = s1 * (1.0f / 64.0f);
    float var  = s2 * (1.0f / 64.0f) - mean * mean;
    float rstd = rsqrtf(var + 1e-5f);
#pragma unroll
    for (int mt = 0; mt < 4; ++mt) {
#pragma unroll
        for (int r = 0; r < 4; ++r) {
            int ch = mt * 16 + quad * 4 + r;
            vals[mt * 4 + r] = (vals[mt * 4 + r] - mean) * rstd * g[ch] + be[ch];
        }
    }

    // segmented inclusive scan over the wave's 16 edges (l15 dimension)
    int d_l = sdst[e0 + l15];
#pragma unroll
    for (int delta = 1; delta < 16; delta <<= 1) {
        int d_up = __shfl_up(d_l, delta);
        bool merge = (l15 >= delta) && (d_up == d_l);
#pragma unroll
        for (int c = 0; c < 16; ++c) {
            float vu = __shfl_up(vals[c], delta);
            if (merge) vals[c] += vu;
        }
    }
    int d_next = __shfl_down(d_l, 1);
    bool last = (l15 == 15) || (d_next != d_l);
    if (last) {
#pragma unroll
        for (int mt = 0; mt < 4; ++mt) {
#pragma unroll
            for (int r = 0; r < 4; ++r) {
                int ch = mt * 16 + quad * 4 + r;
                atomicAdd(&agg[(size_t)d_l * 64 + ch], vals[mt * 4 + r]);
            }
        }
    }
}

// ---------------------------------------------------------------------------
// Node MLP via MFMA + residual: h = h + LN(silu([h,agg]@W1+b1)@W2+b2)
// Same wave-owns-16-rows structure; no __syncthreads. Updates h and h2.
// LDS: 4 waves x 16 rows x 68 words = 17408 B.
// ---------------------------------------------------------------------------
__global__ __launch_bounds__(256, 4) void node_kernel(
    float* __restrict__ h, unsigned int* __restrict__ h2,
    const float* __restrict__ agg,
    const short* __restrict__ W1pk, const float* __restrict__ b1,
    const short* __restrict__ W2pk, const float* __restrict__ b2,
    const float* __restrict__ g, const float* __restrict__ be)
{
    __shared__ unsigned int lds[4 * 1088];
    const int lane = threadIdx.x & 63;
    const int w    = threadIdx.x >> 6;
    const int quad = lane >> 4;
    const int l15  = lane & 15;
    const int n0   = blockIdx.x * 64 + w * 16;     // this wave's 16 nodes
    unsigned int* B1  = lds + w * 1088;            // 16 rows x 68 words
    unsigned int* MID = B1;                        // aliased; stride 36

    // stage h2 rows (words 0..31): 4 iters x 4 nodes
#pragma unroll
    for (int i = 0; i < 4; ++i) {
        int slot = 4 * i + quad;
        int n = n0 + slot; if (n >= NN) n = NN - 1;
        uint2 v = *(const uint2*)(h2 + (size_t)n * 32 + l15 * 2);
        *(uint2*)(B1 + slot * 68 + l15 * 2) = v;
    }
    // stage agg (fp32 -> bf16, words 32..63): 8 iters x 2 nodes
    const int half = lane >> 5;        // 0/1
    const int j31  = lane & 31;
#pragma unroll
    for (int i = 0; i < 8; ++i) {
        int slot = 2 * i + half;
        int n = n0 + slot; if (n >= NN) n = NN - 1;
        float2 v = *(const float2*)(agg + (size_t)n * 64 + j31 * 2);
        B1[slot * 68 + 32 + j31] = pack_bf16x2(v.x, v.y);
    }

    // GEMM1: K=128 (4 ks)
    f32x4 acc1[4] = {{0,0,0,0},{0,0,0,0},{0,0,0,0},{0,0,0,0}};
    const unsigned int* brow = B1 + l15 * 68;
    for (int ks = 0; ks < 4; ++ks) {
        bf16x8 bfrag = *(const bf16x8*)(brow + ks * 16 + quad * 4);
        const short* apk = W1pk + (size_t)(ks * 4) * 512 + lane * 8;
#pragma unroll
        for (int mt = 0; mt < 4; ++mt) {
            bf16x8 afrag = *(const bf16x8*)(apk + mt * 512);
            acc1[mt] = __builtin_amdgcn_mfma_f32_16x16x32_bf16(
                afrag, bfrag, acc1[mt], 0, 0, 0);
        }
    }
#pragma unroll
    for (int mt = 0; mt < 4; ++mt) {
        int ch0 = mt * 16 + quad * 4;
        float v0 = silu_f(acc1[mt][0] + b1[ch0 + 0]);
        float v1 = silu_f(acc1[mt][1] + b1[ch0 + 1]);
        float v2 = silu_f(acc1[mt][2] + b1[ch0 + 2]);
        float v3 = silu_f(acc1[mt][3] + b1[ch0 + 3]);
        uint2 pk;
        pk.x = pack_bf16x2(v0, v1);
        pk.y = pack_bf16x2(v2, v3);
        *(uint2*)(MID + l15 * 36 + mt * 8 + quad * 2) = pk;
    }

    // GEMM2: K=64 (2 ks)
    f32x4 acc2[4] = {{0,0,0,0},{0,0,0,0},{0,0,0,0},{0,0,0,0}};
    const unsigned int* mrow = MID + l15 * 36;
    for (int ks = 0; ks < 2; ++ks) {
        bf16x8 bfrag = *(const bf16x8*)(mrow + ks * 16 + quad * 4);
        const short* apk = W2pk + (size_t)(ks * 4) * 512 + lane * 8;
#pragma unroll
        for (int mt = 0; mt < 4; ++mt) {
            bf16x8 afrag = *(const bf16x8*)(apk + mt * 512);
            acc2[mt] = __builtin_amdgcn_mfma_f32_16x16x32_bf16(
                afrag, bfrag, acc2[mt], 0, 0, 0);
        }
    }

    // bias + LN over the 64 channels of this lane's node
    float vals[16];
    float s1 = 0.f, s2 = 0.f;
#pragma unroll
    for (int mt = 0; mt < 4; ++mt) {
#pragma unroll
        for (int r = 0; r < 4; ++r) {
            int ch = mt * 16 + quad * 4 + r;
            float vv = acc2[mt][r] + b2[ch];
            vals[mt * 4 + r] = vv;
            s1 += vv; s2 += vv * vv;
        }
    }
    s1 += __shfl_xor(s1, 16); s1 += __shfl_xor(s1, 32);
    s2 += __shfl_xor(s2, 16); s2 += __shfl_xor(s2, 32);
    float mean = s1 * (1.0f / 64.0f);
    float var  = s2 * (1.0f / 64.0f) - mean * mean;
    float rstd = rsqrtf(var + 1e-5f);

    int n = n0 + l15;
    if (n < NN) {
#pragma unroll
        for (int mt = 0; mt < 4; ++mt) {
            int ch0 = mt * 16 + quad * 4;
            float4 hv = *(const float4*)(h + (size_t)n * 64 + ch0);
            float o0 = hv.x + (vals[mt*4+0] - mean) * rstd * g[ch0+0] + be[ch0+0];
            float o1 = hv.y + (vals[mt*4+1] - mean) * rstd * g[ch0+1] + be[ch0+1];
            float o2 = hv.z + (vals[mt*4+2] - mean) * rstd * g[ch0+2] + be[ch0+2];
            float o3 = hv.w + (vals[mt*4+3] - mean) * rstd * g[ch0+3] + be[ch0+3];
            float4 st = {o0, o1, o2, o3};
            *(float4*)(h + (size_t)n * 64 + ch0) = st;
            uint2 pk;
            pk.x = pack_bf16x2(o0, o1);
            pk.y = pack_bf16x2(o2, o3);
            *(uint2*)(h2 + (size_t)n * 32 + mt * 8 + quad * 2) = pk;
        }
    }
}

// ---------------------------------------------------------------------------
// Local decoder: out_local = silu(h @ W1 + b1) @ W2 + b2  -> [NN, 6]
// ---------------------------------------------------------------------------
__global__ __launch_bounds__(256) void dec_local_kernel(
    const float* __restrict__ h,
    const float* __restrict__ W1, const float* __restrict__ b1,
    const float* __restrict__ W2, const float* __restrict__ b2,
    float* __restrict__ out)
{
    __shared__ float mid_sh[4][64];
    const int lane = threadIdx.x & 63;
    const int w    = threadIdx.x >> 6;
    const int n = blockIdx.x * 4 + w;
    if (n >= NN) return;

    float a = b1[lane];
    for (int k = 0; k < 64; ++k)
        a = fmaf(h[n * 64 + k], W1[k * 64 + lane], a);
    mid_sh[w][lane] = silu_f(a);
    if (lane < 6) {
        float o = b2[lane];
        for (int k = 0; k < 64; ++k)
            o = fmaf(mid_sh[w][k], W2[k * 6 + lane], o);
        out[n * 6 + lane] = o;
    }
}

// ---------------------------------------------------------------------------
// Pooling: pooled[g][c] = sum_{batch[n]==g} h[n][c];  cnt[g] = count
// ---------------------------------------------------------------------------
__global__ __launch_bounds__(256) void pool_kernel(
    const float* __restrict__ h, const int* __restrict__ batch,
    float* __restrict__ pooled, float* __restrict__ cnt)
{
    const int c   = threadIdx.x & 63;
    const int rep = blockIdx.x * 4 + (threadIdx.x >> 6);   // 1024 reps
    float acc[NG] = {0.f, 0.f, 0.f, 0.f};
    float cl[NG]  = {0.f, 0.f, 0.f, 0.f};
    for (int n = rep; n < NN; n += 1024) {
        int b = batch[n];
        float v = h[n * 64 + c];
#pragma unroll
        for (int gph = 0; gph < NG; ++gph) {
            if (b == gph) { acc[gph] += v; cl[gph] += 1.0f; }
        }
    }
#pragma unroll
    for (int gph = 0; gph < NG; ++gph) {
        atomicAdd(&pooled[gph * 64 + c], acc[gph]);
        if (c == 0) atomicAdd(&cnt[gph], cl[gph]);
    }
}

// ---------------------------------------------------------------------------
// Global decoder: out_global = silu(mean_pool @ W1 + b1) @ W2 + b2 -> [4,4]
// ---------------------------------------------------------------------------
__global__ __launch_bounds__(256) void dec_global_kernel(
    const float* __restrict__ pooled, const float* __restrict__ cnt,
    const float* __restrict__ W1, const float* __restrict__ b1,
    const float* __restrict__ W2, const float* __restrict__ b2,
    float* __restrict__ out)
{
    __shared__ float mid_sh[4][32];
    const int lane = threadIdx.x & 63;
    const int gph  = threadIdx.x >> 6;
    float inv = 1.0f / fmaxf(cnt[gph], 1.0f);
    if (lane < 32) {
        float a = b1[lane];
        for (int k = 0; k < 64; ++k)
            a = fmaf(pooled[gph * 64 + k] * inv, W1[k * 32 + lane], a);
        mid_sh[gph][lane] = silu_f(a);
    }
    __syncthreads();
    if (lane < 4) {
        float o = b2[lane];
        for (int k = 0; k < 32; ++k)
            o = fmaf(mid_sh[gph][k], W2[k * 4 + lane], o);
        out[gph * 4 + lane] = o;
    }
}

// ---------------------------------------------------------------------------
extern "C" void kernel_launch(void* const* d_in, const int* in_sizes, int n_in,
                              void* d_out, int out_size, void* d_ws, size_t ws_size,
                              hipStream_t stream)
{
    const float* x      = (const float*)d_in[0];
    const int*   ei     = (const int*)  d_in[1];
    const float* ea     = (const float*)d_in[2];
    const int*   batch  = (const int*)  d_in[3];
    const float* case_p = (const float*)d_in[4];
    const float* bc_p   = (const float*)d_in[5];
    const float* enc_W1 = (const float*)d_in[6];
    const float* enc_b1 = (const float*)d_in[7];
    const float* enc_W2 = (const float*)d_in[8];
    const float* enc_b2 = (const float*)d_in[9];
    const float* enc_g  = (const float*)d_in[10];
    const float* enc_be = (const float*)d_in[11];
    const float* eW1    = (const float*)d_in[12];
    const float* eb1    = (const float*)d_in[13];
    const float* eW2    = (const float*)d_in[14];
    const float* eb2    = (const float*)d_in[15];
    const float* eg     = (const float*)d_in[16];
    const float* ebe    = (const float*)d_in[17];
    const float* nW1    = (const float*)d_in[18];
    const float* nb1    = (const float*)d_in[19];
    const float* nW2    = (const float*)d_in[20];
    const float* nb2    = (const float*)d_in[21];
    const float* ng     = (const float*)d_in[22];
    const float* nbe    = (const float*)d_in[23];
    const float* dlW1   = (const float*)d_in[24];
    const float* dlb1   = (const float*)d_in[25];
    const float* dlW2   = (const float*)d_in[26];
    const float* dlb2   = (const float*)d_in[27];
    const float* dgW1   = (const float*)d_in[28];
    const float* dgb1   = (const float*)d_in[29];
    const float* dgW2   = (const float*)d_in[30];
    const float* dgb2   = (const float*)d_in[31];

    float* out = (float*)d_out;

    char* ws = (char*)d_ws;
    size_t off_b = 0;
    auto alloc = [&](size_t bytes) {
        void* p = ws + off_b;
        off_b = (off_b + bytes + 255) & ~(size_t)255;
        return p;
    };
    const size_t hBytes = (size_t)NN * H * sizeof(float);     // 12.8 MB
    float*        h      = (float*)alloc(hBytes);
    float*        agg    = (float*)alloc(hBytes);
    unsigned int* h2     = (unsigned int*)alloc((size_t)NN * 32 * 4);  // bf16 mirror
    float*        pooled = (float*)alloc(256 * sizeof(float));
    float*        cnt    = (float*)alloc(4 * sizeof(float));
    int*          deg    = (int*)alloc((NN + 1) * sizeof(int));
    int*          offs   = (int*)alloc((NN + 1) * sizeof(int));
    int*          cursor = (int*)alloc((NN + 1) * sizeof(int));
    int*          sidx   = (int*)alloc((size_t)NE * sizeof(int));
    int*          sdst   = (int*)alloc((size_t)NE * sizeof(int));
    int*          ssrc   = (int*)alloc((size_t)NE * sizeof(int));
    uint4*        ea_pk  = (uint4*)alloc((size_t)NE * sizeof(uint4));  // 25.6 MB
    short*        eW1pk  = (short*)alloc((size_t)NL * 10240 * sizeof(short));
    short*        eW2pk  = (short*)alloc((size_t)NL * 4096 * sizeof(short));
    short*        nW1pk  = (short*)alloc((size_t)NL * 8192 * sizeof(short));
    short*        nW2pk  = (short*)alloc((size_t)NL * 4096 * sizeof(short));

    hipMemsetAsync(pooled, 0, (256 + 4 + 64) * sizeof(float), stream);
    hipMemsetAsync(deg, 0, (NN + 1) * sizeof(int), stream);

    // counting sort of edges by dst + operand pre-pack (deterministic per call)
    degree_kernel<<<(NE + 255) / 256, 256, 0, stream>>>(ei, deg);
    scan_kernel<<<1, 1024, 0, stream>>>(deg, offs, cursor);
    scatter_kernel<<<(NE + 255) / 256, 256, 0, stream>>>(ei, cursor, sidx, sdst, ssrc);
    ea_pack_kernel<<<(NE + 255) / 256, 256, 0, stream>>>(ea, sidx, ea_pk);
    pack_weights_kernel<<<dim3(104, NL), 256, 0, stream>>>(
        eW1, eW2, nW1, nW2, eW1pk, eW2pk, nW1pk, nW2pk);

    const int nodeBlocks = (NN + 63) / 64;    // 782
    encoder_kernel<<<nodeBlocks, 256, 0, stream>>>(
        x, batch, case_p, bc_p, enc_W1, enc_b1, enc_W2, enc_b2, enc_g, enc_be,
        h, h2);

    for (int l = 0; l < NL; ++l) {
        hipMemsetAsync(agg, 0, hBytes, stream);
        edge_kernel<<<NE / 64, 256, 0, stream>>>(
            h2, sdst, ssrc, ea_pk,
            eW1pk + (size_t)l * 10240, eb1 + l * H,
            eW2pk + (size_t)l * 4096,  eb2 + l * H,
            eg + l * H, ebe + l * H, agg);
        node_kernel<<<nodeBlocks, 256, 0, stream>>>(
            h, h2, agg,
            nW1pk + (size_t)l * 8192, nb1 + l * H,
            nW2pk + (size_t)l * 4096, nb2 + l * H,
            ng + l * H, nbe + l * H);
    }

    dec_local_kernel<<<(NN + 3) / 4, 256, 0, stream>>>(h, dlW1, dlb1, dlW2, dlb2, out);
    pool_kernel<<<256, 256, 0, stream>>>(h, batch, pooled, cnt);
    dec_global_kernel<<<1, 256, 0, stream>>>(pooled, cnt, dgW1, dgb1, dgW2, dgb2,
                                             out + (size_t)NN * 6);
}

// Round 7
// 1778.056 us; speedup vs baseline: 16.6757x; 1.0389x over previous
//
#include <hip/hip_runtime.h>
#include <cmath>

// Problem constants (from reference)
constexpr int NN = 50000;      // nodes
constexpr int NE = 1600000;    // edges
constexpr int H  = 64;         // hidden
constexpr int NL = 5;          // layers
constexpr int NG = 4;          // graphs
constexpr int EIN = 2 * H + 5; // 133
constexpr int NIN = 2 * H;     // 128

typedef short bf16x8 __attribute__((ext_vector_type(8)));
typedef float f32x4  __attribute__((ext_vector_type(4)));

__device__ __forceinline__ float silu_f(float x) {
    return x / (1.0f + __expf(-x));
}

// round-to-nearest-even fp32 -> bf16 bits
__device__ __forceinline__ unsigned int f2bf(float f) {
    unsigned int u = __float_as_uint(f);
    u += 0x7fffu + ((u >> 16) & 1u);
    return u >> 16;
}
__device__ __forceinline__ unsigned int pack_bf16x2(float x, float y) {
    return f2bf(x) | (f2bf(y) << 16);
}

// ---------------------------------------------------------------------------
// Counting sort of edges by dst
// ---------------------------------------------------------------------------
__global__ __launch_bounds__(256) void degree_kernel(
    const int* __restrict__ ei, int* __restrict__ deg)
{
    int e = blockIdx.x * 256 + threadIdx.x;
    if (e < NE) atomicAdd(&deg[ei[NE + e]], 1);
}

// Hierarchical exclusive scan: 49 parallel block scans -> 1-wave scan of
// block sums -> add block bases.  (Old single-block version serialized 50
// Hillis-Steele passes on one CU.)
__global__ __launch_bounds__(1024) void scan1_kernel(
    const int* __restrict__ deg, int* __restrict__ off, int* __restrict__ bsum)
{
    __shared__ int sh[1024];
    const int tid = threadIdx.x;
    int i = blockIdx.x * 1024 + tid;
    int v = (i < NN) ? deg[i] : 0;
    sh[tid] = v;
    __syncthreads();
    for (int d = 1; d < 1024; d <<= 1) {
        int t = (tid >= d) ? sh[tid - d] : 0;
        __syncthreads();
        sh[tid] += t;
        __syncthreads();
    }
    if (i < NN) off[i] = sh[tid] - v;          // block-local exclusive
    if (tid == 1023) bsum[blockIdx.x] = sh[1023];
}

__global__ __launch_bounds__(64) void scan2_kernel(
    const int* __restrict__ bsum, int* __restrict__ bbase, int nb)
{
    int lane = threadIdx.x;
    int v = (lane < nb) ? bsum[lane] : 0;
    int orig = v;
    for (int d = 1; d < 64; d <<= 1) {
        int t = __shfl_up(v, d);
        if (lane >= d) v += t;
    }
    bbase[lane] = v - orig;                    // exclusive
}

__global__ __launch_bounds__(1024) void scan3_kernel(
    int* __restrict__ off, const int* __restrict__ bbase,
    int* __restrict__ cursor)
{
    int i = blockIdx.x * 1024 + threadIdx.x;
    if (i < NN) {
        int o = off[i] + bbase[blockIdx.x];
        off[i] = o;
        cursor[i] = o;
    }
}

__global__ __launch_bounds__(256) void scatter_kernel(
    const int* __restrict__ ei, int* __restrict__ cursor,
    int* __restrict__ sidx, int* __restrict__ sdst, int* __restrict__ ssrc)
{
    int e = blockIdx.x * 256 + threadIdx.x;
    if (e < NE) {
        int d = ei[NE + e];
        int p = atomicAdd(&cursor[d], 1);
        sidx[p] = e;
        sdst[p] = d;
        ssrc[p] = ei[e];
    }
}

// ---------------------------------------------------------------------------
// Pre-pack edge_attr into sorted-edge order, bf16, 16B/edge (5 vals + 3 zero)
// ---------------------------------------------------------------------------
__global__ __launch_bounds__(256) void ea_pack_kernel(
    const float* __restrict__ ea, const int* __restrict__ sidx,
    uint4* __restrict__ ea_pk)
{
    int p = blockIdx.x * 256 + threadIdx.x;
    if (p < NE) {
        const float* s = ea + (size_t)sidx[p] * 5;
        uint4 v;
        v.x = pack_bf16x2(s[0], s[1]);
        v.y = pack_bf16x2(s[2], s[3]);
        v.z = pack_bf16x2(s[4], 0.0f);
        v.w = 0u;
        ea_pk[p] = v;
    }
}

// ---------------------------------------------------------------------------
// Pre-pack MLP weights into MFMA A-fragment order (bf16).
// elem(ks, mt, lane, j) = W[k = ks*32 + (lane>>4)*8 + j][ch = mt*16 + (lane&15)]
// edge W1: K 133->160 (10240/layer); edge W2: 4096; node W1: 8192;
// node W2: 4096 (26624/layer). Dec (l==0 only): dlW1 4096, dlW2 (6->16 pad) 1024.
// ---------------------------------------------------------------------------
__global__ __launch_bounds__(256) void pack_weights_kernel(
    const float* __restrict__ eW1, const float* __restrict__ eW2,
    const float* __restrict__ nW1, const float* __restrict__ nW2,
    const float* __restrict__ dlW1, const float* __restrict__ dlW2,
    short* __restrict__ eW1pk, short* __restrict__ eW2pk,
    short* __restrict__ nW1pk, short* __restrict__ nW2pk,
    short* __restrict__ dlW1pk, short* __restrict__ dlW2pk)
{
    int l = blockIdx.y;
    int t = blockIdx.x * 256 + threadIdx.x;
    if (t < 10240) {
        int j = t & 7, lane = (t >> 3) & 63, mt = (t >> 9) & 3, ks = t >> 11;
        int k  = ks * 32 + (lane >> 4) * 8 + j;
        int ch = mt * 16 + (lane & 15);
        float v = (k < EIN) ? eW1[(size_t)l * EIN * H + k * H + ch] : 0.0f;
        eW1pk[(size_t)l * 10240 + t] = (short)f2bf(v);
    } else if (t < 14336) {
        int t2 = t - 10240;
        int j = t2 & 7, lane = (t2 >> 3) & 63, mt = (t2 >> 9) & 3, ks = t2 >> 11;
        int k = ks * 32 + (lane >> 4) * 8 + j;
        int ch = mt * 16 + (lane & 15);
        eW2pk[(size_t)l * 4096 + t2] = (short)f2bf(eW2[(size_t)l * H * H + k * H + ch]);
    } else if (t < 22528) {
        int t3 = t - 14336;
        int j = t3 & 7, lane = (t3 >> 3) & 63, mt = (t3 >> 9) & 3, ks = t3 >> 11;
        int k = ks * 32 + (lane >> 4) * 8 + j;
        int ch = mt * 16 + (lane & 15);
        nW1pk[(size_t)l * 8192 + t3] = (short)f2bf(nW1[(size_t)l * NIN * H + k * H + ch]);
    } else if (t < 26624) {
        int t4 = t - 22528;
        int j = t4 & 7, lane = (t4 >> 3) & 63, mt = (t4 >> 9) & 3, ks = t4 >> 11;
        int k = ks * 32 + (lane >> 4) * 8 + j;
        int ch = mt * 16 + (lane & 15);
        nW2pk[(size_t)l * 4096 + t4] = (short)f2bf(nW2[(size_t)l * H * H + k * H + ch]);
    } else if (t < 30720) {
        if (l == 0) {
            int t5 = t - 26624;
            int j = t5 & 7, lane = (t5 >> 3) & 63, mt = (t5 >> 9) & 3, ks = t5 >> 11;
            int k = ks * 32 + (lane >> 4) * 8 + j;
            int ch = mt * 16 + (lane & 15);
            dlW1pk[t5] = (short)f2bf(dlW1[k * H + ch]);
        }
    } else if (t < 31744) {
        if (l == 0) {
            int t6 = t - 30720;
            int j = t6 & 7, lane = (t6 >> 3) & 63, ks = t6 >> 9;
            int k = ks * 32 + (lane >> 4) * 8 + j;
            int m = lane & 15;
            float v = (m < 6) ? dlW2[k * 6 + m] : 0.0f;
            dlW2pk[t6] = (short)f2bf(v);
        }
    }
}

// ---------------------------------------------------------------------------
// Encoder: h = LN(silu([x, gv[batch]] @ W1 + b1) @ W2 + b2); writes h (fp32)
// and h2 (bf16 mirror used by MFMA staging).
// ---------------------------------------------------------------------------
__global__ __launch_bounds__(256) void encoder_kernel(
    const float* __restrict__ x, const int* __restrict__ batch,
    const float* __restrict__ case_p, const float* __restrict__ bc_p,
    const float* __restrict__ W1, const float* __restrict__ b1,
    const float* __restrict__ W2, const float* __restrict__ b2,
    const float* __restrict__ g, const float* __restrict__ be,
    float* __restrict__ h, unsigned int* __restrict__ h2)
{
    __shared__ float in_sh[64 * 17];
    __shared__ float m1_sh[64 * 65];
    __shared__ float red_sh[2 * 4 * 64];
    const int lane = threadIdx.x & 63;
    const int w    = threadIdx.x >> 6;
    const int wb   = __builtin_amdgcn_readfirstlane(w * 16);
    const int n0   = blockIdx.x * 64;

    for (int i = 0; i < 16; ++i) {
        int slot = w * 16 + i;
        int n = n0 + slot;
        if (n < NN && lane < 16) {
            float v;
            if (lane < 8) v = x[n * 8 + lane];
            else {
                int b = batch[n];
                v = (lane < 12) ? case_p[b * 4 + (lane - 8)]
                                : bc_p[b * 4 + (lane - 12)];
            }
            in_sh[slot * 17 + lane] = v;
        }
    }
    __syncthreads();

    float acc[16];
#pragma unroll
    for (int c = 0; c < 16; ++c) acc[c] = b1[wb + c];
    for (int k = 0; k < 16; ++k) {
        float a = in_sh[lane * 17 + k];
        const float4* wr = (const float4*)(W1 + k * 64 + wb);
        float4 w0 = wr[0], w1 = wr[1], w2 = wr[2], w3 = wr[3];
        acc[0]  = fmaf(a, w0.x, acc[0]);  acc[1]  = fmaf(a, w0.y, acc[1]);
        acc[2]  = fmaf(a, w0.z, acc[2]);  acc[3]  = fmaf(a, w0.w, acc[3]);
        acc[4]  = fmaf(a, w1.x, acc[4]);  acc[5]  = fmaf(a, w1.y, acc[5]);
        acc[6]  = fmaf(a, w1.z, acc[6]);  acc[7]  = fmaf(a, w1.w, acc[7]);
        acc[8]  = fmaf(a, w2.x, acc[8]);  acc[9]  = fmaf(a, w2.y, acc[9]);
        acc[10] = fmaf(a, w2.z, acc[10]); acc[11] = fmaf(a, w2.w, acc[11]);
        acc[12] = fmaf(a, w3.x, acc[12]); acc[13] = fmaf(a, w3.y, acc[13]);
        acc[14] = fmaf(a, w3.z, acc[14]); acc[15] = fmaf(a, w3.w, acc[15]);
    }
#pragma unroll
    for (int c = 0; c < 16; ++c) m1_sh[lane * 65 + wb + c] = silu_f(acc[c]);
    __syncthreads();

    float acc2[16];
#pragma unroll
    for (int c = 0; c < 16; ++c) acc2[c] = b2[wb + c];
    for (int k = 0; k < 64; ++k) {
        float a = m1_sh[lane * 65 + k];
        const float4* wr = (const float4*)(W2 + k * 64 + wb);
        float4 w0 = wr[0], w1 = wr[1], w2 = wr[2], w3 = wr[3];
        acc2[0]  = fmaf(a, w0.x, acc2[0]);  acc2[1]  = fmaf(a, w0.y, acc2[1]);
        acc2[2]  = fmaf(a, w0.z, acc2[2]);  acc2[3]  = fmaf(a, w0.w, acc2[3]);
        acc2[4]  = fmaf(a, w1.x, acc2[4]);  acc2[5]  = fmaf(a, w1.y, acc2[5]);
        acc2[6]  = fmaf(a, w1.z, acc2[6]);  acc2[7]  = fmaf(a, w1.w, acc2[7]);
        acc2[8]  = fmaf(a, w2.x, acc2[8]);  acc2[9]  = fmaf(a, w2.y, acc2[9]);
        acc2[10] = fmaf(a, w2.z, acc2[10]); acc2[11] = fmaf(a, w2.w, acc2[11]);
        acc2[12] = fmaf(a, w3.x, acc2[12]); acc2[13] = fmaf(a, w3.y, acc2[13]);
        acc2[14] = fmaf(a, w3.z, acc2[14]); acc2[15] = fmaf(a, w3.w, acc2[15]);
    }

    float s1 = 0.f, s2 = 0.f;
#pragma unroll
    for (int c = 0; c < 16; ++c) { s1 += acc2[c]; s2 += acc2[c] * acc2[c]; }
    red_sh[w * 64 + lane] = s1;
    red_sh[256 + w * 64 + lane] = s2;
    __syncthreads();
    float t1 = 0.f, t2 = 0.f;
#pragma unroll
    for (int j = 0; j < 4; ++j) {
        t1 += red_sh[j * 64 + lane];
        t2 += red_sh[256 + j * 64 + lane];
    }
    float mean = t1 * (1.0f / 64.0f);
    float var  = t2 * (1.0f / 64.0f) - mean * mean;
    float rstd = rsqrtf(var + 1e-5f);

    int n = n0 + lane;
    if (n < NN) {
        float vals[16];
#pragma unroll
        for (int c = 0; c < 16; ++c) {
            int ch = wb + c;
            vals[c] = (acc2[c] - mean) * rstd * g[ch] + be[ch];
            h[n * 64 + ch] = vals[c];
        }
        uint4 p0, p1;
        p0.x = pack_bf16x2(vals[0], vals[1]);   p0.y = pack_bf16x2(vals[2], vals[3]);
        p0.z = pack_bf16x2(vals[4], vals[5]);   p0.w = pack_bf16x2(vals[6], vals[7]);
        p1.x = pack_bf16x2(vals[8], vals[9]);   p1.y = pack_bf16x2(vals[10], vals[11]);
        p1.z = pack_bf16x2(vals[12], vals[13]); p1.w = pack_bf16x2(vals[14], vals[15]);
        *(uint4*)(h2 + (size_t)n * 32 + w * 8)     = p0;
        *(uint4*)(h2 + (size_t)n * 32 + w * 8 + 4) = p1;
    }
}

// ---------------------------------------------------------------------------
// Edge MLP via MFMA + segmented scatter-add over dst-sorted edges.
// uint4 staging (b128), DPP width-16 scan (no DS-pipe shuffles), MID aliases
// B1 (wave-local). No __syncthreads anywhere.
// ---------------------------------------------------------------------------
__global__ __launch_bounds__(256, 7) void edge_kernel(
    const unsigned int* __restrict__ h2,
    const int* __restrict__ sdst, const int* __restrict__ ssrc,
    const uint4* __restrict__ ea_pk,
    const short* __restrict__ W1pk, const float* __restrict__ b1,
    const short* __restrict__ W2pk, const float* __restrict__ b2,
    const float* __restrict__ g, const float* __restrict__ be,
    float* __restrict__ agg)
{
    __shared__ unsigned int lds[4 * 1344];
    const int lane = threadIdx.x & 63;
    const int w    = threadIdx.x >> 6;
    const int quad = lane >> 4;
    const int l15  = lane & 15;
    const int e0   = blockIdx.x * 64 + w * 16;     // this wave's 16 edges
    unsigned int* B1  = lds + w * 1344;            // 16 rows x 84 words
    unsigned int* MID = B1;                        // aliased; stride 36

    // stage h2: 32 half-rows (edge x {dst,src}) x 8 uint4; 4 iters of b128
#pragma unroll
    for (int i = 0; i < 4; ++i) {
        int hr   = i * 8 + (lane >> 3);            // half-row 0..31
        int p    = e0 + (hr >> 1);
        int node = (hr & 1) ? ssrc[p] : sdst[p];
        int w4   = (lane & 7) * 4;
        uint4 v = *(const uint4*)(h2 + (size_t)node * 32 + w4);
        *(uint4*)(B1 + (hr >> 1) * 84 + (hr & 1) * 32 + w4) = v;
    }
    // ea (words 64..67): lanes 0..15
    if (lane < 16) {
        uint4 v = ea_pk[e0 + lane];
        *(uint4*)(B1 + lane * 84 + 64) = v;
    }
    // zeros (words 68..79): lanes 0..47
    if (lane < 48) {
        uint4 z = {0u, 0u, 0u, 0u};
        *(uint4*)(B1 + (lane / 3) * 84 + 68 + (lane % 3) * 4) = z;
    }

    // GEMM1: C1^T[ch][edge], K=160 (5 ks)
    f32x4 acc1[4] = {{0,0,0,0},{0,0,0,0},{0,0,0,0},{0,0,0,0}};
    const unsigned int* brow = B1 + l15 * 84;
    for (int ks = 0; ks < 5; ++ks) {
        bf16x8 bfrag = *(const bf16x8*)(brow + ks * 16 + quad * 4);
        const short* apk = W1pk + (size_t)(ks * 4) * 512 + lane * 8;
#pragma unroll
        for (int mt = 0; mt < 4; ++mt) {
            bf16x8 afrag = *(const bf16x8*)(apk + mt * 512);
            acc1[mt] = __builtin_amdgcn_mfma_f32_16x16x32_bf16(
                afrag, bfrag, acc1[mt], 0, 0, 0);
        }
    }
    // epilogue 1: bias + silu -> MID (aliased over B1; all B1 reads complete)
#pragma unroll
    for (int mt = 0; mt < 4; ++mt) {
        int ch0 = mt * 16 + quad * 4;
        float v0 = silu_f(acc1[mt][0] + b1[ch0 + 0]);
        float v1 = silu_f(acc1[mt][1] + b1[ch0 + 1]);
        float v2 = silu_f(acc1[mt][2] + b1[ch0 + 2]);
        float v3 = silu_f(acc1[mt][3] + b1[ch0 + 3]);
        uint2 pk;
        pk.x = pack_bf16x2(v0, v1);
        pk.y = pack_bf16x2(v2, v3);
        *(uint2*)(MID + l15 * 36 + mt * 8 + quad * 2) = pk;
    }

    // GEMM2: C2^T[ch][edge], K=64 (2 ks)
    f32x4 acc2[4] = {{0,0,0,0},{0,0,0,0},{0,0,0,0},{0,0,0,0}};
    const unsigned int* mrow = MID + l15 * 36;
    for (int ks = 0; ks < 2; ++ks) {
        bf16x8 bfrag = *(const bf16x8*)(mrow + ks * 16 + quad * 4);
        const short* apk = W2pk + (size_t)(ks * 4) * 512 + lane * 8;
#pragma unroll
        for (int mt = 0; mt < 4; ++mt) {
            bf16x8 afrag = *(const bf16x8*)(apk + mt * 512);
            acc2[mt] = __builtin_amdgcn_mfma_f32_16x16x32_bf16(
                afrag, bfrag, acc2[mt], 0, 0, 0);
        }
    }

    // bias + LN over the 64 channels of this lane's edge
    float vals[16];
    float s1 = 0.f, s2 = 0.f;
#pragma unroll
    for (int mt = 0; mt < 4; ++mt) {
#pragma unroll
        for (int r = 0; r < 4; ++r) {
            int ch = mt * 16 + quad * 4 + r;
            float vv = acc2[mt][r] + b2[ch];
            vals[mt * 4 + r] = vv;
            s1 += vv; s2 += vv * vv;
        }
    }
    s1 += __shfl_xor(s1, 16); s1 += __shfl_xor(s1, 32);
    s2 += __shfl_xor(s2, 16); s2 += __shfl_xor(s2, 32);
    float mean = s1 * (1.0f / 64.0f);
    float var  = s2 * (1.0f / 64.0f) - mean * mean;
    float rstd = rsqrtf(var + 1e-5f);
#pragma unroll
    for (int mt = 0; mt < 4; ++mt) {
#pragma unroll
        for (int r = 0; r < 4; ++r) {
            int ch = mt * 16 + quad * 4 + r;
            vals[mt * 4 + r] = (vals[mt * 4 + r] - mean) * rstd * g[ch] + be[ch];
        }
    }

    // segmented inclusive scan over the wave's 16 edges; width-16 shuffles
    // lower to DPP row_shr (VALU pipe, no ds_bpermute)
    int d_l = sdst[e0 + l15];
#pragma unroll
    for (int delta = 1; delta < 16; delta <<= 1) {
        int d_up = __shfl_up(d_l, delta, 16);
        bool merge = (l15 >= delta) && (d_up == d_l);
#pragma unroll
        for (int c = 0; c < 16; ++c) {
            float vu = __shfl_up(vals[c], delta, 16);
            if (merge) vals[c] += vu;
        }
    }
    int d_next = __shfl_down(d_l, 1, 16);
    bool last = (l15 == 15) || (d_next != d_l);
    if (last) {
#pragma unroll
        for (int mt = 0; mt < 4; ++mt) {
#pragma unroll
            for (int r = 0; r < 4; ++r) {
                int ch = mt * 16 + quad * 4 + r;
                atomicAdd(&agg[(size_t)d_l * 64 + ch], vals[mt * 4 + r]);
            }
        }
    }
}

// ---------------------------------------------------------------------------
// Node MLP via MFMA + residual: h = h + LN(silu([h,agg]@W1+b1)@W2+b2)
// uint4/float4 staging; no __syncthreads. Updates h and h2.
// ---------------------------------------------------------------------------
__global__ __launch_bounds__(256, 4) void node_kernel(
    float* __restrict__ h, unsigned int* __restrict__ h2,
    const float* __restrict__ agg,
    const short* __restrict__ W1pk, const float* __restrict__ b1,
    const short* __restrict__ W2pk, const float* __restrict__ b2,
    const float* __restrict__ g, const float* __restrict__ be)
{
    __shared__ unsigned int lds[4 * 1088];
    const int lane = threadIdx.x & 63;
    const int w    = threadIdx.x >> 6;
    const int quad = lane >> 4;
    const int l15  = lane & 15;
    const int n0   = blockIdx.x * 64 + w * 16;     // this wave's 16 nodes
    unsigned int* B1  = lds + w * 1088;            // 16 rows x 68 words
    unsigned int* MID = B1;                        // aliased; stride 36

    // stage h2 rows (words 0..31): 16 rows x 8 uint4; 2 iters
#pragma unroll
    for (int i = 0; i < 2; ++i) {
        int row = i * 8 + (lane >> 3);
        int n = n0 + row; if (n >= NN) n = NN - 1;
        int w4 = (lane & 7) * 4;
        uint4 v = *(const uint4*)(h2 + (size_t)n * 32 + w4);
        *(uint4*)(B1 + row * 68 + w4) = v;
    }
    // stage agg (fp32 -> bf16, words 32..63): 16 rows x 16 float4; 4 iters
#pragma unroll
    for (int i = 0; i < 4; ++i) {
        int row = i * 4 + (lane >> 4);
        int n = n0 + row; if (n >= NN) n = NN - 1;
        int f4 = lane & 15;
        float4 v = *(const float4*)(agg + (size_t)n * 64 + f4 * 4);
        uint2 pk;
        pk.x = pack_bf16x2(v.x, v.y);
        pk.y = pack_bf16x2(v.z, v.w);
        *(uint2*)(B1 + row * 68 + 32 + f4 * 2) = pk;
    }

    // GEMM1: K=128 (4 ks)
    f32x4 acc1[4] = {{0,0,0,0},{0,0,0,0},{0,0,0,0},{0,0,0,0}};
    const unsigned int* brow = B1 + l15 * 68;
    for (int ks = 0; ks < 4; ++ks) {
        bf16x8 bfrag = *(const bf16x8*)(brow + ks * 16 + quad * 4);
        const short* apk = W1pk + (size_t)(ks * 4) * 512 + lane * 8;
#pragma unroll
        for (int mt = 0; mt < 4; ++mt) {
            bf16x8 afrag = *(const bf16x8*)(apk + mt * 512);
            acc1[mt] = __builtin_amdgcn_mfma_f32_16x16x32_bf16(
                afrag, bfrag, acc1[mt], 0, 0, 0);
        }
    }
#pragma unroll
    for (int mt = 0; mt < 4; ++mt) {
        int ch0 = mt * 16 + quad * 4;
        float v0 = silu_f(acc1[mt][0] + b1[ch0 + 0]);
        float v1 = silu_f(acc1[mt][1] + b1[ch0 + 1]);
        float v2 = silu_f(acc1[mt][2] + b1[ch0 + 2]);
        float v3 = silu_f(acc1[mt][3] + b1[ch0 + 3]);
        uint2 pk;
        pk.x = pack_bf16x2(v0, v1);
        pk.y = pack_bf16x2(v2, v3);
        *(uint2*)(MID + l15 * 36 + mt * 8 + quad * 2) = pk;
    }

    // GEMM2: K=64 (2 ks)
    f32x4 acc2[4] = {{0,0,0,0},{0,0,0,0},{0,0,0,0},{0,0,0,0}};
    const unsigned int* mrow = MID + l15 * 36;
    for (int ks = 0; ks < 2; ++ks) {
        bf16x8 bfrag = *(const bf16x8*)(mrow + ks * 16 + quad * 4);
        const short* apk = W2pk + (size_t)(ks * 4) * 512 + lane * 8;
#pragma unroll
        for (int mt = 0; mt < 4; ++mt) {
            bf16x8 afrag = *(const bf16x8*)(apk + mt * 512);
            acc2[mt] = __builtin_amdgcn_mfma_f32_16x16x32_bf16(
                afrag, bfrag, acc2[mt], 0, 0, 0);
        }
    }

    // bias + LN over the 64 channels of this lane's node
    float vals[16];
    float s1 = 0.f, s2 = 0.f;
#pragma unroll
    for (int mt = 0; mt < 4; ++mt) {
#pragma unroll
        for (int r = 0; r < 4; ++r) {
            int ch = mt * 16 + quad * 4 + r;
            float vv = acc2[mt][r] + b2[ch];
            vals[mt * 4 + r] = vv;
            s1 += vv; s2 += vv * vv;
        }
    }
    s1 += __shfl_xor(s1, 16); s1 += __shfl_xor(s1, 32);
    s2 += __shfl_xor(s2, 16); s2 += __shfl_xor(s2, 32);
    float mean = s1 * (1.0f / 64.0f);
    float var  = s2 * (1.0f / 64.0f) - mean * mean;
    float rstd = rsqrtf(var + 1e-5f);

    int n = n0 + l15;
    if (n < NN) {
#pragma unroll
        for (int mt = 0; mt < 4; ++mt) {
            int ch0 = mt * 16 + quad * 4;
            float4 hv = *(const float4*)(h + (size_t)n * 64 + ch0);
            float o0 = hv.x + (vals[mt*4+0] - mean) * rstd * g[ch0+0] + be[ch0+0];
            float o1 = hv.y + (vals[mt*4+1] - mean) * rstd * g[ch0+1] + be[ch0+1];
            float o2 = hv.z + (vals[mt*4+2] - mean) * rstd * g[ch0+2] + be[ch0+2];
            float o3 = hv.w + (vals[mt*4+3] - mean) * rstd * g[ch0+3] + be[ch0+3];
            float4 st = {o0, o1, o2, o3};
            *(float4*)(h + (size_t)n * 64 + ch0) = st;
            uint2 pk;
            pk.x = pack_bf16x2(o0, o1);
            pk.y = pack_bf16x2(o2, o3);
            *(uint2*)(h2 + (size_t)n * 32 + mt * 8 + quad * 2) = pk;
        }
    }
}

// ---------------------------------------------------------------------------
// Local decoder via MFMA: out_local = silu(h @ W1 + b1) @ W2 + b2 -> [NN, 6]
// Wave owns 16 nodes; GEMM2 output padded 6->16; no __syncthreads.
// ---------------------------------------------------------------------------
__global__ __launch_bounds__(256, 7) void dec_local_kernel(
    const unsigned int* __restrict__ h2,
    const short* __restrict__ W1pk, const float* __restrict__ b1,
    const short* __restrict__ W2pk, const float* __restrict__ b2,
    float* __restrict__ out)
{
    __shared__ unsigned int lds[4 * 576];
    const int lane = threadIdx.x & 63;
    const int w    = threadIdx.x >> 6;
    const int quad = lane >> 4;
    const int l15  = lane & 15;
    const int n0   = blockIdx.x * 64 + w * 16;
    unsigned int* B1  = lds + w * 576;             // 16 rows x 36 words
    unsigned int* MID = B1;                        // aliased; stride 36

    // stage h2: 16 rows x 8 uint4; 2 iters
#pragma unroll
    for (int i = 0; i < 2; ++i) {
        int row = i * 8 + (lane >> 3);
        int n = n0 + row; if (n >= NN) n = NN - 1;
        int w4 = (lane & 7) * 4;
        uint4 v = *(const uint4*)(h2 + (size_t)n * 32 + w4);
        *(uint4*)(B1 + row * 36 + w4) = v;
    }

    // GEMM1: K=64 (2 ks), M=64 (4 mt)
    f32x4 acc1[4] = {{0,0,0,0},{0,0,0,0},{0,0,0,0},{0,0,0,0}};
    const unsigned int* brow = B1 + l15 * 36;
    for (int ks = 0; ks < 2; ++ks) {
        bf16x8 bfrag = *(const bf16x8*)(brow + ks * 16 + quad * 4);
        const short* apk = W1pk + (size_t)(ks * 4) * 512 + lane * 8;
#pragma unroll
        for (int mt = 0; mt < 4; ++mt) {
            bf16x8 afrag = *(const bf16x8*)(apk + mt * 512);
            acc1[mt] = __builtin_amdgcn_mfma_f32_16x16x32_bf16(
                afrag, bfrag, acc1[mt], 0, 0, 0);
        }
    }
    // epilogue: bias + silu -> MID (bf16)
#pragma unroll
    for (int mt = 0; mt < 4; ++mt) {
        int ch0 = mt * 16 + quad * 4;
        float v0 = silu_f(acc1[mt][0] + b1[ch0 + 0]);
        float v1 = silu_f(acc1[mt][1] + b1[ch0 + 1]);
        float v2 = silu_f(acc1[mt][2] + b1[ch0 + 2]);
        float v3 = silu_f(acc1[mt][3] + b1[ch0 + 3]);
        uint2 pk;
        pk.x = pack_bf16x2(v0, v1);
        pk.y = pack_bf16x2(v2, v3);
        *(uint2*)(MID + l15 * 36 + mt * 8 + quad * 2) = pk;
    }

    // GEMM2: K=64 (2 ks), M=16 (out padded 6->16)
    f32x4 acc2 = {0, 0, 0, 0};
    const unsigned int* mrow = MID + l15 * 36;
    for (int ks = 0; ks < 2; ++ks) {
        bf16x8 bfrag = *(const bf16x8*)(mrow + ks * 16 + quad * 4);
        bf16x8 afrag = *(const bf16x8*)(W2pk + (size_t)ks * 512 + lane * 8);
        acc2 = __builtin_amdgcn_mfma_f32_16x16x32_bf16(afrag, bfrag, acc2, 0, 0, 0);
    }

    int n = n0 + l15;
    if (n < NN && quad < 2) {
#pragma unroll
        for (int r = 0; r < 4; ++r) {
            int ch = quad * 4 + r;
            if (ch < 6) out[(size_t)n * 6 + ch] = acc2[r] + b2[ch];
        }
    }
}

// ---------------------------------------------------------------------------
// Pooling: pooled[g][c] = sum_{batch[n]==g} h[n][c];  cnt[g] = count
// ---------------------------------------------------------------------------
__global__ __launch_bounds__(256) void pool_kernel(
    const float* __restrict__ h, const int* __restrict__ batch,
    float* __restrict__ pooled, float* __restrict__ cnt)
{
    const int c   = threadIdx.x & 63;
    const int rep = blockIdx.x * 4 + (threadIdx.x >> 6);   // 1024 reps
    float acc[NG] = {0.f, 0.f, 0.f, 0.f};
    float cl[NG]  = {0.f, 0.f, 0.f, 0.f};
    for (int n = rep; n < NN; n += 1024) {
        int b = batch[n];
        float v = h[n * 64 + c];
#pragma unroll
        for (int gph = 0; gph < NG; ++gph) {
            if (b == gph) { acc[gph] += v; cl[gph] += 1.0f; }
        }
    }
#pragma unroll
    for (int gph = 0; gph < NG; ++gph) {
        atomicAdd(&pooled[gph * 64 + c], acc[gph]);
        if (c == 0) atomicAdd(&cnt[gph], cl[gph]);
    }
}

// ---------------------------------------------------------------------------
// Global decoder: out_global = silu(mean_pool @ W1 + b1) @ W2 + b2 -> [4,4]
// ---------------------------------------------------------------------------
__global__ __launch_bounds__(256) void dec_global_kernel(
    const float* __restrict__ pooled, const float* __restrict__ cnt,
    const float* __restrict__ W1, const float* __restrict__ b1,
    const float* __restrict__ W2, const float* __restrict__ b2,
    float* __restrict__ out)
{
    __shared__ float mid_sh[4][32];
    const int lane = threadIdx.x & 63;
    const int gph  = threadIdx.x >> 6;
    float inv = 1.0f / fmaxf(cnt[gph], 1.0f);
    if (lane < 32) {
        float a = b1[lane];
        for (int k = 0; k < 64; ++k)
            a = fmaf(pooled[gph * 64 + k] * inv, W1[k * 32 + lane], a);
        mid_sh[gph][lane] = silu_f(a);
    }
    __syncthreads();
    if (lane < 4) {
        float o = b2[lane];
        for (int k = 0; k < 32; ++k)
            o = fmaf(mid_sh[gph][k], W2[k * 4 + lane], o);
        out[gph * 4 + lane] = o;
    }
}

// ---------------------------------------------------------------------------
extern "C" void kernel_launch(void* const* d_in, const int* in_sizes, int n_in,
                              void* d_out, int out_size, void* d_ws, size_t ws_size,
                              hipStream_t stream)
{
    const float* x      = (const float*)d_in[0];
    const int*   ei     = (const int*)  d_in[1];
    const float* ea     = (const float*)d_in[2];
    const int*   batch  = (const int*)  d_in[3];
    const float* case_p = (const float*)d_in[4];
    const float* bc_p   = (const float*)d_in[5];
    const float* enc_W1 = (const float*)d_in[6];
    const float* enc_b1 = (const float*)d_in[7];
    const float* enc_W2 = (const float*)d_in[8];
    const float* enc_b2 = (const float*)d_in[9];
    const float* enc_g  = (const float*)d_in[10];
    const float* enc_be = (const float*)d_in[11];
    const float* eW1    = (const float*)d_in[12];
    const float* eb1    = (const float*)d_in[13];
    const float* eW2    = (const float*)d_in[14];
    const float* eb2    = (const float*)d_in[15];
    const float* eg     = (const float*)d_in[16];
    const float* ebe    = (const float*)d_in[17];
    const float* nW1    = (const float*)d_in[18];
    const float* nb1    = (const float*)d_in[19];
    const float* nW2    = (const float*)d_in[20];
    const float* nb2    = (const float*)d_in[21];
    const float* ng     = (const float*)d_in[22];
    const float* nbe    = (const float*)d_in[23];
    const float* dlW1   = (const float*)d_in[24];
    const float* dlb1   = (const float*)d_in[25];
    const float* dlW2   = (const float*)d_in[26];
    const float* dlb2   = (const float*)d_in[27];
    const float* dgW1   = (const float*)d_in[28];
    const float* dgb1   = (const float*)d_in[29];
    const float* dgW2   = (const float*)d_in[30];
    const float* dgb2   = (const float*)d_in[31];

    float* out = (float*)d_out;

    char* ws = (char*)d_ws;
    size_t off_b = 0;
    auto alloc = [&](size_t bytes) {
        void* p = ws + off_b;
        off_b = (off_b + bytes + 255) & ~(size_t)255;
        return p;
    };
    const size_t hBytes = (size_t)NN * H * sizeof(float);     // 12.8 MB
    float*        h      = (float*)alloc(hBytes);
    float*        agg    = (float*)alloc(hBytes);
    unsigned int* h2     = (unsigned int*)alloc((size_t)NN * 32 * 4);  // bf16 mirror
    float*        pooled = (float*)alloc(256 * sizeof(float));
    float*        cnt    = (float*)alloc(4 * sizeof(float));
    int*          deg    = (int*)alloc((NN + 1) * sizeof(int));
    int*          offs   = (int*)alloc((NN + 1) * sizeof(int));
    int*          cursor = (int*)alloc((NN + 1) * sizeof(int));
    int*          bsum   = (int*)alloc(64 * sizeof(int));
    int*          bbase  = (int*)alloc(64 * sizeof(int));
    int*          sidx   = (int*)alloc((size_t)NE * sizeof(int));
    int*          sdst   = (int*)alloc((size_t)NE * sizeof(int));
    int*          ssrc   = (int*)alloc((size_t)NE * sizeof(int));
    uint4*        ea_pk  = (uint4*)alloc((size_t)NE * sizeof(uint4));  // 25.6 MB
    short*        eW1pk  = (short*)alloc((size_t)NL * 10240 * sizeof(short));
    short*        eW2pk  = (short*)alloc((size_t)NL * 4096 * sizeof(short));
    short*        nW1pk  = (short*)alloc((size_t)NL * 8192 * sizeof(short));
    short*        nW2pk  = (short*)alloc((size_t)NL * 4096 * sizeof(short));
    short*        dlW1pk = (short*)alloc(4096 * sizeof(short));
    short*        dlW2pk = (short*)alloc(1024 * sizeof(short));

    hipMemsetAsync(pooled, 0, (256 + 4 + 64) * sizeof(float), stream);
    hipMemsetAsync(deg, 0, (NN + 1) * sizeof(int), stream);

    const int NB = (NN + 1023) / 1024;   // 49
    degree_kernel<<<(NE + 255) / 256, 256, 0, stream>>>(ei, deg);
    scan1_kernel<<<NB, 1024, 0, stream>>>(deg, offs, bsum);
    scan2_kernel<<<1, 64, 0, stream>>>(bsum, bbase, NB);
    scan3_kernel<<<NB, 1024, 0, stream>>>(offs, bbase, cursor);
    scatter_kernel<<<(NE + 255) / 256, 256, 0, stream>>>(ei, cursor, sidx, sdst, ssrc);
    ea_pack_kernel<<<(NE + 255) / 256, 256, 0, stream>>>(ea, sidx, ea_pk);
    pack_weights_kernel<<<dim3(124, NL), 256, 0, stream>>>(
        eW1, eW2, nW1, nW2, dlW1, dlW2,
        eW1pk, eW2pk, nW1pk, nW2pk, dlW1pk, dlW2pk);

    const int nodeBlocks = (NN + 63) / 64;    // 782
    encoder_kernel<<<nodeBlocks, 256, 0, stream>>>(
        x, batch, case_p, bc_p, enc_W1, enc_b1, enc_W2, enc_b2, enc_g, enc_be,
        h, h2);

    for (int l = 0; l < NL; ++l) {
        hipMemsetAsync(agg, 0, hBytes, stream);
        edge_kernel<<<NE / 64, 256, 0, stream>>>(
            h2, sdst, ssrc, ea_pk,
            eW1pk + (size_t)l * 10240, eb1 + l * H,
            eW2pk + (size_t)l * 4096,  eb2 + l * H,
            eg + l * H, ebe + l * H, agg);
        node_kernel<<<nodeBlocks, 256, 0, stream>>>(
            h, h2, agg,
            nW1pk + (size_t)l * 8192, nb1 + l * H,
            nW2pk + (size_t)l * 4096, nb2 + l * H,
            ng + l * H, nbe + l * H);
    }

    dec_local_kernel<<<nodeBlocks, 256, 0, stream>>>(
        h2, dlW1pk, dlb1, dlW2pk, dlb2, out);
    pool_kernel<<<256, 256, 0, stream>>>(h, batch, pooled, cnt);
    dec_global_kernel<<<1, 256, 0, stream>>>(pooled, cnt, dgW1, dgb1, dgW2, dgb2,
                                             out + (size_t)NN * 6);
}